// Round 1
// baseline (4374.577 us; speedup 1.0000x reference)
//
#include <hip/hip_runtime.h>
#include <hip/hip_bf16.h>

// ---------------------------------------------------------------------------
// Sizes (fixed by the problem)
// ---------------------------------------------------------------------------
// N=50000 ops, OP=128, IT=128, RESD=64, MATD=32, H=256, H2=128, OUT=128
// x concat layout (f32 cols): [pred 0..127 | succ 128..255 | res 256..319 |
//                              mat 320..351 | item 352..479 | self 480..607]

// ---------------------------------------------------------------------------
// Scatter: agg[dst_idx[e]] += tab[src_idx[e]]  (D floats per row, f32 atomics)
// ---------------------------------------------------------------------------
template <int D>
__global__ __launch_bounds__(256) void scatter_kernel(
    const float* __restrict__ tab, const int* __restrict__ src_idx,
    const int* __restrict__ dst_idx, float* __restrict__ agg, int E) {
  constexpr int Q = D / 4;  // float4 chunks per row
  int t = blockIdx.x * 256 + threadIdx.x;
  if (t >= E * Q) return;
  int e = t / Q;
  int q = t - e * Q;
  int s = src_idx[e];
  int d = dst_idx[e];
  float4 v = *reinterpret_cast<const float4*>(tab + (size_t)s * D + q * 4);
  float* p = agg + (size_t)d * D + q * 4;
  atomicAdd(p + 0, v.x);
  atomicAdd(p + 1, v.y);
  atomicAdd(p + 2, v.z);
  atomicAdd(p + 3, v.w);
}

// ---------------------------------------------------------------------------
// Fused 2-layer MLP: out = relu(X @ W1 + b1) @ W2 + b2, written as bf16 into
// the strided concat buffer. X optionally gathered through gidx.
// K = input dim, O = output dim, hidden H = 256 always.
// Block: 256 threads, 32 rows. Phase 1: 8 rows x 4 cols per thread.
// ---------------------------------------------------------------------------
template <int K, int O>
__global__ __launch_bounds__(256) void mlp2_kernel(
    const float* __restrict__ X, const int* __restrict__ gidx,
    const float* __restrict__ W1, const float* __restrict__ B1,
    const float* __restrict__ W2, const float* __restrict__ B2,
    __hip_bfloat16* __restrict__ out, int ostride, int ooff, int n) {
  constexpr int H = 256;
  constexpr int ROWS = 32;
  __shared__ float sX[ROWS * K];
  __shared__ float sH[ROWS * H];
  const int tid = threadIdx.x;
  const int row0 = blockIdx.x * ROWS;

  // ---- stage X rows (float4) ----
  constexpr int XV = ROWS * K / 4;
  for (int i = tid; i < XV; i += 256) {
    int r = i / (K / 4);
    int kq = i - r * (K / 4);
    int row = row0 + r;
    float4 v = make_float4(0.f, 0.f, 0.f, 0.f);
    if (row < n) {
      int srow = gidx ? gidx[row] : row;
      v = *reinterpret_cast<const float4*>(X + (size_t)srow * K + kq * 4);
    }
    *reinterpret_cast<float4*>(&sX[r * K + kq * 4]) = v;
  }
  __syncthreads();

  // ---- phase 1: h = relu(X @ W1 + b1), 32x256 outputs ----
  {
    const int cg = tid & 63;   // col group (4 cols)
    const int rg = tid >> 6;   // row group (8 rows)
    const int c = cg * 4;
    const int rbase = rg * 8;
    float acc[8][4];
    float4 b = *reinterpret_cast<const float4*>(B1 + c);
#pragma unroll
    for (int r = 0; r < 8; ++r) {
      acc[r][0] = b.x; acc[r][1] = b.y; acc[r][2] = b.z; acc[r][3] = b.w;
    }
    for (int k0 = 0; k0 < K; k0 += 4) {
      float4 w0 = *reinterpret_cast<const float4*>(W1 + (size_t)(k0 + 0) * H + c);
      float4 w1 = *reinterpret_cast<const float4*>(W1 + (size_t)(k0 + 1) * H + c);
      float4 w2 = *reinterpret_cast<const float4*>(W1 + (size_t)(k0 + 2) * H + c);
      float4 w3 = *reinterpret_cast<const float4*>(W1 + (size_t)(k0 + 3) * H + c);
#pragma unroll
      for (int r = 0; r < 8; ++r) {
        float4 a = *reinterpret_cast<const float4*>(&sX[(rbase + r) * K + k0]);
        acc[r][0] += a.x * w0.x + a.y * w1.x + a.z * w2.x + a.w * w3.x;
        acc[r][1] += a.x * w0.y + a.y * w1.y + a.z * w2.y + a.w * w3.y;
        acc[r][2] += a.x * w0.z + a.y * w1.z + a.z * w2.z + a.w * w3.z;
        acc[r][3] += a.x * w0.w + a.y * w1.w + a.z * w2.w + a.w * w3.w;
      }
    }
#pragma unroll
    for (int r = 0; r < 8; ++r) {
#pragma unroll
      for (int j = 0; j < 4; ++j) {
        sH[(rbase + r) * H + c + j] = fmaxf(acc[r][j], 0.f);
      }
    }
  }
  __syncthreads();

  // ---- phase 2: out = h @ W2 + b2 ----
  {
    constexpr int CPT = (O >= 128) ? 2 : 1;
    constexpr int NCG = O / CPT;
    constexpr int RPT = ROWS * NCG / 256;
    const int cg = tid % NCG;
    const int rg = tid / NCG;
    const int c = cg * CPT;
    const int rbase = rg * RPT;
    float acc[RPT][CPT];
#pragma unroll
    for (int r = 0; r < RPT; ++r)
#pragma unroll
      for (int j = 0; j < CPT; ++j) acc[r][j] = B2[c + j];
    for (int k0 = 0; k0 < H; k0 += 4) {
      float wv[4][CPT];
#pragma unroll
      for (int kk = 0; kk < 4; ++kk)
#pragma unroll
        for (int j = 0; j < CPT; ++j) wv[kk][j] = W2[(size_t)(k0 + kk) * O + c + j];
#pragma unroll
      for (int r = 0; r < RPT; ++r) {
        float4 a = *reinterpret_cast<const float4*>(&sH[(rbase + r) * H + k0]);
#pragma unroll
        for (int j = 0; j < CPT; ++j) {
          acc[r][j] += a.x * wv[0][j] + a.y * wv[1][j] + a.z * wv[2][j] + a.w * wv[3][j];
        }
      }
    }
#pragma unroll
    for (int r = 0; r < RPT; ++r) {
      int row = row0 + rbase + r;
      if (row < n) {
#pragma unroll
        for (int j = 0; j < CPT; ++j) {
          out[(size_t)row * ostride + ooff + c + j] = __float2bfloat16(acc[r][j]);
        }
      }
    }
  }
}

// ---------------------------------------------------------------------------
// Final 3-layer MLP: out = (relu(relu(x@Wc1+b)@Wc2+b))@Wc3+b, x is bf16[N,608]
// Block: 256 threads, 16 rows. All intermediates in LDS.
// ---------------------------------------------------------------------------
__global__ __launch_bounds__(256) void final_mlp_kernel(
    const __hip_bfloat16* __restrict__ xb,
    const float* __restrict__ W1, const float* __restrict__ B1,
    const float* __restrict__ W2, const float* __restrict__ B2,
    const float* __restrict__ W3, const float* __restrict__ B3,
    float* __restrict__ out, int n) {
  constexpr int KX = 608, H1 = 256, H2 = 128, OUT = 128;
  constexpr int ROWS = 16;
  __shared__ float sX[ROWS * KX];    // 38.9 KB
  __shared__ float sH1[ROWS * H1];   // 16 KB
  __shared__ float sH2[ROWS * H2];   // 8 KB
  const int tid = threadIdx.x;
  const int row0 = blockIdx.x * ROWS;

  // ---- stage x rows (bf16 -> f32), 2 elems per uint ----
  const uint* xr = reinterpret_cast<const uint*>(xb + (size_t)row0 * KX);
  for (int i = tid; i < ROWS * KX / 2; i += 256) {
    int j = i * 2;
    int r = j / KX;
    int jj = j - r * KX;
    float lo = 0.f, hi = 0.f;
    if (row0 + r < n) {
      uint u = xr[i];
      lo = __uint_as_float((u & 0xffffu) << 16);
      hi = __uint_as_float(u & 0xffff0000u);
    }
    sX[r * KX + jj] = lo;
    sX[r * KX + jj + 1] = hi;
  }
  __syncthreads();

  // ---- layer 1: sH1 = relu(sX @ W1 + b1), 16x256 ----
  {
    const int cg = tid & 63;
    const int rg = tid >> 6;
    const int c = cg * 4;
    const int rbase = rg * 4;
    float acc[4][4];
    float4 b = *reinterpret_cast<const float4*>(B1 + c);
#pragma unroll
    for (int r = 0; r < 4; ++r) {
      acc[r][0] = b.x; acc[r][1] = b.y; acc[r][2] = b.z; acc[r][3] = b.w;
    }
    for (int k0 = 0; k0 < KX; k0 += 4) {
      float4 w0 = *reinterpret_cast<const float4*>(W1 + (size_t)(k0 + 0) * H1 + c);
      float4 w1 = *reinterpret_cast<const float4*>(W1 + (size_t)(k0 + 1) * H1 + c);
      float4 w2 = *reinterpret_cast<const float4*>(W1 + (size_t)(k0 + 2) * H1 + c);
      float4 w3 = *reinterpret_cast<const float4*>(W1 + (size_t)(k0 + 3) * H1 + c);
#pragma unroll
      for (int r = 0; r < 4; ++r) {
        float4 a = *reinterpret_cast<const float4*>(&sX[(rbase + r) * KX + k0]);
        acc[r][0] += a.x * w0.x + a.y * w1.x + a.z * w2.x + a.w * w3.x;
        acc[r][1] += a.x * w0.y + a.y * w1.y + a.z * w2.y + a.w * w3.y;
        acc[r][2] += a.x * w0.z + a.y * w1.z + a.z * w2.z + a.w * w3.z;
        acc[r][3] += a.x * w0.w + a.y * w1.w + a.z * w2.w + a.w * w3.w;
      }
    }
#pragma unroll
    for (int r = 0; r < 4; ++r)
#pragma unroll
      for (int j = 0; j < 4; ++j)
        sH1[(rbase + r) * H1 + c + j] = fmaxf(acc[r][j], 0.f);
  }
  __syncthreads();

  // ---- layer 2: sH2 = relu(sH1 @ W2 + b2), 16x128 ----
  {
    const int cg = tid & 63;
    const int rg = tid >> 6;
    const int c = cg * 2;
    const int rbase = rg * 4;
    float acc[4][2];
#pragma unroll
    for (int r = 0; r < 4; ++r) { acc[r][0] = B2[c]; acc[r][1] = B2[c + 1]; }
    for (int k0 = 0; k0 < H1; k0 += 4) {
      float wv[4][2];
#pragma unroll
      for (int kk = 0; kk < 4; ++kk) {
        wv[kk][0] = W2[(size_t)(k0 + kk) * H2 + c];
        wv[kk][1] = W2[(size_t)(k0 + kk) * H2 + c + 1];
      }
#pragma unroll
      for (int r = 0; r < 4; ++r) {
        float4 a = *reinterpret_cast<const float4*>(&sH1[(rbase + r) * H1 + k0]);
#pragma unroll
        for (int j = 0; j < 2; ++j)
          acc[r][j] += a.x * wv[0][j] + a.y * wv[1][j] + a.z * wv[2][j] + a.w * wv[3][j];
      }
    }
#pragma unroll
    for (int r = 0; r < 4; ++r)
#pragma unroll
      for (int j = 0; j < 2; ++j)
        sH2[(rbase + r) * H2 + c + j] = fmaxf(acc[r][j], 0.f);
  }
  __syncthreads();

  // ---- layer 3: out = sH2 @ W3 + b3, 16x128, f32 store ----
  {
    const int cg = tid & 63;
    const int rg = tid >> 6;
    const int c = cg * 2;
    const int rbase = rg * 4;
    float acc[4][2];
#pragma unroll
    for (int r = 0; r < 4; ++r) { acc[r][0] = B3[c]; acc[r][1] = B3[c + 1]; }
    for (int k0 = 0; k0 < H2; k0 += 4) {
      float wv[4][2];
#pragma unroll
      for (int kk = 0; kk < 4; ++kk) {
        wv[kk][0] = W3[(size_t)(k0 + kk) * OUT + c];
        wv[kk][1] = W3[(size_t)(k0 + kk) * OUT + c + 1];
      }
#pragma unroll
      for (int r = 0; r < 4; ++r) {
        float4 a = *reinterpret_cast<const float4*>(&sH2[(rbase + r) * H2 + k0]);
#pragma unroll
        for (int j = 0; j < 2; ++j)
          acc[r][j] += a.x * wv[0][j] + a.y * wv[1][j] + a.z * wv[2][j] + a.w * wv[3][j];
      }
    }
#pragma unroll
    for (int r = 0; r < 4; ++r) {
      int row = row0 + rbase + r;
      if (row < n) {
        float2 v = make_float2(acc[r][0], acc[r][1]);
        *reinterpret_cast<float2*>(&out[(size_t)row * OUT + c]) = v;
      }
    }
  }
}

// ---------------------------------------------------------------------------
// kernel_launch
// ---------------------------------------------------------------------------
extern "C" void kernel_launch(void* const* d_in, const int* in_sizes, int n_in,
                              void* d_out, int out_size, void* d_ws,
                              size_t ws_size, hipStream_t stream) {
  const float* operations = (const float*)d_in[0];
  const float* items      = (const float*)d_in[1];
  const float* materials  = (const float*)d_in[2];
  const float* resources  = (const float*)d_in[3];
  const int* related      = (const int*)d_in[4];
  const int* res_op       = (const int*)d_in[5];
  const int* res_res      = (const int*)d_in[6];
  const int* mat_op       = (const int*)d_in[7];
  const int* mat_mat      = (const int*)d_in[8];
  const int* prec_src     = (const int*)d_in[9];
  const int* prec_dst     = (const int*)d_in[10];
  const float* w_self1 = (const float*)d_in[11];
  const float* b_self1 = (const float*)d_in[12];
  const float* w_self2 = (const float*)d_in[13];
  const float* b_self2 = (const float*)d_in[14];
  const float* w_item1 = (const float*)d_in[15];
  const float* b_item1 = (const float*)d_in[16];
  const float* w_item2 = (const float*)d_in[17];
  const float* b_item2 = (const float*)d_in[18];
  const float* w_pred1 = (const float*)d_in[19];
  const float* b_pred1 = (const float*)d_in[20];
  const float* w_pred2 = (const float*)d_in[21];
  const float* b_pred2 = (const float*)d_in[22];
  const float* w_succ1 = (const float*)d_in[23];
  const float* b_succ1 = (const float*)d_in[24];
  const float* w_succ2 = (const float*)d_in[25];
  const float* b_succ2 = (const float*)d_in[26];
  const float* w_res1  = (const float*)d_in[27];
  const float* b_res1  = (const float*)d_in[28];
  const float* w_res2  = (const float*)d_in[29];
  const float* b_res2  = (const float*)d_in[30];
  const float* w_mat1  = (const float*)d_in[31];
  const float* b_mat1  = (const float*)d_in[32];
  const float* w_mat2  = (const float*)d_in[33];
  const float* b_mat2  = (const float*)d_in[34];
  const float* w_c1    = (const float*)d_in[35];
  const float* b_c1    = (const float*)d_in[36];
  const float* w_c2    = (const float*)d_in[37];
  const float* b_c2    = (const float*)d_in[38];
  const float* w_c3    = (const float*)d_in[39];
  const float* b_c3    = (const float*)d_in[40];

  const int N = in_sizes[0] / 128;       // 50000
  const int E_RES = in_sizes[5];         // 100000
  const int E_MAT = in_sizes[7];         // 100000
  const int E_PREC = in_sizes[9];        // 800000

  // ws layout: x bf16 [N,608] | aggs f32 [N,128]+[N,128]+[N,64]+[N,32]
  __hip_bfloat16* xbuf = (__hip_bfloat16*)d_ws;
  size_t xbytes = (size_t)N * 608 * sizeof(__hip_bfloat16);
  float* aggf = (float*)((char*)d_ws + xbytes);
  float* agg_pred = aggf;
  float* agg_succ = aggf + (size_t)N * 128;
  float* agg_res  = aggf + (size_t)N * 256;
  float* agg_mat  = aggf + (size_t)N * 320;

  hipMemsetAsync(aggf, 0, (size_t)N * 352 * sizeof(float), stream);

  dim3 blk(256);
  // scatter aggregations
  scatter_kernel<32><<<(E_MAT * 8 + 255) / 256, blk, 0, stream>>>(
      materials, mat_mat, mat_op, agg_mat, E_MAT);
  scatter_kernel<64><<<(E_RES * 16 + 255) / 256, blk, 0, stream>>>(
      resources, res_res, res_op, agg_res, E_RES);
  scatter_kernel<128><<<(E_PREC * 32 + 255) / 256, blk, 0, stream>>>(
      operations, prec_dst, prec_src, agg_pred, E_PREC);
  scatter_kernel<128><<<(E_PREC * 32 + 255) / 256, blk, 0, stream>>>(
      operations, prec_src, prec_dst, agg_succ, E_PREC);

  // per-node MLPs -> bf16 concat buffer
  int gb = (N + 31) / 32;
  mlp2_kernel<128, 128><<<gb, blk, 0, stream>>>(
      agg_pred, nullptr, w_pred1, b_pred1, w_pred2, b_pred2, xbuf, 608, 0, N);
  mlp2_kernel<128, 128><<<gb, blk, 0, stream>>>(
      agg_succ, nullptr, w_succ1, b_succ1, w_succ2, b_succ2, xbuf, 608, 128, N);
  mlp2_kernel<64, 64><<<gb, blk, 0, stream>>>(
      agg_res, nullptr, w_res1, b_res1, w_res2, b_res2, xbuf, 608, 256, N);
  mlp2_kernel<32, 32><<<gb, blk, 0, stream>>>(
      agg_mat, nullptr, w_mat1, b_mat1, w_mat2, b_mat2, xbuf, 608, 320, N);
  mlp2_kernel<128, 128><<<gb, blk, 0, stream>>>(
      items, related, w_item1, b_item1, w_item2, b_item2, xbuf, 608, 352, N);
  mlp2_kernel<128, 128><<<gb, blk, 0, stream>>>(
      operations, nullptr, w_self1, b_self1, w_self2, b_self2, xbuf, 608, 480, N);

  // final combiner
  final_mlp_kernel<<<(N + 15) / 16, blk, 0, stream>>>(
      xbuf, w_c1, b_c1, w_c2, b_c2, w_c3, b_c3, (float*)d_out, N);
}

// Round 2
// 1901.824 us; speedup vs baseline: 2.3002x; 2.3002x over previous
//
#include <hip/hip_runtime.h>
#include <hip/hip_bf16.h>

// ---------------------------------------------------------------------------
// N=50000 ops, OP=128, H=256, H2=128, OUT=128
// x concat layout: [pred 0..127 | succ 128..255 | res 256..319 |
//                   mat 320..351 | item 352..479 | self 480..607]
// ---------------------------------------------------------------------------

// ---------------------------------------------------------------------------
// CSR build: count -> scan -> cursor copy -> fill
// ---------------------------------------------------------------------------
__global__ __launch_bounds__(256) void count_kernel(
    const int* __restrict__ dst, int* __restrict__ counts, int E) {
  int e = blockIdx.x * 256 + threadIdx.x;
  if (e < E) atomicAdd(&counts[dst[e]], 1);
}

// 4 independent exclusive scans, one per block. counts: 4 arrays of n,
// offsets: 4 arrays of (n+1).
__global__ __launch_bounds__(1024) void scan4_kernel(
    const int* __restrict__ counts, int* __restrict__ offsets, int n) {
  const int* cnt = counts + (size_t)blockIdx.x * n;
  int* offs = offsets + (size_t)blockIdx.x * (n + 1);
  __shared__ int wsum[16];
  __shared__ int carry_s;
  const int lane = threadIdx.x & 63;
  const int wid = threadIdx.x >> 6;
  if (threadIdx.x == 0) carry_s = 0;
  __syncthreads();
  for (int base = 0; base < n; base += 1024) {
    int i = base + threadIdx.x;
    int v = (i < n) ? cnt[i] : 0;
    int x = v;
#pragma unroll
    for (int off = 1; off < 64; off <<= 1) {
      int t = __shfl_up(x, off, 64);
      if (lane >= off) x += t;
    }
    if (lane == 63) wsum[wid] = x;
    __syncthreads();
    if (wid == 0 && lane < 16) {
      int w = wsum[lane];
#pragma unroll
      for (int off = 1; off < 16; off <<= 1) {
        int t = __shfl_up(w, off, 16);
        if (lane >= off) w += t;
      }
      wsum[lane] = w;
    }
    __syncthreads();
    int carry = carry_s;
    int wpre = (wid == 0) ? 0 : wsum[wid - 1];
    if (i < n) offs[i] = carry + wpre + x - v;
    __syncthreads();
    if (threadIdx.x == 1023) carry_s = carry + wsum[15];
    __syncthreads();
  }
  if (threadIdx.x == 0) offs[n] = carry_s;
}

// cursor[t][i] = offsets[t][i] for the 4 CSR structures
__global__ __launch_bounds__(256) void cursor_copy_kernel(
    const int* __restrict__ offsets, int* __restrict__ cursor, int n) {
  int i = blockIdx.x * 256 + threadIdx.x;
  if (i < 4 * n) {
    int t = i / n, j = i - t * n;
    cursor[(size_t)t * n + j] = offsets[(size_t)t * (n + 1) + j];
  }
}

__global__ __launch_bounds__(256) void fill_kernel(
    const int* __restrict__ dst, const int* __restrict__ src,
    int* __restrict__ cursor, int* __restrict__ col, int E) {
  int e = blockIdx.x * 256 + threadIdx.x;
  if (e < E) {
    int p = atomicAdd(&cursor[dst[e]], 1);
    col[p] = src[e];
  }
}

// ---------------------------------------------------------------------------
// CSR aggregate: out[r] = sum_{e in row r} tab[col[e]]  (D floats per row)
// LPR lanes per row, float2 per lane.
// ---------------------------------------------------------------------------
template <int D, int LPR>
__global__ __launch_bounds__(256) void csr_agg_kernel(
    const float* __restrict__ tab, const int* __restrict__ col,
    const int* __restrict__ offsets, float* __restrict__ out, int n) {
  constexpr int RPB = 256 / LPR;
  const int lane = threadIdx.x % LPR;
  const int r = blockIdx.x * RPB + threadIdx.x / LPR;
  if (r >= n) return;
  const int beg = offsets[r];
  const int end = offsets[r + 1];
  float2 acc = make_float2(0.f, 0.f);
  for (int e = beg; e < end; ++e) {
    int s = col[e];
    float2 v = *reinterpret_cast<const float2*>(tab + (size_t)s * D + lane * 2);
    acc.x += v.x;
    acc.y += v.y;
  }
  *reinterpret_cast<float2*>(out + (size_t)r * D + lane * 2) = acc;
}

// ---------------------------------------------------------------------------
// Fused 2-layer MLP: out = relu(X @ W1 + b1) @ W2 + b2, bf16 strided store.
// ---------------------------------------------------------------------------
template <int K, int O>
__global__ __launch_bounds__(256) void mlp2_kernel(
    const float* __restrict__ X, const int* __restrict__ gidx,
    const float* __restrict__ W1, const float* __restrict__ B1,
    const float* __restrict__ W2, const float* __restrict__ B2,
    __hip_bfloat16* __restrict__ out, int ostride, int ooff, int n) {
  constexpr int H = 256;
  constexpr int ROWS = 32;
  __shared__ float sX[ROWS * K];
  __shared__ float sH[ROWS * H];
  const int tid = threadIdx.x;
  const int row0 = blockIdx.x * ROWS;

  constexpr int XV = ROWS * K / 4;
  for (int i = tid; i < XV; i += 256) {
    int r = i / (K / 4);
    int kq = i - r * (K / 4);
    int row = row0 + r;
    float4 v = make_float4(0.f, 0.f, 0.f, 0.f);
    if (row < n) {
      int srow = gidx ? gidx[row] : row;
      v = *reinterpret_cast<const float4*>(X + (size_t)srow * K + kq * 4);
    }
    *reinterpret_cast<float4*>(&sX[r * K + kq * 4]) = v;
  }
  __syncthreads();

  {
    const int cg = tid & 63;
    const int rg = tid >> 6;
    const int c = cg * 4;
    const int rbase = rg * 8;
    float acc[8][4];
    float4 b = *reinterpret_cast<const float4*>(B1 + c);
#pragma unroll
    for (int r = 0; r < 8; ++r) {
      acc[r][0] = b.x; acc[r][1] = b.y; acc[r][2] = b.z; acc[r][3] = b.w;
    }
    for (int k0 = 0; k0 < K; k0 += 4) {
      float4 w0 = *reinterpret_cast<const float4*>(W1 + (size_t)(k0 + 0) * H + c);
      float4 w1 = *reinterpret_cast<const float4*>(W1 + (size_t)(k0 + 1) * H + c);
      float4 w2 = *reinterpret_cast<const float4*>(W1 + (size_t)(k0 + 2) * H + c);
      float4 w3 = *reinterpret_cast<const float4*>(W1 + (size_t)(k0 + 3) * H + c);
#pragma unroll
      for (int r = 0; r < 8; ++r) {
        float4 a = *reinterpret_cast<const float4*>(&sX[(rbase + r) * K + k0]);
        acc[r][0] += a.x * w0.x + a.y * w1.x + a.z * w2.x + a.w * w3.x;
        acc[r][1] += a.x * w0.y + a.y * w1.y + a.z * w2.y + a.w * w3.y;
        acc[r][2] += a.x * w0.z + a.y * w1.z + a.z * w2.z + a.w * w3.z;
        acc[r][3] += a.x * w0.w + a.y * w1.w + a.z * w2.w + a.w * w3.w;
      }
    }
#pragma unroll
    for (int r = 0; r < 8; ++r) {
#pragma unroll
      for (int j = 0; j < 4; ++j) {
        sH[(rbase + r) * H + c + j] = fmaxf(acc[r][j], 0.f);
      }
    }
  }
  __syncthreads();

  {
    constexpr int CPT = (O >= 128) ? 2 : 1;
    constexpr int NCG = O / CPT;
    constexpr int RPT = ROWS * NCG / 256;
    const int cg = tid % NCG;
    const int rg = tid / NCG;
    const int c = cg * CPT;
    const int rbase = rg * RPT;
    float acc[RPT][CPT];
#pragma unroll
    for (int r = 0; r < RPT; ++r)
#pragma unroll
      for (int j = 0; j < CPT; ++j) acc[r][j] = B2[c + j];
    for (int k0 = 0; k0 < H; k0 += 4) {
      float wv[4][CPT];
#pragma unroll
      for (int kk = 0; kk < 4; ++kk)
#pragma unroll
        for (int j = 0; j < CPT; ++j) wv[kk][j] = W2[(size_t)(k0 + kk) * O + c + j];
#pragma unroll
      for (int r = 0; r < RPT; ++r) {
        float4 a = *reinterpret_cast<const float4*>(&sH[(rbase + r) * H + k0]);
#pragma unroll
        for (int j = 0; j < CPT; ++j) {
          acc[r][j] += a.x * wv[0][j] + a.y * wv[1][j] + a.z * wv[2][j] + a.w * wv[3][j];
        }
      }
    }
#pragma unroll
    for (int r = 0; r < RPT; ++r) {
      int row = row0 + rbase + r;
      if (row < n) {
#pragma unroll
        for (int j = 0; j < CPT; ++j) {
          out[(size_t)row * ostride + ooff + c + j] = __float2bfloat16(acc[r][j]);
        }
      }
    }
  }
}

// ---------------------------------------------------------------------------
// Final 3-layer MLP (x bf16[N,608] -> f32[N,128])
// ---------------------------------------------------------------------------
__global__ __launch_bounds__(256) void final_mlp_kernel(
    const __hip_bfloat16* __restrict__ xb,
    const float* __restrict__ W1, const float* __restrict__ B1,
    const float* __restrict__ W2, const float* __restrict__ B2,
    const float* __restrict__ W3, const float* __restrict__ B3,
    float* __restrict__ out, int n) {
  constexpr int KX = 608, H1 = 256, H2 = 128, OUT = 128;
  constexpr int ROWS = 16;
  __shared__ float sX[ROWS * KX];
  __shared__ float sH1[ROWS * H1];
  __shared__ float sH2[ROWS * H2];
  const int tid = threadIdx.x;
  const int row0 = blockIdx.x * ROWS;

  const uint* xr = reinterpret_cast<const uint*>(xb + (size_t)row0 * KX);
  for (int i = tid; i < ROWS * KX / 2; i += 256) {
    int j = i * 2;
    int r = j / KX;
    int jj = j - r * KX;
    float lo = 0.f, hi = 0.f;
    if (row0 + r < n) {
      uint u = xr[i];
      lo = __uint_as_float((u & 0xffffu) << 16);
      hi = __uint_as_float(u & 0xffff0000u);
    }
    sX[r * KX + jj] = lo;
    sX[r * KX + jj + 1] = hi;
  }
  __syncthreads();

  {
    const int cg = tid & 63;
    const int rg = tid >> 6;
    const int c = cg * 4;
    const int rbase = rg * 4;
    float acc[4][4];
    float4 b = *reinterpret_cast<const float4*>(B1 + c);
#pragma unroll
    for (int r = 0; r < 4; ++r) {
      acc[r][0] = b.x; acc[r][1] = b.y; acc[r][2] = b.z; acc[r][3] = b.w;
    }
    for (int k0 = 0; k0 < KX; k0 += 4) {
      float4 w0 = *reinterpret_cast<const float4*>(W1 + (size_t)(k0 + 0) * H1 + c);
      float4 w1 = *reinterpret_cast<const float4*>(W1 + (size_t)(k0 + 1) * H1 + c);
      float4 w2 = *reinterpret_cast<const float4*>(W1 + (size_t)(k0 + 2) * H1 + c);
      float4 w3 = *reinterpret_cast<const float4*>(W1 + (size_t)(k0 + 3) * H1 + c);
#pragma unroll
      for (int r = 0; r < 4; ++r) {
        float4 a = *reinterpret_cast<const float4*>(&sX[(rbase + r) * KX + k0]);
        acc[r][0] += a.x * w0.x + a.y * w1.x + a.z * w2.x + a.w * w3.x;
        acc[r][1] += a.x * w0.y + a.y * w1.y + a.z * w2.y + a.w * w3.y;
        acc[r][2] += a.x * w0.z + a.y * w1.z + a.z * w2.z + a.w * w3.z;
        acc[r][3] += a.x * w0.w + a.y * w1.w + a.z * w2.w + a.w * w3.w;
      }
    }
#pragma unroll
    for (int r = 0; r < 4; ++r)
#pragma unroll
      for (int j = 0; j < 4; ++j)
        sH1[(rbase + r) * H1 + c + j] = fmaxf(acc[r][j], 0.f);
  }
  __syncthreads();

  {
    const int cg = tid & 63;
    const int rg = tid >> 6;
    const int c = cg * 2;
    const int rbase = rg * 4;
    float acc[4][2];
#pragma unroll
    for (int r = 0; r < 4; ++r) { acc[r][0] = B2[c]; acc[r][1] = B2[c + 1]; }
    for (int k0 = 0; k0 < H1; k0 += 4) {
      float wv[4][2];
#pragma unroll
      for (int kk = 0; kk < 4; ++kk) {
        wv[kk][0] = W2[(size_t)(k0 + kk) * H2 + c];
        wv[kk][1] = W2[(size_t)(k0 + kk) * H2 + c + 1];
      }
#pragma unroll
      for (int r = 0; r < 4; ++r) {
        float4 a = *reinterpret_cast<const float4*>(&sH1[(rbase + r) * H1 + k0]);
#pragma unroll
        for (int j = 0; j < 2; ++j)
          acc[r][j] += a.x * wv[0][j] + a.y * wv[1][j] + a.z * wv[2][j] + a.w * wv[3][j];
      }
    }
#pragma unroll
    for (int r = 0; r < 4; ++r)
#pragma unroll
      for (int j = 0; j < 2; ++j)
        sH2[(rbase + r) * H2 + c + j] = fmaxf(acc[r][j], 0.f);
  }
  __syncthreads();

  {
    const int cg = tid & 63;
    const int rg = tid >> 6;
    const int c = cg * 2;
    const int rbase = rg * 4;
    float acc[4][2];
#pragma unroll
    for (int r = 0; r < 4; ++r) { acc[r][0] = B3[c]; acc[r][1] = B3[c + 1]; }
    for (int k0 = 0; k0 < H2; k0 += 4) {
      float wv[4][2];
#pragma unroll
      for (int kk = 0; kk < 4; ++kk) {
        wv[kk][0] = W3[(size_t)(k0 + kk) * OUT + c];
        wv[kk][1] = W3[(size_t)(k0 + kk) * OUT + c + 1];
      }
#pragma unroll
      for (int r = 0; r < 4; ++r) {
        float4 a = *reinterpret_cast<const float4*>(&sH2[(rbase + r) * H2 + k0]);
#pragma unroll
        for (int j = 0; j < 2; ++j)
          acc[r][j] += a.x * wv[0][j] + a.y * wv[1][j] + a.z * wv[2][j] + a.w * wv[3][j];
      }
    }
#pragma unroll
    for (int r = 0; r < 4; ++r) {
      int row = row0 + rbase + r;
      if (row < n) {
        float2 v = make_float2(acc[r][0], acc[r][1]);
        *reinterpret_cast<float2*>(&out[(size_t)row * OUT + c]) = v;
      }
    }
  }
}

// ---------------------------------------------------------------------------
// kernel_launch
// ---------------------------------------------------------------------------
extern "C" void kernel_launch(void* const* d_in, const int* in_sizes, int n_in,
                              void* d_out, int out_size, void* d_ws,
                              size_t ws_size, hipStream_t stream) {
  const float* operations = (const float*)d_in[0];
  const float* items      = (const float*)d_in[1];
  const float* materials  = (const float*)d_in[2];
  const float* resources  = (const float*)d_in[3];
  const int* related      = (const int*)d_in[4];
  const int* res_op       = (const int*)d_in[5];
  const int* res_res      = (const int*)d_in[6];
  const int* mat_op       = (const int*)d_in[7];
  const int* mat_mat      = (const int*)d_in[8];
  const int* prec_src     = (const int*)d_in[9];
  const int* prec_dst     = (const int*)d_in[10];
  const float* w_self1 = (const float*)d_in[11];
  const float* b_self1 = (const float*)d_in[12];
  const float* w_self2 = (const float*)d_in[13];
  const float* b_self2 = (const float*)d_in[14];
  const float* w_item1 = (const float*)d_in[15];
  const float* b_item1 = (const float*)d_in[16];
  const float* w_item2 = (const float*)d_in[17];
  const float* b_item2 = (const float*)d_in[18];
  const float* w_pred1 = (const float*)d_in[19];
  const float* b_pred1 = (const float*)d_in[20];
  const float* w_pred2 = (const float*)d_in[21];
  const float* b_pred2 = (const float*)d_in[22];
  const float* w_succ1 = (const float*)d_in[23];
  const float* b_succ1 = (const float*)d_in[24];
  const float* w_succ2 = (const float*)d_in[25];
  const float* b_succ2 = (const float*)d_in[26];
  const float* w_res1  = (const float*)d_in[27];
  const float* b_res1  = (const float*)d_in[28];
  const float* w_res2  = (const float*)d_in[29];
  const float* b_res2  = (const float*)d_in[30];
  const float* w_mat1  = (const float*)d_in[31];
  const float* b_mat1  = (const float*)d_in[32];
  const float* w_mat2  = (const float*)d_in[33];
  const float* b_mat2  = (const float*)d_in[34];
  const float* w_c1    = (const float*)d_in[35];
  const float* b_c1    = (const float*)d_in[36];
  const float* w_c2    = (const float*)d_in[37];
  const float* b_c2    = (const float*)d_in[38];
  const float* w_c3    = (const float*)d_in[39];
  const float* b_c3    = (const float*)d_in[40];

  const int N = in_sizes[0] / 128;   // 50000
  const int E_RES = in_sizes[5];     // 100000
  const int E_MAT = in_sizes[7];     // 100000
  const int E_PREC = in_sizes[9];    // 800000

  // ws layout:
  //   [0, 60.8MB)  xbuf bf16 [N,608]  -- ALSO aliased early by CSR ints
  //   [60.8MB, +70.4MB) agg f32: pred[N*128] succ[N*128] res[N*64] mat[N*32]
  __hip_bfloat16* xbuf = (__hip_bfloat16*)d_ws;
  size_t xbytes = (size_t)N * 608 * sizeof(__hip_bfloat16);
  float* aggf = (float*)((char*)d_ws + xbytes);
  float* agg_pred = aggf;
  float* agg_succ = aggf + (size_t)N * 128;
  float* agg_res  = aggf + (size_t)N * 256;
  float* agg_mat  = aggf + (size_t)N * 320;

  // CSR scratch aliased over xbuf region (dead before any MLP writes xbuf):
  // offs: 4 arrays of (N+1) | tmp(count/cursor): 4 arrays of N | cols
  int* offs = (int*)d_ws;                 // 4*(N+1)
  int* tmp  = offs + 4 * (size_t)(N + 1); // 4*N
  int* col_pred = tmp + 4 * (size_t)N;    // E_PREC
  int* col_succ = col_pred + E_PREC;      // E_PREC
  int* col_res  = col_succ + E_PREC;      // E_RES
  int* col_mat  = col_res + E_RES;        // E_MAT
  int* offs_pred = offs;
  int* offs_succ = offs + (N + 1);
  int* offs_res  = offs + 2 * (N + 1);
  int* offs_mat  = offs + 3 * (N + 1);
  int* cur_pred = tmp;
  int* cur_succ = tmp + N;
  int* cur_res  = tmp + 2 * N;
  int* cur_mat  = tmp + 3 * N;

  dim3 blk(256);

  // ---- CSR build ----
  hipMemsetAsync(tmp, 0, 4 * (size_t)N * sizeof(int), stream);
  // pred: agg_pred[prec_src] += ops[prec_dst]  -> dst=prec_src, gather=prec_dst
  count_kernel<<<(E_PREC + 255) / 256, blk, 0, stream>>>(prec_src, cur_pred, E_PREC);
  count_kernel<<<(E_PREC + 255) / 256, blk, 0, stream>>>(prec_dst, cur_succ, E_PREC);
  count_kernel<<<(E_RES + 255) / 256, blk, 0, stream>>>(res_op, cur_res, E_RES);
  count_kernel<<<(E_MAT + 255) / 256, blk, 0, stream>>>(mat_op, cur_mat, E_MAT);
  scan4_kernel<<<4, 1024, 0, stream>>>(tmp, offs, N);
  cursor_copy_kernel<<<(4 * N + 255) / 256, blk, 0, stream>>>(offs, tmp, N);
  fill_kernel<<<(E_PREC + 255) / 256, blk, 0, stream>>>(prec_src, prec_dst, cur_pred, col_pred, E_PREC);
  fill_kernel<<<(E_PREC + 255) / 256, blk, 0, stream>>>(prec_dst, prec_src, cur_succ, col_succ, E_PREC);
  fill_kernel<<<(E_RES + 255) / 256, blk, 0, stream>>>(res_op, res_res, cur_res, col_res, E_RES);
  fill_kernel<<<(E_MAT + 255) / 256, blk, 0, stream>>>(mat_op, mat_mat, cur_mat, col_mat, E_MAT);

  // ---- aggregate ----
  csr_agg_kernel<128, 64><<<(N + 3) / 4, blk, 0, stream>>>(operations, col_pred, offs_pred, agg_pred, N);
  csr_agg_kernel<128, 64><<<(N + 3) / 4, blk, 0, stream>>>(operations, col_succ, offs_succ, agg_succ, N);
  csr_agg_kernel<64, 32><<<(N + 7) / 8, blk, 0, stream>>>(resources, col_res, offs_res, agg_res, N);
  csr_agg_kernel<32, 16><<<(N + 15) / 16, blk, 0, stream>>>(materials, col_mat, offs_mat, agg_mat, N);

  // ---- per-node MLPs -> bf16 concat buffer (overwrites CSR scratch; fine) ----
  int gb = (N + 31) / 32;
  mlp2_kernel<128, 128><<<gb, blk, 0, stream>>>(
      agg_pred, nullptr, w_pred1, b_pred1, w_pred2, b_pred2, xbuf, 608, 0, N);
  mlp2_kernel<128, 128><<<gb, blk, 0, stream>>>(
      agg_succ, nullptr, w_succ1, b_succ1, w_succ2, b_succ2, xbuf, 608, 128, N);
  mlp2_kernel<64, 64><<<gb, blk, 0, stream>>>(
      agg_res, nullptr, w_res1, b_res1, w_res2, b_res2, xbuf, 608, 256, N);
  mlp2_kernel<32, 32><<<gb, blk, 0, stream>>>(
      agg_mat, nullptr, w_mat1, b_mat1, w_mat2, b_mat2, xbuf, 608, 320, N);
  mlp2_kernel<128, 128><<<gb, blk, 0, stream>>>(
      items, related, w_item1, b_item1, w_item2, b_item2, xbuf, 608, 352, N);
  mlp2_kernel<128, 128><<<gb, blk, 0, stream>>>(
      operations, nullptr, w_self1, b_self1, w_self2, b_self2, xbuf, 608, 480, N);

  // ---- final combiner ----
  final_mlp_kernel<<<(N + 15) / 16, blk, 0, stream>>>(
      xbuf, w_c1, b_c1, w_c2, b_c2, w_c3, b_c3, (float*)d_out, N);
}

// Round 3
// 732.726 us; speedup vs baseline: 5.9703x; 2.5955x over previous
//
#include <hip/hip_runtime.h>
#include <hip/hip_bf16.h>

typedef __attribute__((ext_vector_type(8))) short short8;
typedef __attribute__((ext_vector_type(4))) float f32x4;
using bf16 = __hip_bfloat16;

// N=50000, OP=128, H=256, H2=128, OUT=128
// xbuf concat: [pred 0 | succ 128 | res 256 | mat 320 | item 352 | self 480], 608 wide

__device__ __forceinline__ short f2bf(float f) {
  union { float f; unsigned u; } v; v.f = f;
  unsigned r = (v.u + 0x7fffu + ((v.u >> 16) & 1u)) >> 16;  // RNE
  return (short)r;
}

// ---------------------------------------------------------------------------
// CSR build (unchanged from R2 — verified)
// ---------------------------------------------------------------------------
__global__ __launch_bounds__(256) void count_kernel(
    const int* __restrict__ dst, int* __restrict__ counts, int E) {
  int e = blockIdx.x * 256 + threadIdx.x;
  if (e < E) atomicAdd(&counts[dst[e]], 1);
}

__global__ __launch_bounds__(1024) void scan4_kernel(
    const int* __restrict__ counts, int* __restrict__ offsets, int n) {
  const int* cnt = counts + (size_t)blockIdx.x * n;
  int* offs = offsets + (size_t)blockIdx.x * (n + 1);
  __shared__ int wsum[16];
  __shared__ int carry_s;
  const int lane = threadIdx.x & 63;
  const int wid = threadIdx.x >> 6;
  if (threadIdx.x == 0) carry_s = 0;
  __syncthreads();
  for (int base = 0; base < n; base += 1024) {
    int i = base + threadIdx.x;
    int v = (i < n) ? cnt[i] : 0;
    int x = v;
#pragma unroll
    for (int off = 1; off < 64; off <<= 1) {
      int t = __shfl_up(x, off, 64);
      if (lane >= off) x += t;
    }
    if (lane == 63) wsum[wid] = x;
    __syncthreads();
    if (wid == 0 && lane < 16) {
      int w = wsum[lane];
#pragma unroll
      for (int off = 1; off < 16; off <<= 1) {
        int t = __shfl_up(w, off, 16);
        if (lane >= off) w += t;
      }
      wsum[lane] = w;
    }
    __syncthreads();
    int carry = carry_s;
    int wpre = (wid == 0) ? 0 : wsum[wid - 1];
    if (i < n) offs[i] = carry + wpre + x - v;
    __syncthreads();
    if (threadIdx.x == 1023) carry_s = carry + wsum[15];
    __syncthreads();
  }
  if (threadIdx.x == 0) offs[n] = carry_s;
}

__global__ __launch_bounds__(256) void cursor_copy_kernel(
    const int* __restrict__ offsets, int* __restrict__ cursor, int n) {
  int i = blockIdx.x * 256 + threadIdx.x;
  if (i < 4 * n) {
    int t = i / n, j = i - t * n;
    cursor[(size_t)t * n + j] = offsets[(size_t)t * (n + 1) + j];
  }
}

__global__ __launch_bounds__(256) void fill_kernel(
    const int* __restrict__ dst, const int* __restrict__ src,
    int* __restrict__ cursor, int* __restrict__ col, int E) {
  int e = blockIdx.x * 256 + threadIdx.x;
  if (e < E) {
    int p = atomicAdd(&cursor[dst[e]], 1);
    col[p] = src[e];
  }
}

// ---------------------------------------------------------------------------
// CSR aggregate -> bf16 output
// ---------------------------------------------------------------------------
template <int D, int LPR>
__global__ __launch_bounds__(256) void csr_agg_kernel(
    const float* __restrict__ tab, const int* __restrict__ col,
    const int* __restrict__ offsets, bf16* __restrict__ out, int n) {
  constexpr int RPB = 256 / LPR;
  const int lane = threadIdx.x % LPR;
  const int r = blockIdx.x * RPB + threadIdx.x / LPR;
  if (r >= n) return;
  const int beg = offsets[r], end = offsets[r + 1];
  float2 acc = make_float2(0.f, 0.f);
  for (int e = beg; e < end; ++e) {
    int s = col[e];
    float2 v = *reinterpret_cast<const float2*>(tab + (size_t)s * D + lane * 2);
    acc.x += v.x;
    acc.y += v.y;
  }
  unsigned u = (unsigned)(unsigned short)f2bf(acc.x) |
               ((unsigned)(unsigned short)f2bf(acc.y) << 16);
  *reinterpret_cast<unsigned*>(out + (size_t)r * D + lane * 2) = u;
}

// ---------------------------------------------------------------------------
// Weight -> MFMA B-fragment layout conversion (f32 row-major [K][C] -> bf16
// frags: frag[tile= kc*CT+ct][lane][j] = W[kc*32 + (lane>>4)*8 + j][ct*16 + (lane&15)])
// ---------------------------------------------------------------------------
struct WDesc { const float* src; int K; int C; int dstoff; };
struct WDescs13 { WDesc w[13]; };

__global__ __launch_bounds__(256) void wconv_kernel(WDescs13 ds, short* __restrict__ dstbase) {
  WDesc d = ds.w[blockIdx.y];
  int KC = d.K >> 5, CT = d.C >> 4;
  int t = blockIdx.x * 256 + threadIdx.x;
  if (t >= KC * CT * 64) return;
  int lane = t & 63, tile = t >> 6;
  int kc = tile / CT, ct = tile - kc * CT;
  int g = lane >> 4, lp = lane & 15;
  short8 v;
#pragma unroll
  for (int j = 0; j < 8; ++j)
    v[j] = f2bf(d.src[(size_t)(kc * 32 + g * 8 + j) * d.C + ct * 16 + lp]);
  *reinterpret_cast<short8*>(dstbase + d.dstoff + (size_t)t * 8) = v;
}

// ---------------------------------------------------------------------------
// MFMA fused 2-layer MLP: out = relu(X@W1+b1)@W2+b2 -> bf16 strided xbuf.
// 4 waves/block, 16 rows/wave, hidden=256. h round-trips per-wave LDS (bf16,
// XOR-swizzled). No __syncthreads (per-wave private LDS; DS in-order per wave).
// ---------------------------------------------------------------------------
template <int K, int O, bool XF32, bool GATHER>
__global__ __launch_bounds__(256) void mlp2_mfma_kernel(
    const void* __restrict__ Xv, const int* __restrict__ gidx,
    const short* __restrict__ W1f, const float* __restrict__ B1,
    const short* __restrict__ W2f, const float* __restrict__ B2,
    bf16* __restrict__ xbuf, int ooff, int ntiles) {
  constexpr int KC = K / 32;
  constexpr int KC2 = 8;       // 256/32
  constexpr int OT = O / 16;
  __shared__ short hbuf[4 * 16 * 256];  // 32 KB, per-wave 8 KB
  const int tid = threadIdx.x;
  const int lane = tid & 63, wid = tid >> 6;
  int tile = blockIdx.x * 4 + wid;
  if (tile >= ntiles) tile = ntiles - 1;   // dup work, benign same-value stores
  const int g = lane >> 4, lp = lane & 15;
  const int row0 = tile * 16;
  char* hw = (char*)(hbuf + wid * (16 * 256));

  // ---- A-fragments for L1 ----
  short8 a[KC];
  if (XF32) {
    const float* X = (const float*)Xv;
    int srow = GATHER ? gidx[row0 + lp] : (row0 + lp);
    const float* xp = X + (size_t)srow * K + g * 8;
#pragma unroll
    for (int kc = 0; kc < KC; ++kc) {
      f32x4 u0 = *reinterpret_cast<const f32x4*>(xp + kc * 32);
      f32x4 u1 = *reinterpret_cast<const f32x4*>(xp + kc * 32 + 4);
      short8 t;
#pragma unroll
      for (int j = 0; j < 4; ++j) { t[j] = f2bf(u0[j]); t[j + 4] = f2bf(u1[j]); }
      a[kc] = t;
    }
  } else {
    const bf16* X = (const bf16*)Xv;
    const bf16* xp = X + (size_t)(row0 + lp) * K + g * 8;
#pragma unroll
    for (int kc = 0; kc < KC; ++kc)
      a[kc] = *reinterpret_cast<const short8*>(xp + kc * 32);
  }

  // ---- L1: h = relu(X@W1+b1) -> LDS bf16 (swizzled) ----
#pragma unroll
  for (int ct = 0; ct < 16; ++ct) {
    float bv = B1[ct * 16 + lp];
    f32x4 acc = {bv, bv, bv, bv};
#pragma unroll
    for (int kc = 0; kc < KC; ++kc) {
      short8 b = *reinterpret_cast<const short8*>(
          W1f + ((size_t)(kc * 16 + ct) * 64 + lane) * 8);
      acc = __builtin_amdgcn_mfma_f32_16x16x32_bf16(a[kc], b, acc, 0, 0, 0);
    }
#pragma unroll
    for (int r = 0; r < 4; ++r) {
      int rr = g * 4 + r;  // D layout: row=(lane>>4)*4+r, col=ct*16+(lane&15)
      int byte = rr * 512 + (ct * 16 + lp) * 2;
      byte ^= (rr & 7) << 4;
      *reinterpret_cast<short*>(hw + byte) = f2bf(fmaxf(acc[r], 0.f));
    }
  }
  asm volatile("s_waitcnt lgkmcnt(0)" ::: "memory");
  __builtin_amdgcn_sched_barrier(0);

  // ---- L2: out = h@W2+b2 ----
  short8 a2[KC2];
#pragma unroll
  for (int kc = 0; kc < KC2; ++kc) {
    int byte = lp * 512 + (kc * 32 + g * 8) * 2;
    byte ^= (lp & 7) << 4;
    a2[kc] = *reinterpret_cast<const short8*>(hw + byte);
  }
#pragma unroll
  for (int ot = 0; ot < OT; ++ot) {
    float bv = B2[ot * 16 + lp];
    f32x4 acc = {bv, bv, bv, bv};
#pragma unroll
    for (int kc = 0; kc < KC2; ++kc) {
      short8 b = *reinterpret_cast<const short8*>(
          W2f + ((size_t)(kc * OT + ot) * 64 + lane) * 8);
      acc = __builtin_amdgcn_mfma_f32_16x16x32_bf16(a2[kc], b, acc, 0, 0, 0);
    }
#pragma unroll
    for (int r = 0; r < 4; ++r) {
      int rr = g * 4 + r;
      *reinterpret_cast<short*>(xbuf + (size_t)(row0 + rr) * 608 + ooff + ot * 16 + lp) =
          f2bf(acc[r]);
    }
  }
}

// ---------------------------------------------------------------------------
// Final combiner: L1 (608->256) bf16 MFMA; L2 (256->128) + L3 (128->128) f32
// VALU (precision: late-stage bf16 would blow the 2.56e-4 budget).
// 4 waves, 64 rows/block. h1 f32 in 64 KB LDS; h2 aliased in first 32 KB.
// ---------------------------------------------------------------------------
__global__ __launch_bounds__(256) void final_kernel(
    const bf16* __restrict__ xbuf,
    const short* __restrict__ Wc1f, const float* __restrict__ B1,
    const float* __restrict__ W2, const float* __restrict__ B2,
    const float* __restrict__ W3, const float* __restrict__ B3,
    float* __restrict__ out, int n) {
  __shared__ float lds[16384];  // 64 KB: h1[64][256]; h2[64][128] aliased low 32 KB
  const int tid = threadIdx.x;
  const int lane = tid & 63, wid = tid >> 6;
  const int g = lane >> 4, lp = lane & 15;
  const int row0b = blockIdx.x * 64;

  // ---- L1 MFMA: h1 = relu(x @ Wc1 + b1) ----
  {
    int arow = row0b + wid * 16 + lp;
    if (arow >= n) arow = n - 1;  // tail clamp (unstored dup)
    const bf16* xp = xbuf + (size_t)arow * 608 + g * 8;
    short8 a[19];
#pragma unroll
    for (int kc = 0; kc < 19; ++kc)
      a[kc] = *reinterpret_cast<const short8*>(xp + kc * 32);
    for (int ct = 0; ct < 16; ++ct) {
      float bv = B1[ct * 16 + lp];
      f32x4 acc = {bv, bv, bv, bv};
#pragma unroll
      for (int kc = 0; kc < 19; ++kc) {
        short8 b = *reinterpret_cast<const short8*>(
            Wc1f + ((size_t)(kc * 16 + ct) * 64 + lane) * 8);
        acc = __builtin_amdgcn_mfma_f32_16x16x32_bf16(a[kc], b, acc, 0, 0, 0);
      }
#pragma unroll
      for (int r = 0; r < 4; ++r) {
        int rr = wid * 16 + g * 4 + r;
        int byte = (rr << 10) + ((ct * 16 + lp) << 2);
        byte ^= (rr & 7) << 4;  // kill write bank-conflict; reads are broadcast
        *reinterpret_cast<float*>((char*)lds + byte) = fmaxf(acc[r], 0.f);
      }
    }
  }
  __syncthreads();

  const int half = lane >> 5;
  const int c = (lane & 31) * 4;
  const int rbase = wid * 16 + half * 8;  // block-local row base (8 rows/thread)

  // ---- L2 (f32): h2 = relu(h1 @ W2 + b2), kept in regs ----
  f32x4 acc2[8];
  {
    f32x4 bv = *reinterpret_cast<const f32x4*>(B2 + c);
#pragma unroll
    for (int rr = 0; rr < 8; ++rr) acc2[rr] = bv;
    for (int k0 = 0; k0 < 256; k0 += 4) {
      f32x4 w0 = *reinterpret_cast<const f32x4*>(W2 + (size_t)(k0 + 0) * 128 + c);
      f32x4 w1 = *reinterpret_cast<const f32x4*>(W2 + (size_t)(k0 + 1) * 128 + c);
      f32x4 w2v = *reinterpret_cast<const f32x4*>(W2 + (size_t)(k0 + 2) * 128 + c);
      f32x4 w3v = *reinterpret_cast<const f32x4*>(W2 + (size_t)(k0 + 3) * 128 + c);
#pragma unroll
      for (int rr = 0; rr < 8; ++rr) {
        int row = rbase + rr;
        int byte = (row << 10) + (k0 << 2);
        byte ^= (row & 7) << 4;
        f32x4 h = *reinterpret_cast<const f32x4*>((char*)lds + byte);
        acc2[rr] += h.x * w0 + h.y * w1 + h.z * w2v + h.w * w3v;
      }
    }
  }
  __syncthreads();  // all h1 reads done before h2 overwrites low 32 KB

  // ---- store h2 (relu) into aliased region ----
#pragma unroll
  for (int rr = 0; rr < 8; ++rr) {
    f32x4 v = acc2[rr];
#pragma unroll
    for (int j = 0; j < 4; ++j) v[j] = fmaxf(v[j], 0.f);
    *reinterpret_cast<f32x4*>((char*)lds + ((rbase + rr) << 9) + (c << 2)) = v;
  }
  __syncthreads();

  // ---- L3 (f32): out = h2 @ W3 + b3 ----
  {
    f32x4 acc3[8];
    f32x4 bv = *reinterpret_cast<const f32x4*>(B3 + c);
#pragma unroll
    for (int rr = 0; rr < 8; ++rr) acc3[rr] = bv;
    for (int k0 = 0; k0 < 128; k0 += 4) {
      f32x4 w0 = *reinterpret_cast<const f32x4*>(W3 + (size_t)(k0 + 0) * 128 + c);
      f32x4 w1 = *reinterpret_cast<const f32x4*>(W3 + (size_t)(k0 + 1) * 128 + c);
      f32x4 w2v = *reinterpret_cast<const f32x4*>(W3 + (size_t)(k0 + 2) * 128 + c);
      f32x4 w3v = *reinterpret_cast<const f32x4*>(W3 + (size_t)(k0 + 3) * 128 + c);
#pragma unroll
      for (int rr = 0; rr < 8; ++rr) {
        f32x4 h = *reinterpret_cast<const f32x4*>(
            (char*)lds + ((rbase + rr) << 9) + (k0 << 2));
        acc3[rr] += h.x * w0 + h.y * w1 + h.z * w2v + h.w * w3v;
      }
    }
#pragma unroll
    for (int rr = 0; rr < 8; ++rr) {
      int grow = row0b + rbase + rr;
      if (grow < n)
        *reinterpret_cast<f32x4*>(out + (size_t)grow * 128 + c) = acc3[rr];
    }
  }
}

// ---------------------------------------------------------------------------
// kernel_launch
// ---------------------------------------------------------------------------
extern "C" void kernel_launch(void* const* d_in, const int* in_sizes, int n_in,
                              void* d_out, int out_size, void* d_ws,
                              size_t ws_size, hipStream_t stream) {
  const float* operations = (const float*)d_in[0];
  const float* items      = (const float*)d_in[1];
  const float* materials  = (const float*)d_in[2];
  const float* resources  = (const float*)d_in[3];
  const int* related      = (const int*)d_in[4];
  const int* res_op       = (const int*)d_in[5];
  const int* res_res      = (const int*)d_in[6];
  const int* mat_op       = (const int*)d_in[7];
  const int* mat_mat      = (const int*)d_in[8];
  const int* prec_src     = (const int*)d_in[9];
  const int* prec_dst     = (const int*)d_in[10];
  const float* w_self1 = (const float*)d_in[11];
  const float* b_self1 = (const float*)d_in[12];
  const float* w_self2 = (const float*)d_in[13];
  const float* b_self2 = (const float*)d_in[14];
  const float* w_item1 = (const float*)d_in[15];
  const float* b_item1 = (const float*)d_in[16];
  const float* w_item2 = (const float*)d_in[17];
  const float* b_item2 = (const float*)d_in[18];
  const float* w_pred1 = (const float*)d_in[19];
  const float* b_pred1 = (const float*)d_in[20];
  const float* w_pred2 = (const float*)d_in[21];
  const float* b_pred2 = (const float*)d_in[22];
  const float* w_succ1 = (const float*)d_in[23];
  const float* b_succ1 = (const float*)d_in[24];
  const float* w_succ2 = (const float*)d_in[25];
  const float* b_succ2 = (const float*)d_in[26];
  const float* w_res1  = (const float*)d_in[27];
  const float* b_res1  = (const float*)d_in[28];
  const float* w_res2  = (const float*)d_in[29];
  const float* b_res2  = (const float*)d_in[30];
  const float* w_mat1  = (const float*)d_in[31];
  const float* b_mat1  = (const float*)d_in[32];
  const float* w_mat2  = (const float*)d_in[33];
  const float* b_mat2  = (const float*)d_in[34];
  const float* w_c1    = (const float*)d_in[35];
  const float* b_c1    = (const float*)d_in[36];
  const float* w_c2    = (const float*)d_in[37];
  const float* b_c2    = (const float*)d_in[38];
  const float* w_c3    = (const float*)d_in[39];
  const float* b_c3    = (const float*)d_in[40];

  const int N = in_sizes[0] / 128;   // 50000
  const int E_RES = in_sizes[5];
  const int E_MAT = in_sizes[7];
  const int E_PREC = in_sizes[9];

  // ---- ws layout (64-B aligned sections, ~106 MB total) ----
  size_t off = 0;
  auto take = [&](size_t bytes) {
    size_t o = off;
    off += (bytes + 63) & ~(size_t)63;
    return o;
  };
  size_t xbuf_off = take((size_t)N * 608 * 2);
  size_t aggp_off = take((size_t)N * 128 * 2);
  size_t aggsu_off = take((size_t)N * 128 * 2);
  size_t aggr_off = take((size_t)N * 64 * 2);
  size_t aggm_off = take((size_t)N * 32 * 2);
  size_t wf_off   = take((size_t)466944 * 2);
  size_t offs_off = take((size_t)4 * (N + 1) * 4);
  size_t tmp_off  = take((size_t)4 * N * 4);
  size_t cols_off = take(((size_t)2 * E_PREC + E_RES + E_MAT) * 4);

  char* ws = (char*)d_ws;
  bf16* xbuf = (bf16*)(ws + xbuf_off);
  bf16* agg_pred = (bf16*)(ws + aggp_off);
  bf16* agg_succ = (bf16*)(ws + aggsu_off);
  bf16* agg_res  = (bf16*)(ws + aggr_off);
  bf16* agg_mat  = (bf16*)(ws + aggm_off);
  short* wf = (short*)(ws + wf_off);
  int* offs = (int*)(ws + offs_off);
  int* tmp  = (int*)(ws + tmp_off);
  int* cols = (int*)(ws + cols_off);

  int* offs_pred = offs;
  int* offs_succ = offs + (N + 1);
  int* offs_res  = offs + 2 * (N + 1);
  int* offs_mat  = offs + 3 * (N + 1);
  int* cur_pred = tmp;
  int* cur_succ = tmp + N;
  int* cur_res  = tmp + 2 * N;
  int* cur_mat  = tmp + 3 * N;
  int* col_pred = cols;
  int* col_succ = col_pred + E_PREC;
  int* col_res  = col_succ + E_PREC;
  int* col_mat  = col_res + E_RES;

  dim3 blk(256);

  // ---- weight fragment conversion (13 matrices, one kernel) ----
  WDescs13 wd;
  wd.w[0]  = {w_self1, 128, 256, 0};
  wd.w[1]  = {w_item1, 128, 256, 32768};
  wd.w[2]  = {w_pred1, 128, 256, 65536};
  wd.w[3]  = {w_succ1, 128, 256, 98304};
  wd.w[4]  = {w_res1,   64, 256, 131072};
  wd.w[5]  = {w_mat1,   32, 256, 147456};
  wd.w[6]  = {w_self2, 256, 128, 155648};
  wd.w[7]  = {w_item2, 256, 128, 188416};
  wd.w[8]  = {w_pred2, 256, 128, 221184};
  wd.w[9]  = {w_succ2, 256, 128, 253952};
  wd.w[10] = {w_res2,  256,  64, 286720};
  wd.w[11] = {w_mat2,  256,  32, 303104};
  wd.w[12] = {w_c1,    608, 256, 311296};
  wconv_kernel<<<dim3(76, 13), blk, 0, stream>>>(wd, wf);

  // ---- CSR build ----
  hipMemsetAsync(tmp, 0, 4 * (size_t)N * sizeof(int), stream);
  count_kernel<<<(E_PREC + 255) / 256, blk, 0, stream>>>(prec_src, cur_pred, E_PREC);
  count_kernel<<<(E_PREC + 255) / 256, blk, 0, stream>>>(prec_dst, cur_succ, E_PREC);
  count_kernel<<<(E_RES + 255) / 256, blk, 0, stream>>>(res_op, cur_res, E_RES);
  count_kernel<<<(E_MAT + 255) / 256, blk, 0, stream>>>(mat_op, cur_mat, E_MAT);
  scan4_kernel<<<4, 1024, 0, stream>>>(tmp, offs, N);
  cursor_copy_kernel<<<(4 * N + 255) / 256, blk, 0, stream>>>(offs, tmp, N);
  fill_kernel<<<(E_PREC + 255) / 256, blk, 0, stream>>>(prec_src, prec_dst, cur_pred, col_pred, E_PREC);
  fill_kernel<<<(E_PREC + 255) / 256, blk, 0, stream>>>(prec_dst, prec_src, cur_succ, col_succ, E_PREC);
  fill_kernel<<<(E_RES + 255) / 256, blk, 0, stream>>>(res_op, res_res, cur_res, col_res, E_RES);
  fill_kernel<<<(E_MAT + 255) / 256, blk, 0, stream>>>(mat_op, mat_mat, cur_mat, col_mat, E_MAT);

  // ---- aggregate (bf16 out) ----
  csr_agg_kernel<128, 64><<<(N + 3) / 4, blk, 0, stream>>>(operations, col_pred, offs_pred, agg_pred, N);
  csr_agg_kernel<128, 64><<<(N + 3) / 4, blk, 0, stream>>>(operations, col_succ, offs_succ, agg_succ, N);
  csr_agg_kernel<64, 32><<<(N + 7) / 8, blk, 0, stream>>>(resources, col_res, offs_res, agg_res, N);
  csr_agg_kernel<32, 16><<<(N + 15) / 16, blk, 0, stream>>>(materials, col_mat, offs_mat, agg_mat, N);

  // ---- per-node MLPs (MFMA) -> bf16 concat buffer ----
  int ntiles = N / 16;               // 3125 (N % 16 == 0)
  int mgrid = (ntiles + 3) / 4;      // 782
  mlp2_mfma_kernel<128, 128, false, false><<<mgrid, blk, 0, stream>>>(
      agg_pred, nullptr, wf + 65536, b_pred1, wf + 221184, b_pred2, xbuf, 0, ntiles);
  mlp2_mfma_kernel<128, 128, false, false><<<mgrid, blk, 0, stream>>>(
      agg_succ, nullptr, wf + 98304, b_succ1, wf + 253952, b_succ2, xbuf, 128, ntiles);
  mlp2_mfma_kernel<64, 64, false, false><<<mgrid, blk, 0, stream>>>(
      agg_res, nullptr, wf + 131072, b_res1, wf + 286720, b_res2, xbuf, 256, ntiles);
  mlp2_mfma_kernel<32, 32, false, false><<<mgrid, blk, 0, stream>>>(
      agg_mat, nullptr, wf + 147456, b_mat1, wf + 303104, b_mat2, xbuf, 320, ntiles);
  mlp2_mfma_kernel<128, 128, true, true><<<mgrid, blk, 0, stream>>>(
      items, related, wf + 32768, b_item1, wf + 188416, b_item2, xbuf, 352, ntiles);
  mlp2_mfma_kernel<128, 128, true, false><<<mgrid, blk, 0, stream>>>(
      operations, nullptr, wf + 0, b_self1, wf + 155648, b_self2, xbuf, 480, ntiles);

  // ---- final combiner ----
  final_kernel<<<(N + 63) / 64, blk, 0, stream>>>(
      xbuf, wf + 311296, b_c1, w_c2, b_c2, w_c3, b_c3, (float*)d_out, N);
}

// Round 4
// 642.629 us; speedup vs baseline: 6.8073x; 1.1402x over previous
//
#include <hip/hip_runtime.h>
#include <hip/hip_bf16.h>

typedef __attribute__((ext_vector_type(8))) short short8;
typedef __attribute__((ext_vector_type(4))) float f32x4;
using bf16 = __hip_bfloat16;

// N=50000, OP=128, H=256, H2=128, OUT=128
// xbuf concat: [pred 0 | succ 128 | res 256 | mat 320 | item 352 | self 480], 608

__device__ __forceinline__ short f2bf(float f) {
  union { float f; unsigned u; } v; v.f = f;
  unsigned r = (v.u + 0x7fffu + ((v.u >> 16) & 1u)) >> 16;  // RNE
  return (short)r;
}
__device__ __forceinline__ float bf2f(short s) {
  union { unsigned u; float f; } x;
  x.u = ((unsigned)(unsigned short)s) << 16;
  return x.f;
}

// ---------------------------------------------------------------------------
// f32 -> bf16 table conversion
// ---------------------------------------------------------------------------
__global__ __launch_bounds__(256) void cvt_bf16_kernel(
    const float* __restrict__ src, bf16* __restrict__ dst, int n4) {
  int i = blockIdx.x * 256 + threadIdx.x;
  if (i >= n4) return;
  f32x4 v = *reinterpret_cast<const f32x4*>(src + (size_t)i * 4);
  uint2 u;
  u.x = (unsigned)(unsigned short)f2bf(v.x) | ((unsigned)(unsigned short)f2bf(v.y) << 16);
  u.y = (unsigned)(unsigned short)f2bf(v.z) | ((unsigned)(unsigned short)f2bf(v.w) << 16);
  *reinterpret_cast<uint2*>(dst + (size_t)i * 4) = u;
}

// ---------------------------------------------------------------------------
// CSR build: merged count / scan / cursor / merged fill
// ---------------------------------------------------------------------------
struct EdgeList { const int* dst; const int* src; int* counts; int* col; int E; };
struct EdgeLists4 { EdgeList l[4]; };

__global__ __launch_bounds__(256) void count4_kernel(EdgeLists4 ls) {
  EdgeList l = ls.l[blockIdx.y];
  int e = blockIdx.x * 256 + threadIdx.x;
  if (e < l.E) atomicAdd(&l.counts[l.dst[e]], 1);
}

__global__ __launch_bounds__(1024) void scan4_kernel(
    const int* __restrict__ counts, int* __restrict__ offsets, int n) {
  const int* cnt = counts + (size_t)blockIdx.x * n;
  int* offs = offsets + (size_t)blockIdx.x * (n + 1);
  __shared__ int wsum[16];
  __shared__ int carry_s;
  const int lane = threadIdx.x & 63;
  const int wid = threadIdx.x >> 6;
  if (threadIdx.x == 0) carry_s = 0;
  __syncthreads();
  for (int base = 0; base < n; base += 1024) {
    int i = base + threadIdx.x;
    int v = (i < n) ? cnt[i] : 0;
    int x = v;
#pragma unroll
    for (int off = 1; off < 64; off <<= 1) {
      int t = __shfl_up(x, off, 64);
      if (lane >= off) x += t;
    }
    if (lane == 63) wsum[wid] = x;
    __syncthreads();
    if (wid == 0 && lane < 16) {
      int w = wsum[lane];
#pragma unroll
      for (int off = 1; off < 16; off <<= 1) {
        int t = __shfl_up(w, off, 16);
        if (lane >= off) w += t;
      }
      wsum[lane] = w;
    }
    __syncthreads();
    int carry = carry_s;
    int wpre = (wid == 0) ? 0 : wsum[wid - 1];
    if (i < n) offs[i] = carry + wpre + x - v;
    __syncthreads();
    if (threadIdx.x == 1023) carry_s = carry + wsum[15];
    __syncthreads();
  }
  if (threadIdx.x == 0) offs[n] = carry_s;
}

__global__ __launch_bounds__(256) void cursor_copy_kernel(
    const int* __restrict__ offsets, int* __restrict__ cursor, int n) {
  int i = blockIdx.x * 256 + threadIdx.x;
  if (i < 4 * n) {
    int t = i / n, j = i - t * n;
    cursor[(size_t)t * n + j] = offsets[(size_t)t * (n + 1) + j];
  }
}

__global__ __launch_bounds__(256) void fill4_kernel(EdgeLists4 ls) {
  EdgeList l = ls.l[blockIdx.y];
  int e = blockIdx.x * 256 + threadIdx.x;
  if (e < l.E) {
    int p = atomicAdd(&l.counts[l.dst[e]], 1);  // counts == cursor at this stage
    l.col[p] = l.src[e];
  }
}

// ---------------------------------------------------------------------------
// Pred/succ aggregate from bf16 ops table: 1 wave/row, 4 edges/iter, 16B/lane.
// ---------------------------------------------------------------------------
__global__ __launch_bounds__(256) void csr_agg128_kernel(
    const bf16* __restrict__ tab,
    const int* __restrict__ col0, const int* __restrict__ col1,
    const int* __restrict__ offs0, const int* __restrict__ offs1,
    bf16* __restrict__ out0, bf16* __restrict__ out1, int n) {
  const int* col = blockIdx.y ? col1 : col0;
  const int* offs = blockIdx.y ? offs1 : offs0;
  bf16* out = blockIdx.y ? out1 : out0;
  const int lane = threadIdx.x & 63;
  const int wid = threadIdx.x >> 6;
  const int r = blockIdx.x * 4 + wid;
  if (r >= n) return;
  const int slot = lane >> 4, lp = lane & 15;
  const int beg = offs[r], end = offs[r + 1];
  float acc[8] = {0.f, 0.f, 0.f, 0.f, 0.f, 0.f, 0.f, 0.f};
  for (int e = beg; e < end; e += 4) {
    int idx = e + slot;
    if (idx < end) {
      int cc = col[idx];
      short8 v = *reinterpret_cast<const short8*>(tab + (size_t)cc * 128 + lp * 8);
#pragma unroll
      for (int j = 0; j < 8; ++j) acc[j] += bf2f(v[j]);
    }
  }
#pragma unroll
  for (int j = 0; j < 8; ++j) {
    acc[j] += __shfl_xor(acc[j], 16, 64);
    acc[j] += __shfl_xor(acc[j], 32, 64);
  }
  if (slot == 0) {
    short8 sv;
#pragma unroll
    for (int j = 0; j < 8; ++j) sv[j] = f2bf(acc[j]);
    *reinterpret_cast<short8*>(out + (size_t)r * 128 + lp * 8) = sv;
  }
}

// ---------------------------------------------------------------------------
// Small CSR aggregate (res/mat) from f32 tables -> bf16 out
// ---------------------------------------------------------------------------
template <int D, int LPR>
__global__ __launch_bounds__(256) void csr_agg_kernel(
    const float* __restrict__ tab, const int* __restrict__ col,
    const int* __restrict__ offsets, bf16* __restrict__ out, int n) {
  constexpr int RPB = 256 / LPR;
  const int lane = threadIdx.x % LPR;
  const int r = blockIdx.x * RPB + threadIdx.x / LPR;
  if (r >= n) return;
  const int beg = offsets[r], end = offsets[r + 1];
  float2 acc = make_float2(0.f, 0.f);
  for (int e = beg; e < end; ++e) {
    int s = col[e];
    float2 v = *reinterpret_cast<const float2*>(tab + (size_t)s * D + lane * 2);
    acc.x += v.x;
    acc.y += v.y;
  }
  unsigned u = (unsigned)(unsigned short)f2bf(acc.x) |
               ((unsigned)(unsigned short)f2bf(acc.y) << 16);
  *reinterpret_cast<unsigned*>(out + (size_t)r * D + lane * 2) = u;
}

// ---------------------------------------------------------------------------
// Weight -> MFMA B-fragment conversion
// frag[tile=kc*CT+ct][lane][j] = W[kc*32+(lane>>4)*8+j][ct*16+(lane&15)]
// ---------------------------------------------------------------------------
struct WDesc { const float* src; int K; int C; int dstoff; };
struct WDescs14 { WDesc w[14]; };

__global__ __launch_bounds__(256) void wconv_kernel(WDescs14 ds, short* __restrict__ dstbase) {
  WDesc d = ds.w[blockIdx.y];
  int KC = d.K >> 5, CT = d.C >> 4;
  int t = blockIdx.x * 256 + threadIdx.x;
  if (t >= KC * CT * 64) return;
  int lane = t & 63, tile = t >> 6;
  int kc = tile / CT, ct = tile - kc * CT;
  int g = lane >> 4, lp = lane & 15;
  short8 v;
#pragma unroll
  for (int j = 0; j < 8; ++j)
    v[j] = f2bf(d.src[(size_t)(kc * 32 + g * 8 + j) * d.C + ct * 16 + lp]);
  *reinterpret_cast<short8*>(dstbase + d.dstoff + (size_t)t * 8) = v;
}

// ---------------------------------------------------------------------------
// MFMA fused 2-layer MLP device body (bf16 in, bf16 out, wave-private LDS)
// ---------------------------------------------------------------------------
template <int K, int O, bool GATHER>
__device__ __forceinline__ void mlp2_dev(
    const bf16* __restrict__ X, const int* __restrict__ gidx,
    const short* __restrict__ W1f, const float* __restrict__ B1,
    const short* __restrict__ W2f, const float* __restrict__ B2,
    bf16* __restrict__ xbuf, int ooff, int tile, int lane, char* hw) {
  constexpr int KC = K / 32;
  constexpr int KC2 = 8;
  constexpr int OT = O / 16;
  const int g = lane >> 4, lp = lane & 15;
  const int row0 = tile * 16;

  short8 a[KC];
  {
    int srow = GATHER ? gidx[row0 + lp] : (row0 + lp);
    const bf16* xp = X + (size_t)srow * K + g * 8;
#pragma unroll
    for (int kc = 0; kc < KC; ++kc)
      a[kc] = *reinterpret_cast<const short8*>(xp + kc * 32);
  }

#pragma unroll
  for (int ct = 0; ct < 16; ++ct) {
    float bv = B1[ct * 16 + lp];
    f32x4 acc = {bv, bv, bv, bv};
#pragma unroll
    for (int kc = 0; kc < KC; ++kc) {
      short8 b = *reinterpret_cast<const short8*>(
          W1f + ((size_t)(kc * 16 + ct) * 64 + lane) * 8);
      acc = __builtin_amdgcn_mfma_f32_16x16x32_bf16(a[kc], b, acc, 0, 0, 0);
    }
#pragma unroll
    for (int r = 0; r < 4; ++r) {
      int rr = g * 4 + r;
      int byte = rr * 512 + (ct * 16 + lp) * 2;
      byte ^= (rr & 7) << 4;
      *reinterpret_cast<short*>(hw + byte) = f2bf(fmaxf(acc[r], 0.f));
    }
  }
  asm volatile("s_waitcnt lgkmcnt(0)" ::: "memory");
  __builtin_amdgcn_sched_barrier(0);

  short8 a2[KC2];
#pragma unroll
  for (int kc = 0; kc < KC2; ++kc) {
    int byte = lp * 512 + (kc * 32 + g * 8) * 2;
    byte ^= (lp & 7) << 4;
    a2[kc] = *reinterpret_cast<const short8*>(hw + byte);
  }
#pragma unroll
  for (int ot = 0; ot < OT; ++ot) {
    float bv = B2[ot * 16 + lp];
    f32x4 acc = {bv, bv, bv, bv};
#pragma unroll
    for (int kc = 0; kc < KC2; ++kc) {
      short8 b = *reinterpret_cast<const short8*>(
          W2f + ((size_t)(kc * OT + ot) * 64 + lane) * 8);
      acc = __builtin_amdgcn_mfma_f32_16x16x32_bf16(a2[kc], b, acc, 0, 0, 0);
    }
#pragma unroll
    for (int r = 0; r < 4; ++r) {
      int rr = g * 4 + r;
      *reinterpret_cast<short*>(xbuf + (size_t)(row0 + rr) * 608 + ooff + ot * 16 + lp) =
          f2bf(acc[r]);
    }
  }
}

struct Mlp6Args {
  const bf16 *agg_pred, *agg_succ, *agg_res, *agg_mat, *items_bf, *ops_bf;
  const int* related;
  const short* wf;
  const float *b_pred1, *b_pred2, *b_succ1, *b_succ2, *b_res1, *b_res2;
  const float *b_mat1, *b_mat2, *b_item1, *b_item2, *b_self1, *b_self2;
  bf16* xbuf;
  int ntiles;
};

__global__ __launch_bounds__(256) void mlp6_kernel(Mlp6Args A) {
  __shared__ short hbuf[4 * 16 * 256];  // 32 KB, 8 KB/wave
  const int lane = threadIdx.x & 63, wid = threadIdx.x >> 6;
  int tile = blockIdx.x * 4 + wid;
  if (tile >= A.ntiles) tile = A.ntiles - 1;  // dup benign
  char* hw = (char*)(hbuf + wid * (16 * 256));
  const short* wf = A.wf;
  switch (blockIdx.y) {
    case 0: mlp2_dev<128, 128, false>(A.agg_pred, nullptr, wf + 65536, A.b_pred1,
                                      wf + 221184, A.b_pred2, A.xbuf, 0, tile, lane, hw); break;
    case 1: mlp2_dev<128, 128, false>(A.agg_succ, nullptr, wf + 98304, A.b_succ1,
                                      wf + 253952, A.b_succ2, A.xbuf, 128, tile, lane, hw); break;
    case 2: mlp2_dev<64, 64, false>(A.agg_res, nullptr, wf + 131072, A.b_res1,
                                    wf + 286720, A.b_res2, A.xbuf, 256, tile, lane, hw); break;
    case 3: mlp2_dev<32, 32, false>(A.agg_mat, nullptr, wf + 147456, A.b_mat1,
                                    wf + 303104, A.b_mat2, A.xbuf, 320, tile, lane, hw); break;
    case 4: mlp2_dev<128, 128, true>(A.items_bf, A.related, wf + 32768, A.b_item1,
                                     wf + 188416, A.b_item2, A.xbuf, 352, tile, lane, hw); break;
    default: mlp2_dev<128, 128, false>(A.ops_bf, nullptr, wf + 0, A.b_self1,
                                       wf + 155648, A.b_self2, A.xbuf, 480, tile, lane, hw); break;
  }
}

// ---------------------------------------------------------------------------
// Final combiner v2: L1 608->256 MFMA (h1 bf16, wave-private swizzled LDS),
// L2 256->128 MFMA (h2 f32 in aliased LDS), L3 128->128 f32 VALU.
// Zero block-level syncs; 32 KB LDS.
// ---------------------------------------------------------------------------
__global__ __launch_bounds__(256, 4) void final_kernel(
    const bf16* __restrict__ xbuf,
    const short* __restrict__ Wc1f, const float* __restrict__ B1,
    const short* __restrict__ Wc2f, const float* __restrict__ B2,
    const float* __restrict__ W3, const float* __restrict__ B3,
    float* __restrict__ out, int ntiles) {
  __shared__ short hbuf[4 * 16 * 256];  // 32 KB: per-wave h1 bf16, then h2 f32 aliased
  const int lane = threadIdx.x & 63, wid = threadIdx.x >> 6;
  int tile = blockIdx.x * 4 + wid;
  if (tile >= ntiles) tile = ntiles - 1;
  const int g = lane >> 4, lp = lane & 15;
  const int row0 = tile * 16;
  char* hw = (char*)(hbuf + wid * (16 * 256));

  // ---- L1: h1 = relu(x @ Wc1 + b1), 608->256, MFMA ----
  {
    const bf16* xp = xbuf + (size_t)(row0 + lp) * 608 + g * 8;
    short8 a[19];
#pragma unroll
    for (int kc = 0; kc < 19; ++kc)
      a[kc] = *reinterpret_cast<const short8*>(xp + kc * 32);
#pragma unroll
    for (int ct = 0; ct < 16; ++ct) {
      float bv = B1[ct * 16 + lp];
      f32x4 acc = {bv, bv, bv, bv};
#pragma unroll
      for (int kc = 0; kc < 19; ++kc) {
        short8 b = *reinterpret_cast<const short8*>(
            Wc1f + ((size_t)(kc * 16 + ct) * 64 + lane) * 8);
        acc = __builtin_amdgcn_mfma_f32_16x16x32_bf16(a[kc], b, acc, 0, 0, 0);
      }
#pragma unroll
      for (int r = 0; r < 4; ++r) {
        int rr = g * 4 + r;
        int byte = rr * 512 + (ct * 16 + lp) * 2;
        byte ^= (rr & 7) << 4;
        *reinterpret_cast<short*>(hw + byte) = f2bf(fmaxf(acc[r], 0.f));
      }
    }
  }
  asm volatile("s_waitcnt lgkmcnt(0)" ::: "memory");
  __builtin_amdgcn_sched_barrier(0);

  // ---- L2: h2 = relu(h1 @ Wc2 + b2), 256->128, MFMA ----
  {
    short8 a2[8];
#pragma unroll
    for (int kc = 0; kc < 8; ++kc) {
      int byte = lp * 512 + (kc * 32 + g * 8) * 2;
      byte ^= (lp & 7) << 4;
      a2[kc] = *reinterpret_cast<const short8*>(hw + byte);
    }
    asm volatile("s_waitcnt lgkmcnt(0)" ::: "memory");
    __builtin_amdgcn_sched_barrier(0);
    float* h2 = (float*)hw;  // alias over h1 (a2 fully in regs)
#pragma unroll
    for (int ot = 0; ot < 8; ++ot) {
      float bv = B2[ot * 16 + lp];
      f32x4 acc = {bv, bv, bv, bv};
#pragma unroll
      for (int kc = 0; kc < 8; ++kc) {
        short8 b = *reinterpret_cast<const short8*>(
            Wc2f + ((size_t)(kc * 8 + ot) * 64 + lane) * 8);
        acc = __builtin_amdgcn_mfma_f32_16x16x32_bf16(a2[kc], b, acc, 0, 0, 0);
      }
#pragma unroll
      for (int r = 0; r < 4; ++r)
        h2[(g * 4 + r) * 128 + ot * 16 + lp] = fmaxf(acc[r], 0.f);
    }
  }
  asm volatile("s_waitcnt lgkmcnt(0)" ::: "memory");
  __builtin_amdgcn_sched_barrier(0);

  // ---- L3: out = h2 @ W3 + b3, f32 VALU (precision-critical) ----
  {
    const float* h2 = (const float*)hw;
    const int half = lane >> 5;
    const int c = (lane & 31) * 4;
    const int rbase = half * 8;
    f32x4 acc3[8];
    f32x4 bv = *reinterpret_cast<const f32x4*>(B3 + c);
#pragma unroll
    for (int rr = 0; rr < 8; ++rr) acc3[rr] = bv;
    for (int k0 = 0; k0 < 128; k0 += 4) {
      f32x4 w0 = *reinterpret_cast<const f32x4*>(W3 + (size_t)(k0 + 0) * 128 + c);
      f32x4 w1 = *reinterpret_cast<const f32x4*>(W3 + (size_t)(k0 + 1) * 128 + c);
      f32x4 w2v = *reinterpret_cast<const f32x4*>(W3 + (size_t)(k0 + 2) * 128 + c);
      f32x4 w3v = *reinterpret_cast<const f32x4*>(W3 + (size_t)(k0 + 3) * 128 + c);
#pragma unroll
      for (int rr = 0; rr < 8; ++rr) {
        f32x4 h = *reinterpret_cast<const f32x4*>(&h2[(rbase + rr) * 128 + k0]);
        acc3[rr] += h.x * w0 + h.y * w1 + h.z * w2v + h.w * w3v;
      }
    }
#pragma unroll
    for (int rr = 0; rr < 8; ++rr)
      *reinterpret_cast<f32x4*>(out + (size_t)(row0 + rbase + rr) * 128 + c) = acc3[rr];
  }
}

// ---------------------------------------------------------------------------
// kernel_launch
// ---------------------------------------------------------------------------
extern "C" void kernel_launch(void* const* d_in, const int* in_sizes, int n_in,
                              void* d_out, int out_size, void* d_ws,
                              size_t ws_size, hipStream_t stream) {
  const float* operations = (const float*)d_in[0];
  const float* items      = (const float*)d_in[1];
  const float* materials  = (const float*)d_in[2];
  const float* resources  = (const float*)d_in[3];
  const int* related      = (const int*)d_in[4];
  const int* res_op       = (const int*)d_in[5];
  const int* res_res      = (const int*)d_in[6];
  const int* mat_op       = (const int*)d_in[7];
  const int* mat_mat      = (const int*)d_in[8];
  const int* prec_src     = (const int*)d_in[9];
  const int* prec_dst     = (const int*)d_in[10];
  const float* w_self1 = (const float*)d_in[11];
  const float* b_self1 = (const float*)d_in[12];
  const float* w_self2 = (const float*)d_in[13];
  const float* b_self2 = (const float*)d_in[14];
  const float* w_item1 = (const float*)d_in[15];
  const float* b_item1 = (const float*)d_in[16];
  const float* w_item2 = (const float*)d_in[17];
  const float* b_item2 = (const float*)d_in[18];
  const float* w_pred1 = (const float*)d_in[19];
  const float* b_pred1 = (const float*)d_in[20];
  const float* w_pred2 = (const float*)d_in[21];
  const float* b_pred2 = (const float*)d_in[22];
  const float* w_succ1 = (const float*)d_in[23];
  const float* b_succ1 = (const float*)d_in[24];
  const float* w_succ2 = (const float*)d_in[25];
  const float* b_succ2 = (const float*)d_in[26];
  const float* w_res1  = (const float*)d_in[27];
  const float* b_res1  = (const float*)d_in[28];
  const float* w_res2  = (const float*)d_in[29];
  const float* b_res2  = (const float*)d_in[30];
  const float* w_mat1  = (const float*)d_in[31];
  const float* b_mat1  = (const float*)d_in[32];
  const float* w_mat2  = (const float*)d_in[33];
  const float* b_mat2  = (const float*)d_in[34];
  const float* w_c1    = (const float*)d_in[35];
  const float* b_c1    = (const float*)d_in[36];
  const float* w_c2    = (const float*)d_in[37];
  const float* b_c2    = (const float*)d_in[38];
  const float* w_c3    = (const float*)d_in[39];
  const float* b_c3    = (const float*)d_in[40];

  const int N = in_sizes[0] / 128;   // 50000
  const int NI = in_sizes[1] / 128;  // 20000
  const int E_RES = in_sizes[5];
  const int E_MAT = in_sizes[7];
  const int E_PREC = in_sizes[9];

  // ---- ws layout ----
  size_t off = 0;
  auto take = [&](size_t bytes) {
    size_t o = off;
    off += (bytes + 63) & ~(size_t)63;
    return o;
  };
  size_t xbuf_off  = take((size_t)N * 608 * 2);
  size_t aggp_off  = take((size_t)N * 128 * 2);
  size_t aggsu_off = take((size_t)N * 128 * 2);
  size_t aggr_off  = take((size_t)N * 64 * 2);
  size_t aggm_off  = take((size_t)N * 32 * 2);
  size_t wf_off    = take((size_t)499712 * 2);
  size_t opsb_off  = take((size_t)N * 128 * 2);
  size_t itemb_off = take((size_t)NI * 128 * 2);
  size_t offs_off  = take((size_t)4 * (N + 1) * 4);
  size_t tmp_off   = take((size_t)4 * N * 4);
  size_t cols_off  = take(((size_t)2 * E_PREC + E_RES + E_MAT) * 4);

  char* ws = (char*)d_ws;
  bf16* xbuf = (bf16*)(ws + xbuf_off);
  bf16* agg_pred = (bf16*)(ws + aggp_off);
  bf16* agg_succ = (bf16*)(ws + aggsu_off);
  bf16* agg_res  = (bf16*)(ws + aggr_off);
  bf16* agg_mat  = (bf16*)(ws + aggm_off);
  short* wf = (short*)(ws + wf_off);
  bf16* ops_bf   = (bf16*)(ws + opsb_off);
  bf16* items_bf = (bf16*)(ws + itemb_off);
  int* offs = (int*)(ws + offs_off);
  int* tmp  = (int*)(ws + tmp_off);
  int* cols = (int*)(ws + cols_off);

  int* offs_pred = offs;
  int* offs_succ = offs + (N + 1);
  int* offs_res  = offs + 2 * (N + 1);
  int* offs_mat  = offs + 3 * (N + 1);
  int* cur_pred = tmp;
  int* cur_succ = tmp + N;
  int* cur_res  = tmp + 2 * N;
  int* cur_mat  = tmp + 3 * N;
  int* col_pred = cols;
  int* col_succ = col_pred + E_PREC;
  int* col_res  = col_succ + E_PREC;
  int* col_mat  = col_res + E_RES;

  dim3 blk(256);

  // ---- bf16 tables ----
  cvt_bf16_kernel<<<(N * 128 / 4 + 255) / 256, blk, 0, stream>>>(operations, ops_bf, N * 128 / 4);
  cvt_bf16_kernel<<<(NI * 128 / 4 + 255) / 256, blk, 0, stream>>>(items, items_bf, NI * 128 / 4);

  // ---- weight fragments ----
  WDescs14 wd;
  wd.w[0]  = {w_self1, 128, 256, 0};
  wd.w[1]  = {w_item1, 128, 256, 32768};
  wd.w[2]  = {w_pred1, 128, 256, 65536};
  wd.w[3]  = {w_succ1, 128, 256, 98304};
  wd.w[4]  = {w_res1,   64, 256, 131072};
  wd.w[5]  = {w_mat1,   32, 256, 147456};
  wd.w[6]  = {w_self2, 256, 128, 155648};
  wd.w[7]  = {w_item2, 256, 128, 188416};
  wd.w[8]  = {w_pred2, 256, 128, 221184};
  wd.w[9]  = {w_succ2, 256, 128, 253952};
  wd.w[10] = {w_res2,  256,  64, 286720};
  wd.w[11] = {w_mat2,  256,  32, 303104};
  wd.w[12] = {w_c1,    608, 256, 311296};
  wd.w[13] = {w_c2,    256, 128, 466944};
  wconv_kernel<<<dim3(76, 14), blk, 0, stream>>>(wd, wf);

  // ---- CSR build ----
  hipMemsetAsync(tmp, 0, 4 * (size_t)N * sizeof(int), stream);
  EdgeLists4 els;
  els.l[0] = {prec_src, prec_dst, cur_pred, col_pred, E_PREC};
  els.l[1] = {prec_dst, prec_src, cur_succ, col_succ, E_PREC};
  els.l[2] = {res_op, res_res, cur_res, col_res, E_RES};
  els.l[3] = {mat_op, mat_mat, cur_mat, col_mat, E_MAT};
  int cgx = (E_PREC + 255) / 256;
  count4_kernel<<<dim3(cgx, 4), blk, 0, stream>>>(els);
  scan4_kernel<<<4, 1024, 0, stream>>>(tmp, offs, N);
  cursor_copy_kernel<<<(4 * N + 255) / 256, blk, 0, stream>>>(offs, tmp, N);
  fill4_kernel<<<dim3(cgx, 4), blk, 0, stream>>>(els);

  // ---- aggregates ----
  csr_agg128_kernel<<<dim3((N + 3) / 4, 2), blk, 0, stream>>>(
      ops_bf, col_pred, col_succ, offs_pred, offs_succ, agg_pred, agg_succ, N);
  csr_agg_kernel<64, 32><<<(N + 7) / 8, blk, 0, stream>>>(resources, col_res, offs_res, agg_res, N);
  csr_agg_kernel<32, 16><<<(N + 15) / 16, blk, 0, stream>>>(materials, col_mat, offs_mat, agg_mat, N);

  // ---- 6 MLPs in one launch ----
  int ntiles = N / 16;           // 3125
  int mgrid = (ntiles + 3) / 4;  // 782
  Mlp6Args ma;
  ma.agg_pred = agg_pred; ma.agg_succ = agg_succ; ma.agg_res = agg_res; ma.agg_mat = agg_mat;
  ma.items_bf = items_bf; ma.ops_bf = ops_bf; ma.related = related; ma.wf = wf;
  ma.b_pred1 = b_pred1; ma.b_pred2 = b_pred2; ma.b_succ1 = b_succ1; ma.b_succ2 = b_succ2;
  ma.b_res1 = b_res1; ma.b_res2 = b_res2; ma.b_mat1 = b_mat1; ma.b_mat2 = b_mat2;
  ma.b_item1 = b_item1; ma.b_item2 = b_item2; ma.b_self1 = b_self1; ma.b_self2 = b_self2;
  ma.xbuf = xbuf; ma.ntiles = ntiles;
  mlp6_kernel<<<dim3(mgrid, 6), blk, 0, stream>>>(ma);

  // ---- final combiner ----
  final_kernel<<<mgrid, blk, 0, stream>>>(
      xbuf, wf + 311296, b_c1, wf + 466944, b_c2, w_c3, b_c3, (float*)d_out, ntiles);
}

// Round 8
// 636.134 us; speedup vs baseline: 6.8768x; 1.0102x over previous
//
#include <hip/hip_runtime.h>
#include <hip/hip_bf16.h>

typedef __attribute__((ext_vector_type(8))) short short8;
typedef __attribute__((ext_vector_type(4))) float f32x4;
using bf16 = __hip_bfloat16;

// N=50000, OP=128, H=256, H2=128, OUT=128
// xbuf concat: [pred 0 | succ 128 | res 256 | mat 320 | item 352 | self 480], 608

__device__ __forceinline__ short f2bf(float f) {
  union { float f; unsigned u; } v; v.f = f;
  unsigned r = (v.u + 0x7fffu + ((v.u >> 16) & 1u)) >> 16;  // RNE
  return (short)r;
}
__device__ __forceinline__ float bf2f(short s) {
  union { unsigned u; float f; } x;
  x.u = ((unsigned)(unsigned short)s) << 16;
  return x.f;
}

// ---------------------------------------------------------------------------
// f32 -> bf16 table conversion
// ---------------------------------------------------------------------------
__global__ __launch_bounds__(256) void cvt_bf16_kernel(
    const float* __restrict__ src, bf16* __restrict__ dst, int n4) {
  int i = blockIdx.x * 256 + threadIdx.x;
  if (i >= n4) return;
  f32x4 v = *reinterpret_cast<const f32x4*>(src + (size_t)i * 4);
  uint2 u;
  u.x = (unsigned)(unsigned short)f2bf(v.x) | ((unsigned)(unsigned short)f2bf(v.y) << 16);
  u.y = (unsigned)(unsigned short)f2bf(v.z) | ((unsigned)(unsigned short)f2bf(v.w) << 16);
  *reinterpret_cast<uint2*>(dst + (size_t)i * 4) = u;
}

// ---------------------------------------------------------------------------
// CSR build: merged count / scan / cursor / merged fill
// ---------------------------------------------------------------------------
struct EdgeList { const int* dst; const int* src; int* counts; int* col; int E; };
struct EdgeLists4 { EdgeList l[4]; };

__global__ __launch_bounds__(256) void count4_kernel(EdgeLists4 ls) {
  EdgeList l = ls.l[blockIdx.y];
  int e = blockIdx.x * 256 + threadIdx.x;
  if (e < l.E) atomicAdd(&l.counts[l.dst[e]], 1);
}

__global__ __launch_bounds__(1024) void scan4_kernel(
    const int* __restrict__ counts, int* __restrict__ offsets, int n) {
  const int* cnt = counts + (size_t)blockIdx.x * n;
  int* offs = offsets + (size_t)blockIdx.x * (n + 1);
  __shared__ int wsum[16];
  __shared__ int carry_s;
  const int lane = threadIdx.x & 63;
  const int wid = threadIdx.x >> 6;
  if (threadIdx.x == 0) carry_s = 0;
  __syncthreads();
  for (int base = 0; base < n; base += 1024) {
    int i = base + threadIdx.x;
    int v = (i < n) ? cnt[i] : 0;
    int x = v;
#pragma unroll
    for (int off = 1; off < 64; off <<= 1) {
      int t = __shfl_up(x, off, 64);
      if (lane >= off) x += t;
    }
    if (lane == 63) wsum[wid] = x;
    __syncthreads();
    if (wid == 0 && lane < 16) {
      int w = wsum[lane];
#pragma unroll
      for (int off = 1; off < 16; off <<= 1) {
        int t = __shfl_up(w, off, 16);
        if (lane >= off) w += t;
      }
      wsum[lane] = w;
    }
    __syncthreads();
    int carry = carry_s;
    int wpre = (wid == 0) ? 0 : wsum[wid - 1];
    if (i < n) offs[i] = carry + wpre + x - v;
    __syncthreads();
    if (threadIdx.x == 1023) carry_s = carry + wsum[15];
    __syncthreads();
  }
  if (threadIdx.x == 0) offs[n] = carry_s;
}

__global__ __launch_bounds__(256) void cursor_copy_kernel(
    const int* __restrict__ offsets, int* __restrict__ cursor, int n) {
  int i = blockIdx.x * 256 + threadIdx.x;
  if (i < 4 * n) {
    int t = i / n, j = i - t * n;
    cursor[(size_t)t * n + j] = offsets[(size_t)t * (n + 1) + j];
  }
}

__global__ __launch_bounds__(256) void fill4_kernel(EdgeLists4 ls) {
  EdgeList l = ls.l[blockIdx.y];
  int e = blockIdx.x * 256 + threadIdx.x;
  if (e < l.E) {
    int p = atomicAdd(&l.counts[l.dst[e]], 1);  // counts == cursor at this stage
    l.col[p] = l.src[e];
  }
}

// ---------------------------------------------------------------------------
// Pred/succ aggregate from bf16 ops table: 1 wave/row, 4 edges/iter, 16B/lane.
// ---------------------------------------------------------------------------
__global__ __launch_bounds__(256) void csr_agg128_kernel(
    const bf16* __restrict__ tab,
    const int* __restrict__ col0, const int* __restrict__ col1,
    const int* __restrict__ offs0, const int* __restrict__ offs1,
    bf16* __restrict__ out0, bf16* __restrict__ out1, int n) {
  const int* col = blockIdx.y ? col1 : col0;
  const int* offs = blockIdx.y ? offs1 : offs0;
  bf16* out = blockIdx.y ? out1 : out0;
  const int lane = threadIdx.x & 63;
  const int wid = threadIdx.x >> 6;
  const int r = blockIdx.x * 4 + wid;
  if (r >= n) return;
  const int slot = lane >> 4, lp = lane & 15;
  const int beg = offs[r], end = offs[r + 1];
  float acc[8] = {0.f, 0.f, 0.f, 0.f, 0.f, 0.f, 0.f, 0.f};
  for (int e = beg; e < end; e += 4) {
    int idx = e + slot;
    if (idx < end) {
      int cc = col[idx];
      short8 v = *reinterpret_cast<const short8*>(tab + (size_t)cc * 128 + lp * 8);
#pragma unroll
      for (int j = 0; j < 8; ++j) acc[j] += bf2f(v[j]);
    }
  }
#pragma unroll
  for (int j = 0; j < 8; ++j) {
    acc[j] += __shfl_xor(acc[j], 16, 64);
    acc[j] += __shfl_xor(acc[j], 32, 64);
  }
  if (slot == 0) {
    short8 sv;
#pragma unroll
    for (int j = 0; j < 8; ++j) sv[j] = f2bf(acc[j]);
    *reinterpret_cast<short8*>(out + (size_t)r * 128 + lp * 8) = sv;
  }
}

// ---------------------------------------------------------------------------
// Small CSR aggregate (res/mat) from f32 tables -> bf16 out
// ---------------------------------------------------------------------------
template <int D, int LPR>
__global__ __launch_bounds__(256) void csr_agg_kernel(
    const float* __restrict__ tab, const int* __restrict__ col,
    const int* __restrict__ offsets, bf16* __restrict__ out, int n) {
  constexpr int RPB = 256 / LPR;
  const int lane = threadIdx.x % LPR;
  const int r = blockIdx.x * RPB + threadIdx.x / LPR;
  if (r >= n) return;
  const int beg = offsets[r], end = offsets[r + 1];
  float2 acc = make_float2(0.f, 0.f);
  for (int e = beg; e < end; ++e) {
    int s = col[e];
    float2 v = *reinterpret_cast<const float2*>(tab + (size_t)s * D + lane * 2);
    acc.x += v.x;
    acc.y += v.y;
  }
  unsigned u = (unsigned)(unsigned short)f2bf(acc.x) |
               ((unsigned)(unsigned short)f2bf(acc.y) << 16);
  *reinterpret_cast<unsigned*>(out + (size_t)r * D + lane * 2) = u;
}

// ---------------------------------------------------------------------------
// Weight -> MFMA B-fragment conversion
// frag[tile=kc*CT+ct][lane][j] = W[kc*32+(lane>>4)*8+j][ct*16+(lane&15)]
// ---------------------------------------------------------------------------
struct WDesc { const float* src; int K; int C; int dstoff; };
struct WDescs14 { WDesc w[14]; };

__global__ __launch_bounds__(256) void wconv_kernel(WDescs14 ds, short* __restrict__ dstbase) {
  WDesc d = ds.w[blockIdx.y];
  int KC = d.K >> 5, CT = d.C >> 4;
  int t = blockIdx.x * 256 + threadIdx.x;
  if (t >= KC * CT * 64) return;
  int lane = t & 63, tile = t >> 6;
  int kc = tile / CT, ct = tile - kc * CT;
  int g = lane >> 4, lp = lane & 15;
  short8 v;
#pragma unroll
  for (int j = 0; j < 8; ++j)
    v[j] = f2bf(d.src[(size_t)(kc * 32 + g * 8 + j) * d.C + ct * 16 + lp]);
  *reinterpret_cast<short8*>(dstbase + d.dstoff + (size_t)t * 8) = v;
}

// ---------------------------------------------------------------------------
// MFMA fused 2-layer MLP device body (bf16 in, bf16 out, wave-private LDS)
// ---------------------------------------------------------------------------
template <int K, int O, bool GATHER>
__device__ __forceinline__ void mlp2_dev(
    const bf16* __restrict__ X, const int* __restrict__ gidx,
    const short* __restrict__ W1f, const float* __restrict__ B1,
    const short* __restrict__ W2f, const float* __restrict__ B2,
    bf16* __restrict__ xbuf, int ooff, int tile, int lane, char* hw) {
  constexpr int KC = K / 32;
  constexpr int KC2 = 8;
  constexpr int OT = O / 16;
  const int g = lane >> 4, lp = lane & 15;
  const int row0 = tile * 16;

  short8 a[KC];
  {
    int srow = GATHER ? gidx[row0 + lp] : (row0 + lp);
    const bf16* xp = X + (size_t)srow * K + g * 8;
#pragma unroll
    for (int kc = 0; kc < KC; ++kc)
      a[kc] = *reinterpret_cast<const short8*>(xp + kc * 32);
  }

#pragma unroll
  for (int ct = 0; ct < 16; ++ct) {
    float bv = B1[ct * 16 + lp];
    f32x4 acc = {bv, bv, bv, bv};
#pragma unroll
    for (int kc = 0; kc < KC; ++kc) {
      short8 b = *reinterpret_cast<const short8*>(
          W1f + ((size_t)(kc * 16 + ct) * 64 + lane) * 8);
      acc = __builtin_amdgcn_mfma_f32_16x16x32_bf16(a[kc], b, acc, 0, 0, 0);
    }
#pragma unroll
    for (int r = 0; r < 4; ++r) {
      int rr = g * 4 + r;
      int byte = rr * 512 + (ct * 16 + lp) * 2;
      byte ^= (rr & 7) << 4;
      *reinterpret_cast<short*>(hw + byte) = f2bf(fmaxf(acc[r], 0.f));
    }
  }
  asm volatile("s_waitcnt lgkmcnt(0)" ::: "memory");
  __builtin_amdgcn_sched_barrier(0);

  short8 a2[KC2];
#pragma unroll
  for (int kc = 0; kc < KC2; ++kc) {
    int byte = lp * 512 + (kc * 32 + g * 8) * 2;
    byte ^= (lp & 7) << 4;
    a2[kc] = *reinterpret_cast<const short8*>(hw + byte);
  }
#pragma unroll
  for (int ot = 0; ot < OT; ++ot) {
    float bv = B2[ot * 16 + lp];
    f32x4 acc = {bv, bv, bv, bv};
#pragma unroll
    for (int kc = 0; kc < KC2; ++kc) {
      short8 b = *reinterpret_cast<const short8*>(
          W2f + ((size_t)(kc * OT + ot) * 64 + lane) * 8);
      acc = __builtin_amdgcn_mfma_f32_16x16x32_bf16(a2[kc], b, acc, 0, 0, 0);
    }
#pragma unroll
    for (int r = 0; r < 4; ++r) {
      int rr = g * 4 + r;
      *reinterpret_cast<short*>(xbuf + (size_t)(row0 + rr) * 608 + ooff + ot * 16 + lp) =
          f2bf(acc[r]);
    }
  }
}

struct Mlp6Args {
  const bf16 *agg_pred, *agg_succ, *agg_res, *agg_mat, *items_bf, *ops_bf;
  const int* related;
  const short* wf;
  const float *b_pred1, *b_pred2, *b_succ1, *b_succ2, *b_res1, *b_res2;
  const float *b_mat1, *b_mat2, *b_item1, *b_item2, *b_self1, *b_self2;
  bf16* xbuf;
  int ntiles;
};

__global__ __launch_bounds__(256) void mlp6_kernel(Mlp6Args A) {
  __shared__ short hbuf[4 * 16 * 256];  // 32 KB, 8 KB/wave
  const int lane = threadIdx.x & 63, wid = threadIdx.x >> 6;
  int tile = blockIdx.x * 4 + wid;
  if (tile >= A.ntiles) tile = A.ntiles - 1;  // dup benign
  char* hw = (char*)(hbuf + wid * (16 * 256));
  const short* wf = A.wf;
  switch (blockIdx.y) {
    case 0: mlp2_dev<128, 128, false>(A.agg_pred, nullptr, wf + 65536, A.b_pred1,
                                      wf + 221184, A.b_pred2, A.xbuf, 0, tile, lane, hw); break;
    case 1: mlp2_dev<128, 128, false>(A.agg_succ, nullptr, wf + 98304, A.b_succ1,
                                      wf + 253952, A.b_succ2, A.xbuf, 128, tile, lane, hw); break;
    case 2: mlp2_dev<64, 64, false>(A.agg_res, nullptr, wf + 131072, A.b_res1,
                                    wf + 286720, A.b_res2, A.xbuf, 256, tile, lane, hw); break;
    case 3: mlp2_dev<32, 32, false>(A.agg_mat, nullptr, wf + 147456, A.b_mat1,
                                    wf + 303104, A.b_mat2, A.xbuf, 320, tile, lane, hw); break;
    case 4: mlp2_dev<128, 128, true>(A.items_bf, A.related, wf + 32768, A.b_item1,
                                     wf + 188416, A.b_item2, A.xbuf, 352, tile, lane, hw); break;
    default: mlp2_dev<128, 128, false>(A.ops_bf, nullptr, wf + 0, A.b_self1,
                                       wf + 155648, A.b_self2, A.xbuf, 480, tile, lane, hw); break;
  }
}

// ---------------------------------------------------------------------------
// Final combiner: L1 608->256 MFMA (h1 bf16, wave-private swizzled LDS),
// L2 256->128 MFMA (h2 f32 in aliased LDS), L3 128->128 f32 VALU.
// Zero block-level syncs; 32 KB LDS.
// ---------------------------------------------------------------------------
__global__ __launch_bounds__(256, 4) void final_kernel(
    const bf16* __restrict__ xbuf,
    const short* __restrict__ Wc1f, const float* __restrict__ B1,
    const short* __restrict__ Wc2f, const float* __restrict__ B2,
    const float* __restrict__ W3, const float* __restrict__ B3,
    float* __restrict__ out, int ntiles) {
  __shared__ short hbuf[4 * 16 * 256];  // 32 KB: per-wave h1 bf16, then h2 f32 aliased
  const int lane = threadIdx.x & 63, wid = threadIdx.x >> 6;
  int tile = blockIdx.x * 4 + wid;
  if (tile >= ntiles) tile = ntiles - 1;
  const int g = lane >> 4, lp = lane & 15;
  const int row0 = tile * 16;
  char* hw = (char*)(hbuf + wid * (16 * 256));

  // ---- L1: h1 = relu(x @ Wc1 + b1), 608->256, MFMA ----
  {
    const bf16* xp = xbuf + (size_t)(row0 + lp) * 608 + g * 8;
    short8 a[19];
#pragma unroll
    for (int kc = 0; kc < 19; ++kc)
      a[kc] = *reinterpret_cast<const short8*>(xp + kc * 32);
#pragma unroll
    for (int ct = 0; ct < 16; ++ct) {
      float bv = B1[ct * 16 + lp];
      f32x4 acc = {bv, bv, bv, bv};
#pragma unroll
      for (int kc = 0; kc < 19; ++kc) {
        short8 b = *reinterpret_cast<const short8*>(
            Wc1f + ((size_t)(kc * 16 + ct) * 64 + lane) * 8);
        acc = __builtin_amdgcn_mfma_f32_16x16x32_bf16(a[kc], b, acc, 0, 0, 0);
      }
#pragma unroll
      for (int r = 0; r < 4; ++r) {
        int rr = g * 4 + r;
        int byte = rr * 512 + (ct * 16 + lp) * 2;
        byte ^= (rr & 7) << 4;
        *reinterpret_cast<short*>(hw + byte) = f2bf(fmaxf(acc[r], 0.f));
      }
    }
  }
  asm volatile("s_waitcnt lgkmcnt(0)" ::: "memory");
  __builtin_amdgcn_sched_barrier(0);

  // ---- L2: h2 = relu(h1 @ Wc2 + b2), 256->128, MFMA ----
  {
    short8 a2[8];
#pragma unroll
    for (int kc = 0; kc < 8; ++kc) {
      int byte = lp * 512 + (kc * 32 + g * 8) * 2;
      byte ^= (lp & 7) << 4;
      a2[kc] = *reinterpret_cast<const short8*>(hw + byte);
    }
    asm volatile("s_waitcnt lgkmcnt(0)" ::: "memory");
    __builtin_amdgcn_sched_barrier(0);
    float* h2 = (float*)hw;  // alias over h1 (a2 fully in regs)
#pragma unroll
    for (int ot = 0; ot < 8; ++ot) {
      float bv = B2[ot * 16 + lp];
      f32x4 acc = {bv, bv, bv, bv};
#pragma unroll
      for (int kc = 0; kc < 8; ++kc) {
        short8 b = *reinterpret_cast<const short8*>(
            Wc2f + ((size_t)(kc * 8 + ot) * 64 + lane) * 8);
        acc = __builtin_amdgcn_mfma_f32_16x16x32_bf16(a2[kc], b, acc, 0, 0, 0);
      }
#pragma unroll
      for (int r = 0; r < 4; ++r)
        h2[(g * 4 + r) * 128 + ot * 16 + lp] = fmaxf(acc[r], 0.f);
    }
  }
  asm volatile("s_waitcnt lgkmcnt(0)" ::: "memory");
  __builtin_amdgcn_sched_barrier(0);

  // ---- L3: out = h2 @ W3 + b3, f32 VALU (precision-critical) ----
  {
    const float* h2 = (const float*)hw;
    const int half = lane >> 5;
    const int c = (lane & 31) * 4;
    const int rbase = half * 8;
    f32x4 acc3[8];
    f32x4 bv = *reinterpret_cast<const f32x4*>(B3 + c);
#pragma unroll
    for (int rr = 0; rr < 8; ++rr) acc3[rr] = bv;
    for (int k0 = 0; k0 < 128; k0 += 4) {
      f32x4 w0 = *reinterpret_cast<const f32x4*>(W3 + (size_t)(k0 + 0) * 128 + c);
      f32x4 w1 = *reinterpret_cast<const f32x4*>(W3 + (size_t)(k0 + 1) * 128 + c);
      f32x4 w2v = *reinterpret_cast<const f32x4*>(W3 + (size_t)(k0 + 2) * 128 + c);
      f32x4 w3v = *reinterpret_cast<const f32x4*>(W3 + (size_t)(k0 + 3) * 128 + c);
#pragma unroll
      for (int rr = 0; rr < 8; ++rr) {
        f32x4 h = *reinterpret_cast<const f32x4*>(&h2[(rbase + rr) * 128 + k0]);
        acc3[rr] += h.x * w0 + h.y * w1 + h.z * w2v + h.w * w3v;
      }
    }
#pragma unroll
    for (int rr = 0; rr < 8; ++rr)
      *reinterpret_cast<f32x4*>(out + (size_t)(row0 + rbase + rr) * 128 + c) = acc3[rr];
  }
}

// ---------------------------------------------------------------------------
// kernel_launch
// ---------------------------------------------------------------------------
extern "C" void kernel_launch(void* const* d_in, const int* in_sizes, int n_in,
                              void* d_out, int out_size, void* d_ws,
                              size_t ws_size, hipStream_t stream) {
  const float* operations = (const float*)d_in[0];
  const float* items      = (const float*)d_in[1];
  const float* materials  = (const float*)d_in[2];
  const float* resources  = (const float*)d_in[3];
  const int* related      = (const int*)d_in[4];
  const int* res_op       = (const int*)d_in[5];
  const int* res_res      = (const int*)d_in[6];
  const int* mat_op       = (const int*)d_in[7];
  const int* mat_mat      = (const int*)d_in[8];
  const int* prec_src     = (const int*)d_in[9];
  const int* prec_dst     = (const int*)d_in[10];
  const float* w_self1 = (const float*)d_in[11];
  const float* b_self1 = (const float*)d_in[12];
  const float* w_self2 = (const float*)d_in[13];
  const float* b_self2 = (const float*)d_in[14];
  const float* w_item1 = (const float*)d_in[15];
  const float* b_item1 = (const float*)d_in[16];
  const float* w_item2 = (const float*)d_in[17];
  const float* b_item2 = (const float*)d_in[18];
  const float* w_pred1 = (const float*)d_in[19];
  const float* b_pred1 = (const float*)d_in[20];
  const float* w_pred2 = (const float*)d_in[21];
  const float* b_pred2 = (const float*)d_in[22];
  const float* w_succ1 = (const float*)d_in[23];
  const float* b_succ1 = (const float*)d_in[24];
  const float* w_succ2 = (const float*)d_in[25];
  const float* b_succ2 = (const float*)d_in[26];
  const float* w_res1  = (const float*)d_in[27];
  const float* b_res1  = (const float*)d_in[28];
  const float* w_res2  = (const float*)d_in[29];
  const float* b_res2  = (const float*)d_in[30];
  const float* w_mat1  = (const float*)d_in[31];
  const float* b_mat1  = (const float*)d_in[32];
  const float* w_mat2  = (const float*)d_in[33];
  const float* b_mat2  = (const float*)d_in[34];
  const float* w_c1    = (const float*)d_in[35];
  const float* b_c1    = (const float*)d_in[36];
  const float* w_c2    = (const float*)d_in[37];
  const float* b_c2    = (const float*)d_in[38];
  const float* w_c3    = (const float*)d_in[39];
  const float* b_c3    = (const float*)d_in[40];

  const int N = in_sizes[0] / 128;   // 50000
  const int NI = in_sizes[1] / 128;  // 20000
  const int E_RES = in_sizes[5];
  const int E_MAT = in_sizes[7];
  const int E_PREC = in_sizes[9];

  // ---- ws layout ----
  size_t off = 0;
  auto take = [&](size_t bytes) {
    size_t o = off;
    off += (bytes + 63) & ~(size_t)63;
    return o;
  };
  size_t xbuf_off  = take((size_t)N * 608 * 2);
  size_t aggp_off  = take((size_t)N * 128 * 2);
  size_t aggsu_off = take((size_t)N * 128 * 2);
  size_t aggr_off  = take((size_t)N * 64 * 2);
  size_t aggm_off  = take((size_t)N * 32 * 2);
  size_t wf_off    = take((size_t)499712 * 2);
  size_t opsb_off  = take((size_t)N * 128 * 2);
  size_t itemb_off = take((size_t)NI * 128 * 2);
  size_t offs_off  = take((size_t)4 * (N + 1) * 4);
  size_t tmp_off   = take((size_t)4 * N * 4);
  size_t cols_off  = take(((size_t)2 * E_PREC + E_RES + E_MAT) * 4);

  char* ws = (char*)d_ws;
  bf16* xbuf = (bf16*)(ws + xbuf_off);
  bf16* agg_pred = (bf16*)(ws + aggp_off);
  bf16* agg_succ = (bf16*)(ws + aggsu_off);
  bf16* agg_res  = (bf16*)(ws + aggr_off);
  bf16* agg_mat  = (bf16*)(ws + aggm_off);
  short* wf = (short*)(ws + wf_off);
  bf16* ops_bf   = (bf16*)(ws + opsb_off);
  bf16* items_bf = (bf16*)(ws + itemb_off);
  int* offs = (int*)(ws + offs_off);
  int* tmp  = (int*)(ws + tmp_off);
  int* cols = (int*)(ws + cols_off);

  int* offs_pred = offs;
  int* offs_succ = offs + (N + 1);
  int* offs_res  = offs + 2 * (N + 1);
  int* offs_mat  = offs + 3 * (N + 1);
  int* cur_pred = tmp;
  int* cur_succ = tmp + N;
  int* cur_res  = tmp + 2 * N;
  int* cur_mat  = tmp + 3 * N;
  int* col_pred = cols;
  int* col_succ = col_pred + E_PREC;
  int* col_res  = col_succ + E_PREC;
  int* col_mat  = col_res + E_RES;

  dim3 blk(256);

  // ---- bf16 tables ----
  cvt_bf16_kernel<<<(N * 128 / 4 + 255) / 256, blk, 0, stream>>>(operations, ops_bf, N * 128 / 4);
  cvt_bf16_kernel<<<(NI * 128 / 4 + 255) / 256, blk, 0, stream>>>(items, items_bf, NI * 128 / 4);

  // ---- weight fragments ----
  WDescs14 wd;
  wd.w[0]  = {w_self1, 128, 256, 0};
  wd.w[1]  = {w_item1, 128, 256, 32768};
  wd.w[2]  = {w_pred1, 128, 256, 65536};
  wd.w[3]  = {w_succ1, 128, 256, 98304};
  wd.w[4]  = {w_res1,   64, 256, 131072};
  wd.w[5]  = {w_mat1,   32, 256, 147456};
  wd.w[6]  = {w_self2, 256, 128, 155648};
  wd.w[7]  = {w_item2, 256, 128, 188416};
  wd.w[8]  = {w_pred2, 256, 128, 221184};
  wd.w[9]  = {w_succ2, 256, 128, 253952};
  wd.w[10] = {w_res2,  256,  64, 286720};
  wd.w[11] = {w_mat2,  256,  32, 303104};
  wd.w[12] = {w_c1,    608, 256, 311296};
  wd.w[13] = {w_c2,    256, 128, 466944};
  wconv_kernel<<<dim3(76, 14), blk, 0, stream>>>(wd, wf);

  // ---- CSR build ----
  (void)hipMemsetAsync(tmp, 0, 4 * (size_t)N * sizeof(int), stream);
  EdgeLists4 els;
  els.l[0] = {prec_src, prec_dst, cur_pred, col_pred, E_PREC};
  els.l[1] = {prec_dst, prec_src, cur_succ, col_succ, E_PREC};
  els.l[2] = {res_op, res_res, cur_res, col_res, E_RES};
  els.l[3] = {mat_op, mat_mat, cur_mat, col_mat, E_MAT};
  int cgx = (E_PREC + 255) / 256;
  count4_kernel<<<dim3(cgx, 4), blk, 0, stream>>>(els);
  scan4_kernel<<<4, 1024, 0, stream>>>(tmp, offs, N);
  cursor_copy_kernel<<<(4 * N + 255) / 256, blk, 0, stream>>>(offs, tmp, N);
  fill4_kernel<<<dim3(cgx, 4), blk, 0, stream>>>(els);

  // ---- aggregates ----
  csr_agg128_kernel<<<dim3((N + 3) / 4, 2), blk, 0, stream>>>(
      ops_bf, col_pred, col_succ, offs_pred, offs_succ, agg_pred, agg_succ, N);
  csr_agg_kernel<64, 32><<<(N + 7) / 8, blk, 0, stream>>>(resources, col_res, offs_res, agg_res, N);
  csr_agg_kernel<32, 16><<<(N + 15) / 16, blk, 0, stream>>>(materials, col_mat, offs_mat, agg_mat, N);

  // ---- 6 MLPs in one launch ----
  int ntiles = N / 16;           // 3125
  int mgrid = (ntiles + 3) / 4;  // 782
  Mlp6Args ma;
  ma.agg_pred = agg_pred; ma.agg_succ = agg_succ; ma.agg_res = agg_res; ma.agg_mat = agg_mat;
  ma.items_bf = items_bf; ma.ops_bf = ops_bf; ma.related = related; ma.wf = wf;
  ma.b_pred1 = b_pred1; ma.b_pred2 = b_pred2; ma.b_succ1 = b_succ1; ma.b_succ2 = b_succ2;
  ma.b_res1 = b_res1; ma.b_res2 = b_res2; ma.b_mat1 = b_mat1; ma.b_mat2 = b_mat2;
  ma.b_item1 = b_item1; ma.b_item2 = b_item2; ma.b_self1 = b_self1; ma.b_self2 = b_self2;
  ma.xbuf = xbuf; ma.ntiles = ntiles;
  mlp6_kernel<<<dim3(mgrid, 6), blk, 0, stream>>>(ma);

  // ---- final combiner ----
  final_kernel<<<mgrid, blk, 0, stream>>>(
      xbuf, wf + 311296, b_c1, wf + 466944, b_c2, w_c3, b_c3, (float*)d_out, ntiles);
}

// Round 11
// 626.427 us; speedup vs baseline: 6.9834x; 1.0155x over previous
//
#include <hip/hip_runtime.h>
#include <hip/hip_bf16.h>

typedef __attribute__((ext_vector_type(8))) short short8;
typedef __attribute__((ext_vector_type(4))) float f32x4;
using bf16 = __hip_bfloat16;

// N=50000, OP=128, H=256, H2=128, OUT=128
// xbuf concat: [pred 0 | succ 128 | res 256 | mat 320 | item 352 | self 480], 608

__device__ __forceinline__ short f2bf(float f) {
  union { float f; unsigned u; } v; v.f = f;
  unsigned r = (v.u + 0x7fffu + ((v.u >> 16) & 1u)) >> 16;  // RNE
  return (short)r;
}
__device__ __forceinline__ float bf2f(short s) {
  union { unsigned u; float f; } x;
  x.u = ((unsigned)(unsigned short)s) << 16;
  return x.f;
}

// ---------------------------------------------------------------------------
// f32 -> bf16 table conversion
// ---------------------------------------------------------------------------
__global__ __launch_bounds__(256) void cvt_bf16_kernel(
    const float* __restrict__ src, bf16* __restrict__ dst, int n4) {
  int i = blockIdx.x * 256 + threadIdx.x;
  if (i >= n4) return;
  f32x4 v = *reinterpret_cast<const f32x4*>(src + (size_t)i * 4);
  uint2 u;
  u.x = (unsigned)(unsigned short)f2bf(v.x) | ((unsigned)(unsigned short)f2bf(v.y) << 16);
  u.y = (unsigned)(unsigned short)f2bf(v.z) | ((unsigned)(unsigned short)f2bf(v.w) << 16);
  *reinterpret_cast<uint2*>(dst + (size_t)i * 4) = u;
}

// ---------------------------------------------------------------------------
// CSR build: merged count / scan / cursor / merged fill
// ---------------------------------------------------------------------------
struct EdgeList { const int* dst; const int* src; int* counts; int* col; int E; };
struct EdgeLists4 { EdgeList l[4]; };

__global__ __launch_bounds__(256) void count4_kernel(EdgeLists4 ls) {
  EdgeList l = ls.l[blockIdx.y];
  int e = blockIdx.x * 256 + threadIdx.x;
  if (e < l.E) atomicAdd(&l.counts[l.dst[e]], 1);
}

__global__ __launch_bounds__(1024) void scan4_kernel(
    const int* __restrict__ counts, int* __restrict__ offsets, int n) {
  const int* cnt = counts + (size_t)blockIdx.x * n;
  int* offs = offsets + (size_t)blockIdx.x * (n + 1);
  __shared__ int wsum[16];
  __shared__ int carry_s;
  const int lane = threadIdx.x & 63;
  const int wid = threadIdx.x >> 6;
  if (threadIdx.x == 0) carry_s = 0;
  __syncthreads();
  for (int base = 0; base < n; base += 1024) {
    int i = base + threadIdx.x;
    int v = (i < n) ? cnt[i] : 0;
    int x = v;
#pragma unroll
    for (int off = 1; off < 64; off <<= 1) {
      int t = __shfl_up(x, off, 64);
      if (lane >= off) x += t;
    }
    if (lane == 63) wsum[wid] = x;
    __syncthreads();
    if (wid == 0 && lane < 16) {
      int w = wsum[lane];
#pragma unroll
      for (int off = 1; off < 16; off <<= 1) {
        int t = __shfl_up(w, off, 16);
        if (lane >= off) w += t;
      }
      wsum[lane] = w;
    }
    __syncthreads();
    int carry = carry_s;
    int wpre = (wid == 0) ? 0 : wsum[wid - 1];
    if (i < n) offs[i] = carry + wpre + x - v;
    __syncthreads();
    if (threadIdx.x == 1023) carry_s = carry + wsum[15];
    __syncthreads();
  }
  if (threadIdx.x == 0) offs[n] = carry_s;
}

__global__ __launch_bounds__(256) void cursor_copy_kernel(
    const int* __restrict__ offsets, int* __restrict__ cursor, int n) {
  int i = blockIdx.x * 256 + threadIdx.x;
  if (i < 4 * n) {
    int t = i / n, j = i - t * n;
    cursor[(size_t)t * n + j] = offsets[(size_t)t * (n + 1) + j];
  }
}

__global__ __launch_bounds__(256) void fill4_kernel(EdgeLists4 ls) {
  EdgeList l = ls.l[blockIdx.y];
  int e = blockIdx.x * 256 + threadIdx.x;
  if (e < l.E) {
    int p = atomicAdd(&l.counts[l.dst[e]], 1);  // counts == cursor at this stage
    l.col[p] = l.src[e];
  }
}

// ---------------------------------------------------------------------------
// Pred/succ aggregate from bf16 ops table: 1 wave/row, 8 edges in flight
// (2x unrolled, dual accumulator sets merged at the end).
// ---------------------------------------------------------------------------
__global__ __launch_bounds__(256) void csr_agg128_kernel(
    const bf16* __restrict__ tab,
    const int* __restrict__ col0, const int* __restrict__ col1,
    const int* __restrict__ offs0, const int* __restrict__ offs1,
    bf16* __restrict__ out0, bf16* __restrict__ out1, int n) {
  const int* col = blockIdx.y ? col1 : col0;
  const int* offs = blockIdx.y ? offs1 : offs0;
  bf16* out = blockIdx.y ? out1 : out0;
  const int lane = threadIdx.x & 63;
  const int wid = threadIdx.x >> 6;
  const int r = blockIdx.x * 4 + wid;
  if (r >= n) return;
  const int slot = lane >> 4, lp = lane & 15;
  const int beg = offs[r], end = offs[r + 1];
  float acc[8] = {0.f, 0.f, 0.f, 0.f, 0.f, 0.f, 0.f, 0.f};
  float acc2[8] = {0.f, 0.f, 0.f, 0.f, 0.f, 0.f, 0.f, 0.f};
  int e = beg;
  for (; e + 8 <= end; e += 8) {
    int c0 = col[e + slot];
    int c1 = col[e + 4 + slot];
    short8 v0 = *reinterpret_cast<const short8*>(tab + (size_t)c0 * 128 + lp * 8);
    short8 v1 = *reinterpret_cast<const short8*>(tab + (size_t)c1 * 128 + lp * 8);
#pragma unroll
    for (int j = 0; j < 8; ++j) {
      acc[j] += bf2f(v0[j]);
      acc2[j] += bf2f(v1[j]);
    }
  }
  for (; e < end; e += 4) {
    int idx = e + slot;
    if (idx < end) {
      int cc = col[idx];
      short8 v = *reinterpret_cast<const short8*>(tab + (size_t)cc * 128 + lp * 8);
#pragma unroll
      for (int j = 0; j < 8; ++j) acc[j] += bf2f(v[j]);
    }
  }
#pragma unroll
  for (int j = 0; j < 8; ++j) acc[j] += acc2[j];
#pragma unroll
  for (int j = 0; j < 8; ++j) {
    acc[j] += __shfl_xor(acc[j], 16, 64);
    acc[j] += __shfl_xor(acc[j], 32, 64);
  }
  if (slot == 0) {
    short8 sv;
#pragma unroll
    for (int j = 0; j < 8; ++j) sv[j] = f2bf(acc[j]);
    *reinterpret_cast<short8*>(out + (size_t)r * 128 + lp * 8) = sv;
  }
}

// ---------------------------------------------------------------------------
// Small CSR aggregate (res/mat) from f32 tables -> bf16 out
// ---------------------------------------------------------------------------
template <int D, int LPR>
__global__ __launch_bounds__(256) void csr_agg_kernel(
    const float* __restrict__ tab, const int* __restrict__ col,
    const int* __restrict__ offsets, bf16* __restrict__ out, int n) {
  constexpr int RPB = 256 / LPR;
  const int lane = threadIdx.x % LPR;
  const int r = blockIdx.x * RPB + threadIdx.x / LPR;
  if (r >= n) return;
  const int beg = offsets[r], end = offsets[r + 1];
  float2 acc = make_float2(0.f, 0.f);
  for (int e = beg; e < end; ++e) {
    int s = col[e];
    float2 v = *reinterpret_cast<const float2*>(tab + (size_t)s * D + lane * 2);
    acc.x += v.x;
    acc.y += v.y;
  }
  unsigned u = (unsigned)(unsigned short)f2bf(acc.x) |
               ((unsigned)(unsigned short)f2bf(acc.y) << 16);
  *reinterpret_cast<unsigned*>(out + (size_t)r * D + lane * 2) = u;
}

// ---------------------------------------------------------------------------
// Weight -> MFMA B-fragment conversion
// frag[tile=kc*CT+ct][lane][j] = W[kc*32+(lane>>4)*8+j][ct*16+(lane&15)]
// ---------------------------------------------------------------------------
struct WDesc { const float* src; int K; int C; int dstoff; };
struct WDescs14 { WDesc w[14]; };

__global__ __launch_bounds__(256) void wconv_kernel(WDescs14 ds, short* __restrict__ dstbase) {
  WDesc d = ds.w[blockIdx.y];
  int KC = d.K >> 5, CT = d.C >> 4;
  int t = blockIdx.x * 256 + threadIdx.x;
  if (t >= KC * CT * 64) return;
  int lane = t & 63, tile = t >> 6;
  int kc = tile / CT, ct = tile - kc * CT;
  int g = lane >> 4, lp = lane & 15;
  short8 v;
#pragma unroll
  for (int j = 0; j < 8; ++j)
    v[j] = f2bf(d.src[(size_t)(kc * 32 + g * 8 + j) * d.C + ct * 16 + lp]);
  *reinterpret_cast<short8*>(dstbase + d.dstoff + (size_t)t * 8) = v;
}

// ---------------------------------------------------------------------------
// MFMA fused 2-layer MLP device body (bf16 in, bf16 out, wave-private LDS)
// FROZEN AT R8 — byte-for-byte. Do NOT restructure (R5/R6/R9/R10 all failed).
// ---------------------------------------------------------------------------
template <int K, int O, bool GATHER>
__device__ __forceinline__ void mlp2_dev(
    const bf16* __restrict__ X, const int* __restrict__ gidx,
    const short* __restrict__ W1f, const float* __restrict__ B1,
    const short* __restrict__ W2f, const float* __restrict__ B2,
    bf16* __restrict__ xbuf, int ooff, int tile, int lane, char* hw) {
  constexpr int KC = K / 32;
  constexpr int KC2 = 8;
  constexpr int OT = O / 16;
  const int g = lane >> 4, lp = lane & 15;
  const int row0 = tile * 16;

  short8 a[KC];
  {
    int srow = GATHER ? gidx[row0 + lp] : (row0 + lp);
    const bf16* xp = X + (size_t)srow * K + g * 8;
#pragma unroll
    for (int kc = 0; kc < KC; ++kc)
      a[kc] = *reinterpret_cast<const short8*>(xp + kc * 32);
  }

#pragma unroll
  for (int ct = 0; ct < 16; ++ct) {
    float bv = B1[ct * 16 + lp];
    f32x4 acc = {bv, bv, bv, bv};
#pragma unroll
    for (int kc = 0; kc < KC; ++kc) {
      short8 b = *reinterpret_cast<const short8*>(
          W1f + ((size_t)(kc * 16 + ct) * 64 + lane) * 8);
      acc = __builtin_amdgcn_mfma_f32_16x16x32_bf16(a[kc], b, acc, 0, 0, 0);
    }
#pragma unroll
    for (int r = 0; r < 4; ++r) {
      int rr = g * 4 + r;
      int byte = rr * 512 + (ct * 16 + lp) * 2;
      byte ^= (rr & 7) << 4;
      *reinterpret_cast<short*>(hw + byte) = f2bf(fmaxf(acc[r], 0.f));
    }
  }
  asm volatile("s_waitcnt lgkmcnt(0)" ::: "memory");
  __builtin_amdgcn_sched_barrier(0);

  short8 a2[KC2];
#pragma unroll
  for (int kc = 0; kc < KC2; ++kc) {
    int byte = lp * 512 + (kc * 32 + g * 8) * 2;
    byte ^= (lp & 7) << 4;
    a2[kc] = *reinterpret_cast<const short8*>(hw + byte);
  }
#pragma unroll
  for (int ot = 0; ot < OT; ++ot) {
    float bv = B2[ot * 16 + lp];
    f32x4 acc = {bv, bv, bv, bv};
#pragma unroll
    for (int kc = 0; kc < KC2; ++kc) {
      short8 b = *reinterpret_cast<const short8*>(
          W2f + ((size_t)(kc * OT + ot) * 64 + lane) * 8);
      acc = __builtin_amdgcn_mfma_f32_16x16x32_bf16(a2[kc], b, acc, 0, 0, 0);
    }
#pragma unroll
    for (int r = 0; r < 4; ++r) {
      int rr = g * 4 + r;
      *reinterpret_cast<short*>(xbuf + (size_t)(row0 + rr) * 608 + ooff + ot * 16 + lp) =
          f2bf(acc[r]);
    }
  }
}

struct Mlp6Args {
  const bf16 *agg_pred, *agg_succ, *agg_res, *agg_mat, *items_bf, *ops_bf;
  const int* related;
  const short* wf;
  const float *b_pred1, *b_pred2, *b_succ1, *b_succ2, *b_res1, *b_res2;
  const float *b_mat1, *b_mat2, *b_item1, *b_item2, *b_self1, *b_self2;
  bf16* xbuf;
  int ntiles;
};

__global__ __launch_bounds__(256) void mlp6_kernel(Mlp6Args A) {
  __shared__ short hbuf[4 * 16 * 256];  // 32 KB, 8 KB/wave
  const int lane = threadIdx.x & 63, wid = threadIdx.x >> 6;
  int tile = blockIdx.x * 4 + wid;
  if (tile >= A.ntiles) tile = A.ntiles - 1;  // dup benign
  char* hw = (char*)(hbuf + wid * (16 * 256));
  const short* wf = A.wf;
  switch (blockIdx.y) {
    case 0: mlp2_dev<128, 128, false>(A.agg_pred, nullptr, wf + 65536, A.b_pred1,
                                      wf + 221184, A.b_pred2, A.xbuf, 0, tile, lane, hw); break;
    case 1: mlp2_dev<128, 128, false>(A.agg_succ, nullptr, wf + 98304, A.b_succ1,
                                      wf + 253952, A.b_succ2, A.xbuf, 128, tile, lane, hw); break;
    case 2: mlp2_dev<64, 64, false>(A.agg_res, nullptr, wf + 131072, A.b_res1,
                                    wf + 286720, A.b_res2, A.xbuf, 256, tile, lane, hw); break;
    case 3: mlp2_dev<32, 32, false>(A.agg_mat, nullptr, wf + 147456, A.b_mat1,
                                    wf + 303104, A.b_mat2, A.xbuf, 320, tile, lane, hw); break;
    case 4: mlp2_dev<128, 128, true>(A.items_bf, A.related, wf + 32768, A.b_item1,
                                     wf + 188416, A.b_item2, A.xbuf, 352, tile, lane, hw); break;
    default: mlp2_dev<128, 128, false>(A.ops_bf, nullptr, wf + 0, A.b_self1,
                                       wf + 155648, A.b_self2, A.xbuf, 480, tile, lane, hw); break;
  }
}

// ---------------------------------------------------------------------------
// Final combiner: FROZEN AT R8 — byte-for-byte.
// ---------------------------------------------------------------------------
__global__ __launch_bounds__(256, 4) void final_kernel(
    const bf16* __restrict__ xbuf,
    const short* __restrict__ Wc1f, const float* __restrict__ B1,
    const short* __restrict__ Wc2f, const float* __restrict__ B2,
    const float* __restrict__ W3, const float* __restrict__ B3,
    float* __restrict__ out, int ntiles) {
  __shared__ short hbuf[4 * 16 * 256];  // 32 KB: per-wave h1 bf16, then h2 f32 aliased
  const int lane = threadIdx.x & 63, wid = threadIdx.x >> 6;
  int tile = blockIdx.x * 4 + wid;
  if (tile >= ntiles) tile = ntiles - 1;
  const int g = lane >> 4, lp = lane & 15;
  const int row0 = tile * 16;
  char* hw = (char*)(hbuf + wid * (16 * 256));

  // ---- L1: h1 = relu(x @ Wc1 + b1), 608->256, MFMA ----
  {
    const bf16* xp = xbuf + (size_t)(row0 + lp) * 608 + g * 8;
    short8 a[19];
#pragma unroll
    for (int kc = 0; kc < 19; ++kc)
      a[kc] = *reinterpret_cast<const short8*>(xp + kc * 32);
#pragma unroll
    for (int ct = 0; ct < 16; ++ct) {
      float bv = B1[ct * 16 + lp];
      f32x4 acc = {bv, bv, bv, bv};
#pragma unroll
      for (int kc = 0; kc < 19; ++kc) {
        short8 b = *reinterpret_cast<const short8*>(
            Wc1f + ((size_t)(kc * 16 + ct) * 64 + lane) * 8);
        acc = __builtin_amdgcn_mfma_f32_16x16x32_bf16(a[kc], b, acc, 0, 0, 0);
      }
#pragma unroll
      for (int r = 0; r < 4; ++r) {
        int rr = g * 4 + r;
        int byte = rr * 512 + (ct * 16 + lp) * 2;
        byte ^= (rr & 7) << 4;
        *reinterpret_cast<short*>(hw + byte) = f2bf(fmaxf(acc[r], 0.f));
      }
    }
  }
  asm volatile("s_waitcnt lgkmcnt(0)" ::: "memory");
  __builtin_amdgcn_sched_barrier(0);

  // ---- L2: h2 = relu(h1 @ Wc2 + b2), 256->128, MFMA ----
  {
    short8 a2[8];
#pragma unroll
    for (int kc = 0; kc < 8; ++kc) {
      int byte = lp * 512 + (kc * 32 + g * 8) * 2;
      byte ^= (lp & 7) << 4;
      a2[kc] = *reinterpret_cast<const short8*>(hw + byte);
    }
    asm volatile("s_waitcnt lgkmcnt(0)" ::: "memory");
    __builtin_amdgcn_sched_barrier(0);
    float* h2 = (float*)hw;  // alias over h1 (a2 fully in regs)
#pragma unroll
    for (int ot = 0; ot < 8; ++ot) {
      float bv = B2[ot * 16 + lp];
      f32x4 acc = {bv, bv, bv, bv};
#pragma unroll
      for (int kc = 0; kc < 8; ++kc) {
        short8 b = *reinterpret_cast<const short8*>(
            Wc2f + ((size_t)(kc * 8 + ot) * 64 + lane) * 8);
        acc = __builtin_amdgcn_mfma_f32_16x16x32_bf16(a2[kc], b, acc, 0, 0, 0);
      }
#pragma unroll
      for (int r = 0; r < 4; ++r)
        h2[(g * 4 + r) * 128 + ot * 16 + lp] = fmaxf(acc[r], 0.f);
    }
  }
  asm volatile("s_waitcnt lgkmcnt(0)" ::: "memory");
  __builtin_amdgcn_sched_barrier(0);

  // ---- L3: out = h2 @ W3 + b3, f32 VALU (precision-critical) ----
  {
    const float* h2 = (const float*)hw;
    const int half = lane >> 5;
    const int c = (lane & 31) * 4;
    const int rbase = half * 8;
    f32x4 acc3[8];
    f32x4 bv = *reinterpret_cast<const f32x4*>(B3 + c);
#pragma unroll
    for (int rr = 0; rr < 8; ++rr) acc3[rr] = bv;
    for (int k0 = 0; k0 < 128; k0 += 4) {
      f32x4 w0 = *reinterpret_cast<const f32x4*>(W3 + (size_t)(k0 + 0) * 128 + c);
      f32x4 w1 = *reinterpret_cast<const f32x4*>(W3 + (size_t)(k0 + 1) * 128 + c);
      f32x4 w2v = *reinterpret_cast<const f32x4*>(W3 + (size_t)(k0 + 2) * 128 + c);
      f32x4 w3v = *reinterpret_cast<const f32x4*>(W3 + (size_t)(k0 + 3) * 128 + c);
#pragma unroll
      for (int rr = 0; rr < 8; ++rr) {
        f32x4 h = *reinterpret_cast<const f32x4*>(&h2[(rbase + rr) * 128 + k0]);
        acc3[rr] += h.x * w0 + h.y * w1 + h.z * w2v + h.w * w3v;
      }
    }
#pragma unroll
    for (int rr = 0; rr < 8; ++rr)
      *reinterpret_cast<f32x4*>(out + (size_t)(row0 + rbase + rr) * 128 + c) = acc3[rr];
  }
}

// ---------------------------------------------------------------------------
// kernel_launch
// ---------------------------------------------------------------------------
extern "C" void kernel_launch(void* const* d_in, const int* in_sizes, int n_in,
                              void* d_out, int out_size, void* d_ws,
                              size_t ws_size, hipStream_t stream) {
  const float* operations = (const float*)d_in[0];
  const float* items      = (const float*)d_in[1];
  const float* materials  = (const float*)d_in[2];
  const float* resources  = (const float*)d_in[3];
  const int* related      = (const int*)d_in[4];
  const int* res_op       = (const int*)d_in[5];
  const int* res_res      = (const int*)d_in[6];
  const int* mat_op       = (const int*)d_in[7];
  const int* mat_mat      = (const int*)d_in[8];
  const int* prec_src     = (const int*)d_in[9];
  const int* prec_dst     = (const int*)d_in[10];
  const float* w_self1 = (const float*)d_in[11];
  const float* b_self1 = (const float*)d_in[12];
  const float* w_self2 = (const float*)d_in[13];
  const float* b_self2 = (const float*)d_in[14];
  const float* w_item1 = (const float*)d_in[15];
  const float* b_item1 = (const float*)d_in[16];
  const float* w_item2 = (const float*)d_in[17];
  const float* b_item2 = (const float*)d_in[18];
  const float* w_pred1 = (const float*)d_in[19];
  const float* b_pred1 = (const float*)d_in[20];
  const float* w_pred2 = (const float*)d_in[21];
  const float* b_pred2 = (const float*)d_in[22];
  const float* w_succ1 = (const float*)d_in[23];
  const float* b_succ1 = (const float*)d_in[24];
  const float* w_succ2 = (const float*)d_in[25];
  const float* b_succ2 = (const float*)d_in[26];
  const float* w_res1  = (const float*)d_in[27];
  const float* b_res1  = (const float*)d_in[28];
  const float* w_res2  = (const float*)d_in[29];
  const float* b_res2  = (const float*)d_in[30];
  const float* w_mat1  = (const float*)d_in[31];
  const float* b_mat1  = (const float*)d_in[32];
  const float* w_mat2  = (const float*)d_in[33];
  const float* b_mat2  = (const float*)d_in[34];
  const float* w_c1    = (const float*)d_in[35];
  const float* b_c1    = (const float*)d_in[36];
  const float* w_c2    = (const float*)d_in[37];
  const float* b_c2    = (const float*)d_in[38];
  const float* w_c3    = (const float*)d_in[39];
  const float* b_c3    = (const float*)d_in[40];

  const int N = in_sizes[0] / 128;   // 50000
  const int NI = in_sizes[1] / 128;  // 20000
  const int E_RES = in_sizes[5];
  const int E_MAT = in_sizes[7];
  const int E_PREC = in_sizes[9];

  // ---- ws layout ----
  size_t off = 0;
  auto take = [&](size_t bytes) {
    size_t o = off;
    off += (bytes + 63) & ~(size_t)63;
    return o;
  };
  size_t xbuf_off  = take((size_t)N * 608 * 2);
  size_t aggp_off  = take((size_t)N * 128 * 2);
  size_t aggsu_off = take((size_t)N * 128 * 2);
  size_t aggr_off  = take((size_t)N * 64 * 2);
  size_t aggm_off  = take((size_t)N * 32 * 2);
  size_t wf_off    = take((size_t)499712 * 2);
  size_t opsb_off  = take((size_t)N * 128 * 2);
  size_t itemb_off = take((size_t)NI * 128 * 2);
  size_t offs_off  = take((size_t)4 * (N + 1) * 4);
  size_t tmp_off   = take((size_t)4 * N * 4);
  size_t cols_off  = take(((size_t)2 * E_PREC + E_RES + E_MAT) * 4);

  char* ws = (char*)d_ws;
  bf16* xbuf = (bf16*)(ws + xbuf_off);
  bf16* agg_pred = (bf16*)(ws + aggp_off);
  bf16* agg_succ = (bf16*)(ws + aggsu_off);
  bf16* agg_res  = (bf16*)(ws + aggr_off);
  bf16* agg_mat  = (bf16*)(ws + aggm_off);
  short* wf = (short*)(ws + wf_off);
  bf16* ops_bf   = (bf16*)(ws + opsb_off);
  bf16* items_bf = (bf16*)(ws + itemb_off);
  int* offs = (int*)(ws + offs_off);
  int* tmp  = (int*)(ws + tmp_off);
  int* cols = (int*)(ws + cols_off);

  int* offs_pred = offs;
  int* offs_succ = offs + (N + 1);
  int* offs_res  = offs + 2 * (N + 1);
  int* offs_mat  = offs + 3 * (N + 1);
  int* cur_pred = tmp;
  int* cur_succ = tmp + N;
  int* cur_res  = tmp + 2 * N;
  int* cur_mat  = tmp + 3 * N;
  int* col_pred = cols;
  int* col_succ = col_pred + E_PREC;
  int* col_res  = col_succ + E_PREC;
  int* col_mat  = col_res + E_RES;

  dim3 blk(256);

  // ---- bf16 tables ----
  cvt_bf16_kernel<<<(N * 128 / 4 + 255) / 256, blk, 0, stream>>>(operations, ops_bf, N * 128 / 4);
  cvt_bf16_kernel<<<(NI * 128 / 4 + 255) / 256, blk, 0, stream>>>(items, items_bf, NI * 128 / 4);

  // ---- weight fragments ----
  WDescs14 wd;
  wd.w[0]  = {w_self1, 128, 256, 0};
  wd.w[1]  = {w_item1, 128, 256, 32768};
  wd.w[2]  = {w_pred1, 128, 256, 65536};
  wd.w[3]  = {w_succ1, 128, 256, 98304};
  wd.w[4]  = {w_res1,   64, 256, 131072};
  wd.w[5]  = {w_mat1,   32, 256, 147456};
  wd.w[6]  = {w_self2, 256, 128, 155648};
  wd.w[7]  = {w_item2, 256, 128, 188416};
  wd.w[8]  = {w_pred2, 256, 128, 221184};
  wd.w[9]  = {w_succ2, 256, 128, 253952};
  wd.w[10] = {w_res2,  256,  64, 286720};
  wd.w[11] = {w_mat2,  256,  32, 303104};
  wd.w[12] = {w_c1,    608, 256, 311296};
  wd.w[13] = {w_c2,    256, 128, 466944};
  wconv_kernel<<<dim3(76, 14), blk, 0, stream>>>(wd, wf);

  // ---- CSR build ----
  (void)hipMemsetAsync(tmp, 0, 4 * (size_t)N * sizeof(int), stream);
  EdgeLists4 els;
  els.l[0] = {prec_src, prec_dst, cur_pred, col_pred, E_PREC};
  els.l[1] = {prec_dst, prec_src, cur_succ, col_succ, E_PREC};
  els.l[2] = {res_op, res_res, cur_res, col_res, E_RES};
  els.l[3] = {mat_op, mat_mat, cur_mat, col_mat, E_MAT};
  int cgx = (E_PREC + 255) / 256;
  count4_kernel<<<dim3(cgx, 4), blk, 0, stream>>>(els);
  scan4_kernel<<<4, 1024, 0, stream>>>(tmp, offs, N);
  cursor_copy_kernel<<<(4 * N + 255) / 256, blk, 0, stream>>>(offs, tmp, N);
  fill4_kernel<<<dim3(cgx, 4), blk, 0, stream>>>(els);

  // ---- aggregates ----
  csr_agg128_kernel<<<dim3((N + 3) / 4, 2), blk, 0, stream>>>(
      ops_bf, col_pred, col_succ, offs_pred, offs_succ, agg_pred, agg_succ, N);
  csr_agg_kernel<64, 32><<<(N + 7) / 8, blk, 0, stream>>>(resources, col_res, offs_res, agg_res, N);
  csr_agg_kernel<32, 16><<<(N + 15) / 16, blk, 0, stream>>>(materials, col_mat, offs_mat, agg_mat, N);

  // ---- 6 MLPs in one launch ----
  int ntiles = N / 16;           // 3125
  int mgrid = (ntiles + 3) / 4;  // 782
  Mlp6Args ma;
  ma.agg_pred = agg_pred; ma.agg_succ = agg_succ; ma.agg_res = agg_res; ma.agg_mat = agg_mat;
  ma.items_bf = items_bf; ma.ops_bf = ops_bf; ma.related = related; ma.wf = wf;
  ma.b_pred1 = b_pred1; ma.b_pred2 = b_pred2; ma.b_succ1 = b_succ1; ma.b_succ2 = b_succ2;
  ma.b_res1 = b_res1; ma.b_res2 = b_res2; ma.b_mat1 = b_mat1; ma.b_mat2 = b_mat2;
  ma.b_item1 = b_item1; ma.b_item2 = b_item2; ma.b_self1 = b_self1; ma.b_self2 = b_self2;
  ma.xbuf = xbuf; ma.ntiles = ntiles;
  mlp6_kernel<<<dim3(mgrid, 6), blk, 0, stream>>>(ma);

  // ---- final combiner ----
  final_kernel<<<mgrid, blk, 0, stream>>>(
      xbuf, wf + 311296, b_c1, wf + 466944, b_c2, w_c3, b_c3, (float*)d_out, ntiles);
}

// Round 12
// 596.070 us; speedup vs baseline: 7.3390x; 1.0509x over previous
//
#include <hip/hip_runtime.h>
#include <hip/hip_bf16.h>

typedef __attribute__((ext_vector_type(8))) short short8;
typedef __attribute__((ext_vector_type(4))) float f32x4;
using bf16 = __hip_bfloat16;

// N=50000, OP=128, H=256, H2=128, OUT=128
// xbuf concat: [pred 0 | succ 128 | res 256 | mat 320 | item 352 | self 480], 608

__device__ __forceinline__ short f2bf(float f) {
  union { float f; unsigned u; } v; v.f = f;
  unsigned r = (v.u + 0x7fffu + ((v.u >> 16) & 1u)) >> 16;  // RNE
  return (short)r;
}
__device__ __forceinline__ float bf2f(short s) {
  union { unsigned u; float f; } x;
  x.u = ((unsigned)(unsigned short)s) << 16;
  return x.f;
}

// ---------------------------------------------------------------------------
// f32 -> bf16 table conversion
// ---------------------------------------------------------------------------
__global__ __launch_bounds__(256) void cvt_bf16_kernel(
    const float* __restrict__ src, bf16* __restrict__ dst, int n4) {
  int i = blockIdx.x * 256 + threadIdx.x;
  if (i >= n4) return;
  f32x4 v = *reinterpret_cast<const f32x4*>(src + (size_t)i * 4);
  uint2 u;
  u.x = (unsigned)(unsigned short)f2bf(v.x) | ((unsigned)(unsigned short)f2bf(v.y) << 16);
  u.y = (unsigned)(unsigned short)f2bf(v.z) | ((unsigned)(unsigned short)f2bf(v.w) << 16);
  *reinterpret_cast<uint2*>(dst + (size_t)i * 4) = u;
}

// ---------------------------------------------------------------------------
// CSR build: merged count / parallel scan / merged fill
// ---------------------------------------------------------------------------
struct EdgeList { const int* dst; const int* src; int* counts; int* col; int E; };
struct EdgeLists4 { EdgeList l[4]; };

__global__ __launch_bounds__(256) void count4_kernel(EdgeLists4 ls) {
  EdgeList l = ls.l[blockIdx.y];
  int e = blockIdx.x * 256 + threadIdx.x;
  if (e < l.E) atomicAdd(&l.counts[l.dst[e]], 1);
}

// (legacy serial scan kept unlaunched to minimize codegen-context diff)
__global__ __launch_bounds__(1024) void scan4_kernel(
    const int* __restrict__ counts, int* __restrict__ offsets, int n) {
  const int* cnt = counts + (size_t)blockIdx.x * n;
  int* offs = offsets + (size_t)blockIdx.x * (n + 1);
  __shared__ int wsum[16];
  __shared__ int carry_s;
  const int lane = threadIdx.x & 63;
  const int wid = threadIdx.x >> 6;
  if (threadIdx.x == 0) carry_s = 0;
  __syncthreads();
  for (int base = 0; base < n; base += 1024) {
    int i = base + threadIdx.x;
    int v = (i < n) ? cnt[i] : 0;
    int x = v;
#pragma unroll
    for (int off = 1; off < 64; off <<= 1) {
      int t = __shfl_up(x, off, 64);
      if (lane >= off) x += t;
    }
    if (lane == 63) wsum[wid] = x;
    __syncthreads();
    if (wid == 0 && lane < 16) {
      int w = wsum[lane];
#pragma unroll
      for (int off = 1; off < 16; off <<= 1) {
        int t = __shfl_up(w, off, 16);
        if (lane >= off) w += t;
      }
      wsum[lane] = w;
    }
    __syncthreads();
    int carry = carry_s;
    int wpre = (wid == 0) ? 0 : wsum[wid - 1];
    if (i < n) offs[i] = carry + wpre + x - v;
    __syncthreads();
    if (threadIdx.x == 1023) carry_s = carry + wsum[15];
    __syncthreads();
  }
  if (threadIdx.x == 0) offs[n] = carry_s;
}

__global__ __launch_bounds__(256) void cursor_copy_kernel(
    const int* __restrict__ offsets, int* __restrict__ cursor, int n) {
  int i = blockIdx.x * 256 + threadIdx.x;
  if (i < 4 * n) {
    int t = i / n, j = i - t * n;
    cursor[(size_t)t * n + j] = offsets[(size_t)t * (n + 1) + j];
  }
}

// ---- parallel scan, phase B: per-1024-chunk sums for the 4 count arrays ----
__global__ __launch_bounds__(256) void chunksum_kernel(
    const int* __restrict__ counts, int* __restrict__ bsum, int n, int nchunk) {
  const int t = blockIdx.y;
  const int* cnt = counts + (size_t)t * n;
  int base = blockIdx.x * 1024;
  int s = 0;
  for (int j = threadIdx.x; j < 1024; j += 256) {
    int i = base + j;
    if (i < n) s += cnt[i];
  }
#pragma unroll
  for (int off = 32; off > 0; off >>= 1) s += __shfl_down(s, off, 64);
  __shared__ int ws[4];
  const int lane = threadIdx.x & 63, wid = threadIdx.x >> 6;
  if (lane == 0) ws[wid] = s;
  __syncthreads();
  if (threadIdx.x == 0)
    bsum[(size_t)t * nchunk + blockIdx.x] = ws[0] + ws[1] + ws[2] + ws[3];
}

// ---- phase C: exclusive-scan the chunk sums (nchunk <= 64), 1 wave/list ----
__global__ __launch_bounds__(256) void scanchunks_kernel(
    int* __restrict__ bsum, int* __restrict__ offsets, int n, int nchunk) {
  const int t = threadIdx.x >> 6, lane = threadIdx.x & 63;
  int v = (lane < nchunk) ? bsum[(size_t)t * nchunk + lane] : 0;
  int x = v;
#pragma unroll
  for (int off = 1; off < 64; off <<= 1) {
    int u = __shfl_up(x, off, 64);
    if (lane >= off) x += u;
  }
  if (lane < nchunk) bsum[(size_t)t * nchunk + lane] = x - v;  // exclusive
  if (lane == nchunk - 1) offsets[(size_t)t * (n + 1) + n] = x;  // total
}

// ---- phase D: intra-chunk scan + chunk base; writes offs AND cursor ----
__global__ __launch_bounds__(1024) void scanfinal_kernel(
    const int* __restrict__ counts, const int* __restrict__ bsum,
    int* __restrict__ offsets, int* __restrict__ cursor, int n, int nchunk) {
  const int t = blockIdx.y;
  const int* cnt = counts + (size_t)t * n;
  __shared__ int wsum[16];
  const int lane = threadIdx.x & 63, wid = threadIdx.x >> 6;
  int i = blockIdx.x * 1024 + threadIdx.x;
  int v = (i < n) ? cnt[i] : 0;
  int x = v;
#pragma unroll
  for (int off = 1; off < 64; off <<= 1) {
    int u = __shfl_up(x, off, 64);
    if (lane >= off) x += u;
  }
  if (lane == 63) wsum[wid] = x;
  __syncthreads();
  if (wid == 0 && lane < 16) {
    int w = wsum[lane];
#pragma unroll
    for (int off = 1; off < 16; off <<= 1) {
      int u = __shfl_up(w, off, 16);
      if (lane >= off) w += u;
    }
    wsum[lane] = w;
  }
  __syncthreads();
  int wpre = (wid == 0) ? 0 : wsum[wid - 1];
  int val = bsum[(size_t)t * nchunk + blockIdx.x] + wpre + x - v;
  if (i < n) {
    offsets[(size_t)t * (n + 1) + i] = val;
    cursor[(size_t)t * n + i] = val;   // same storage as counts; 1 owner/addr
  }
}

__global__ __launch_bounds__(256) void fill4_kernel(EdgeLists4 ls) {
  EdgeList l = ls.l[blockIdx.y];
  int e = blockIdx.x * 256 + threadIdx.x;
  if (e < l.E) {
    int p = atomicAdd(&l.counts[l.dst[e]], 1);  // counts == cursor at this stage
    l.col[p] = l.src[e];
  }
}

// ---------------------------------------------------------------------------
// Pred/succ aggregate from bf16 ops table: 1 wave/row, 16 edges in flight
// (4 accumulator sets; 8- and masked-4-edge remainders).
// ---------------------------------------------------------------------------
__global__ __launch_bounds__(256) void csr_agg128_kernel(
    const bf16* __restrict__ tab,
    const int* __restrict__ col0, const int* __restrict__ col1,
    const int* __restrict__ offs0, const int* __restrict__ offs1,
    bf16* __restrict__ out0, bf16* __restrict__ out1, int n) {
  const int* col = blockIdx.y ? col1 : col0;
  const int* offs = blockIdx.y ? offs1 : offs0;
  bf16* out = blockIdx.y ? out1 : out0;
  const int lane = threadIdx.x & 63;
  const int wid = threadIdx.x >> 6;
  const int r = blockIdx.x * 4 + wid;
  if (r >= n) return;
  const int slot = lane >> 4, lp = lane & 15;
  const int beg = offs[r], end = offs[r + 1];
  float acc[8] = {0.f, 0.f, 0.f, 0.f, 0.f, 0.f, 0.f, 0.f};
  float acc2[8] = {0.f, 0.f, 0.f, 0.f, 0.f, 0.f, 0.f, 0.f};
  float acc3[8] = {0.f, 0.f, 0.f, 0.f, 0.f, 0.f, 0.f, 0.f};
  float acc4[8] = {0.f, 0.f, 0.f, 0.f, 0.f, 0.f, 0.f, 0.f};
  int e = beg;
  for (; e + 16 <= end; e += 16) {
    int c0 = col[e + slot];
    int c1 = col[e + 4 + slot];
    int c2 = col[e + 8 + slot];
    int c3 = col[e + 12 + slot];
    short8 v0 = *reinterpret_cast<const short8*>(tab + (size_t)c0 * 128 + lp * 8);
    short8 v1 = *reinterpret_cast<const short8*>(tab + (size_t)c1 * 128 + lp * 8);
    short8 v2 = *reinterpret_cast<const short8*>(tab + (size_t)c2 * 128 + lp * 8);
    short8 v3 = *reinterpret_cast<const short8*>(tab + (size_t)c3 * 128 + lp * 8);
#pragma unroll
    for (int j = 0; j < 8; ++j) {
      acc[j] += bf2f(v0[j]);
      acc2[j] += bf2f(v1[j]);
      acc3[j] += bf2f(v2[j]);
      acc4[j] += bf2f(v3[j]);
    }
  }
  for (; e + 8 <= end; e += 8) {
    int c0 = col[e + slot];
    int c1 = col[e + 4 + slot];
    short8 v0 = *reinterpret_cast<const short8*>(tab + (size_t)c0 * 128 + lp * 8);
    short8 v1 = *reinterpret_cast<const short8*>(tab + (size_t)c1 * 128 + lp * 8);
#pragma unroll
    for (int j = 0; j < 8; ++j) {
      acc[j] += bf2f(v0[j]);
      acc2[j] += bf2f(v1[j]);
    }
  }
  for (; e < end; e += 4) {
    int idx = e + slot;
    if (idx < end) {
      int cc = col[idx];
      short8 v = *reinterpret_cast<const short8*>(tab + (size_t)cc * 128 + lp * 8);
#pragma unroll
      for (int j = 0; j < 8; ++j) acc[j] += bf2f(v[j]);
    }
  }
#pragma unroll
  for (int j = 0; j < 8; ++j) acc[j] = (acc[j] + acc2[j]) + (acc3[j] + acc4[j]);
#pragma unroll
  for (int j = 0; j < 8; ++j) {
    acc[j] += __shfl_xor(acc[j], 16, 64);
    acc[j] += __shfl_xor(acc[j], 32, 64);
  }
  if (slot == 0) {
    short8 sv;
#pragma unroll
    for (int j = 0; j < 8; ++j) sv[j] = f2bf(acc[j]);
    *reinterpret_cast<short8*>(out + (size_t)r * 128 + lp * 8) = sv;
  }
}

// ---------------------------------------------------------------------------
// Small CSR aggregate (res/mat) from f32 tables -> bf16 out
// ---------------------------------------------------------------------------
template <int D, int LPR>
__global__ __launch_bounds__(256) void csr_agg_kernel(
    const float* __restrict__ tab, const int* __restrict__ col,
    const int* __restrict__ offsets, bf16* __restrict__ out, int n) {
  constexpr int RPB = 256 / LPR;
  const int lane = threadIdx.x % LPR;
  const int r = blockIdx.x * RPB + threadIdx.x / LPR;
  if (r >= n) return;
  const int beg = offsets[r], end = offsets[r + 1];
  float2 acc = make_float2(0.f, 0.f);
  for (int e = beg; e < end; ++e) {
    int s = col[e];
    float2 v = *reinterpret_cast<const float2*>(tab + (size_t)s * D + lane * 2);
    acc.x += v.x;
    acc.y += v.y;
  }
  unsigned u = (unsigned)(unsigned short)f2bf(acc.x) |
               ((unsigned)(unsigned short)f2bf(acc.y) << 16);
  *reinterpret_cast<unsigned*>(out + (size_t)r * D + lane * 2) = u;
}

// ---------------------------------------------------------------------------
// Weight -> MFMA B-fragment conversion
// frag[tile=kc*CT+ct][lane][j] = W[kc*32+(lane>>4)*8+j][ct*16+(lane&15)]
// ---------------------------------------------------------------------------
struct WDesc { const float* src; int K; int C; int dstoff; };
struct WDescs14 { WDesc w[14]; };

__global__ __launch_bounds__(256) void wconv_kernel(WDescs14 ds, short* __restrict__ dstbase) {
  WDesc d = ds.w[blockIdx.y];
  int KC = d.K >> 5, CT = d.C >> 4;
  int t = blockIdx.x * 256 + threadIdx.x;
  if (t >= KC * CT * 64) return;
  int lane = t & 63, tile = t >> 6;
  int kc = tile / CT, ct = tile - kc * CT;
  int g = lane >> 4, lp = lane & 15;
  short8 v;
#pragma unroll
  for (int j = 0; j < 8; ++j)
    v[j] = f2bf(d.src[(size_t)(kc * 32 + g * 8 + j) * d.C + ct * 16 + lp]);
  *reinterpret_cast<short8*>(dstbase + d.dstoff + (size_t)t * 8) = v;
}

// ---------------------------------------------------------------------------
// MFMA fused 2-layer MLP device body (bf16 in, bf16 out, wave-private LDS)
// FROZEN AT R8 — byte-for-byte. Do NOT restructure (R5/R6/R9/R10 all failed).
// ---------------------------------------------------------------------------
template <int K, int O, bool GATHER>
__device__ __forceinline__ void mlp2_dev(
    const bf16* __restrict__ X, const int* __restrict__ gidx,
    const short* __restrict__ W1f, const float* __restrict__ B1,
    const short* __restrict__ W2f, const float* __restrict__ B2,
    bf16* __restrict__ xbuf, int ooff, int tile, int lane, char* hw) {
  constexpr int KC = K / 32;
  constexpr int KC2 = 8;
  constexpr int OT = O / 16;
  const int g = lane >> 4, lp = lane & 15;
  const int row0 = tile * 16;

  short8 a[KC];
  {
    int srow = GATHER ? gidx[row0 + lp] : (row0 + lp);
    const bf16* xp = X + (size_t)srow * K + g * 8;
#pragma unroll
    for (int kc = 0; kc < KC; ++kc)
      a[kc] = *reinterpret_cast<const short8*>(xp + kc * 32);
  }

#pragma unroll
  for (int ct = 0; ct < 16; ++ct) {
    float bv = B1[ct * 16 + lp];
    f32x4 acc = {bv, bv, bv, bv};
#pragma unroll
    for (int kc = 0; kc < KC; ++kc) {
      short8 b = *reinterpret_cast<const short8*>(
          W1f + ((size_t)(kc * 16 + ct) * 64 + lane) * 8);
      acc = __builtin_amdgcn_mfma_f32_16x16x32_bf16(a[kc], b, acc, 0, 0, 0);
    }
#pragma unroll
    for (int r = 0; r < 4; ++r) {
      int rr = g * 4 + r;
      int byte = rr * 512 + (ct * 16 + lp) * 2;
      byte ^= (rr & 7) << 4;
      *reinterpret_cast<short*>(hw + byte) = f2bf(fmaxf(acc[r], 0.f));
    }
  }
  asm volatile("s_waitcnt lgkmcnt(0)" ::: "memory");
  __builtin_amdgcn_sched_barrier(0);

  short8 a2[KC2];
#pragma unroll
  for (int kc = 0; kc < KC2; ++kc) {
    int byte = lp * 512 + (kc * 32 + g * 8) * 2;
    byte ^= (lp & 7) << 4;
    a2[kc] = *reinterpret_cast<const short8*>(hw + byte);
  }
#pragma unroll
  for (int ot = 0; ot < OT; ++ot) {
    float bv = B2[ot * 16 + lp];
    f32x4 acc = {bv, bv, bv, bv};
#pragma unroll
    for (int kc = 0; kc < KC2; ++kc) {
      short8 b = *reinterpret_cast<const short8*>(
          W2f + ((size_t)(kc * OT + ot) * 64 + lane) * 8);
      acc = __builtin_amdgcn_mfma_f32_16x16x32_bf16(a2[kc], b, acc, 0, 0, 0);
    }
#pragma unroll
    for (int r = 0; r < 4; ++r) {
      int rr = g * 4 + r;
      *reinterpret_cast<short*>(xbuf + (size_t)(row0 + rr) * 608 + ooff + ot * 16 + lp) =
          f2bf(acc[r]);
    }
  }
}

struct Mlp6Args {
  const bf16 *agg_pred, *agg_succ, *agg_res, *agg_mat, *items_bf, *ops_bf;
  const int* related;
  const short* wf;
  const float *b_pred1, *b_pred2, *b_succ1, *b_succ2, *b_res1, *b_res2;
  const float *b_mat1, *b_mat2, *b_item1, *b_item2, *b_self1, *b_self2;
  bf16* xbuf;
  int ntiles;
};

__global__ __launch_bounds__(256) void mlp6_kernel(Mlp6Args A) {
  __shared__ short hbuf[4 * 16 * 256];  // 32 KB, 8 KB/wave
  const int lane = threadIdx.x & 63, wid = threadIdx.x >> 6;
  int tile = blockIdx.x * 4 + wid;
  if (tile >= A.ntiles) tile = A.ntiles - 1;  // dup benign
  char* hw = (char*)(hbuf + wid * (16 * 256));
  const short* wf = A.wf;
  switch (blockIdx.y) {
    case 0: mlp2_dev<128, 128, false>(A.agg_pred, nullptr, wf + 65536, A.b_pred1,
                                      wf + 221184, A.b_pred2, A.xbuf, 0, tile, lane, hw); break;
    case 1: mlp2_dev<128, 128, false>(A.agg_succ, nullptr, wf + 98304, A.b_succ1,
                                      wf + 253952, A.b_succ2, A.xbuf, 128, tile, lane, hw); break;
    case 2: mlp2_dev<64, 64, false>(A.agg_res, nullptr, wf + 131072, A.b_res1,
                                    wf + 286720, A.b_res2, A.xbuf, 256, tile, lane, hw); break;
    case 3: mlp2_dev<32, 32, false>(A.agg_mat, nullptr, wf + 147456, A.b_mat1,
                                    wf + 303104, A.b_mat2, A.xbuf, 320, tile, lane, hw); break;
    case 4: mlp2_dev<128, 128, true>(A.items_bf, A.related, wf + 32768, A.b_item1,
                                     wf + 188416, A.b_item2, A.xbuf, 352, tile, lane, hw); break;
    default: mlp2_dev<128, 128, false>(A.ops_bf, nullptr, wf + 0, A.b_self1,
                                       wf + 155648, A.b_self2, A.xbuf, 480, tile, lane, hw); break;
  }
}

// ---------------------------------------------------------------------------
// Final combiner: FROZEN AT R8 — byte-for-byte.
// ---------------------------------------------------------------------------
__global__ __launch_bounds__(256, 4) void final_kernel(
    const bf16* __restrict__ xbuf,
    const short* __restrict__ Wc1f, const float* __restrict__ B1,
    const short* __restrict__ Wc2f, const float* __restrict__ B2,
    const float* __restrict__ W3, const float* __restrict__ B3,
    float* __restrict__ out, int ntiles) {
  __shared__ short hbuf[4 * 16 * 256];  // 32 KB: per-wave h1 bf16, then h2 f32 aliased
  const int lane = threadIdx.x & 63, wid = threadIdx.x >> 6;
  int tile = blockIdx.x * 4 + wid;
  if (tile >= ntiles) tile = ntiles - 1;
  const int g = lane >> 4, lp = lane & 15;
  const int row0 = tile * 16;
  char* hw = (char*)(hbuf + wid * (16 * 256));

  // ---- L1: h1 = relu(x @ Wc1 + b1), 608->256, MFMA ----
  {
    const bf16* xp = xbuf + (size_t)(row0 + lp) * 608 + g * 8;
    short8 a[19];
#pragma unroll
    for (int kc = 0; kc < 19; ++kc)
      a[kc] = *reinterpret_cast<const short8*>(xp + kc * 32);
#pragma unroll
    for (int ct = 0; ct < 16; ++ct) {
      float bv = B1[ct * 16 + lp];
      f32x4 acc = {bv, bv, bv, bv};
#pragma unroll
      for (int kc = 0; kc < 19; ++kc) {
        short8 b = *reinterpret_cast<const short8*>(
            Wc1f + ((size_t)(kc * 16 + ct) * 64 + lane) * 8);
        acc = __builtin_amdgcn_mfma_f32_16x16x32_bf16(a[kc], b, acc, 0, 0, 0);
      }
#pragma unroll
      for (int r = 0; r < 4; ++r) {
        int rr = g * 4 + r;
        int byte = rr * 512 + (ct * 16 + lp) * 2;
        byte ^= (rr & 7) << 4;
        *reinterpret_cast<short*>(hw + byte) = f2bf(fmaxf(acc[r], 0.f));
      }
    }
  }
  asm volatile("s_waitcnt lgkmcnt(0)" ::: "memory");
  __builtin_amdgcn_sched_barrier(0);

  // ---- L2: h2 = relu(h1 @ Wc2 + b2), 256->128, MFMA ----
  {
    short8 a2[8];
#pragma unroll
    for (int kc = 0; kc < 8; ++kc) {
      int byte = lp * 512 + (kc * 32 + g * 8) * 2;
      byte ^= (lp & 7) << 4;
      a2[kc] = *reinterpret_cast<const short8*>(hw + byte);
    }
    asm volatile("s_waitcnt lgkmcnt(0)" ::: "memory");
    __builtin_amdgcn_sched_barrier(0);
    float* h2 = (float*)hw;  // alias over h1 (a2 fully in regs)
#pragma unroll
    for (int ot = 0; ot < 8; ++ot) {
      float bv = B2[ot * 16 + lp];
      f32x4 acc = {bv, bv, bv, bv};
#pragma unroll
      for (int kc = 0; kc < 8; ++kc) {
        short8 b = *reinterpret_cast<const short8*>(
            Wc2f + ((size_t)(kc * 8 + ot) * 64 + lane) * 8);
        acc = __builtin_amdgcn_mfma_f32_16x16x32_bf16(a2[kc], b, acc, 0, 0, 0);
      }
#pragma unroll
      for (int r = 0; r < 4; ++r)
        h2[(g * 4 + r) * 128 + ot * 16 + lp] = fmaxf(acc[r], 0.f);
    }
  }
  asm volatile("s_waitcnt lgkmcnt(0)" ::: "memory");
  __builtin_amdgcn_sched_barrier(0);

  // ---- L3: out = h2 @ W3 + b3, f32 VALU (precision-critical) ----
  {
    const float* h2 = (const float*)hw;
    const int half = lane >> 5;
    const int c = (lane & 31) * 4;
    const int rbase = half * 8;
    f32x4 acc3[8];
    f32x4 bv = *reinterpret_cast<const f32x4*>(B3 + c);
#pragma unroll
    for (int rr = 0; rr < 8; ++rr) acc3[rr] = bv;
    for (int k0 = 0; k0 < 128; k0 += 4) {
      f32x4 w0 = *reinterpret_cast<const f32x4*>(W3 + (size_t)(k0 + 0) * 128 + c);
      f32x4 w1 = *reinterpret_cast<const f32x4*>(W3 + (size_t)(k0 + 1) * 128 + c);
      f32x4 w2v = *reinterpret_cast<const f32x4*>(W3 + (size_t)(k0 + 2) * 128 + c);
      f32x4 w3v = *reinterpret_cast<const f32x4*>(W3 + (size_t)(k0 + 3) * 128 + c);
#pragma unroll
      for (int rr = 0; rr < 8; ++rr) {
        f32x4 h = *reinterpret_cast<const f32x4*>(&h2[(rbase + rr) * 128 + k0]);
        acc3[rr] += h.x * w0 + h.y * w1 + h.z * w2v + h.w * w3v;
      }
    }
#pragma unroll
    for (int rr = 0; rr < 8; ++rr)
      *reinterpret_cast<f32x4*>(out + (size_t)(row0 + rbase + rr) * 128 + c) = acc3[rr];
  }
}

// ---------------------------------------------------------------------------
// kernel_launch
// ---------------------------------------------------------------------------
extern "C" void kernel_launch(void* const* d_in, const int* in_sizes, int n_in,
                              void* d_out, int out_size, void* d_ws,
                              size_t ws_size, hipStream_t stream) {
  const float* operations = (const float*)d_in[0];
  const float* items      = (const float*)d_in[1];
  const float* materials  = (const float*)d_in[2];
  const float* resources  = (const float*)d_in[3];
  const int* related      = (const int*)d_in[4];
  const int* res_op       = (const int*)d_in[5];
  const int* res_res      = (const int*)d_in[6];
  const int* mat_op       = (const int*)d_in[7];
  const int* mat_mat      = (const int*)d_in[8];
  const int* prec_src     = (const int*)d_in[9];
  const int* prec_dst     = (const int*)d_in[10];
  const float* w_self1 = (const float*)d_in[11];
  const float* b_self1 = (const float*)d_in[12];
  const float* w_self2 = (const float*)d_in[13];
  const float* b_self2 = (const float*)d_in[14];
  const float* w_item1 = (const float*)d_in[15];
  const float* b_item1 = (const float*)d_in[16];
  const float* w_item2 = (const float*)d_in[17];
  const float* b_item2 = (const float*)d_in[18];
  const float* w_pred1 = (const float*)d_in[19];
  const float* b_pred1 = (const float*)d_in[20];
  const float* w_pred2 = (const float*)d_in[21];
  const float* b_pred2 = (const float*)d_in[22];
  const float* w_succ1 = (const float*)d_in[23];
  const float* b_succ1 = (const float*)d_in[24];
  const float* w_succ2 = (const float*)d_in[25];
  const float* b_succ2 = (const float*)d_in[26];
  const float* w_res1  = (const float*)d_in[27];
  const float* b_res1  = (const float*)d_in[28];
  const float* w_res2  = (const float*)d_in[29];
  const float* b_res2  = (const float*)d_in[30];
  const float* w_mat1  = (const float*)d_in[31];
  const float* b_mat1  = (const float*)d_in[32];
  const float* w_mat2  = (const float*)d_in[33];
  const float* b_mat2  = (const float*)d_in[34];
  const float* w_c1    = (const float*)d_in[35];
  const float* b_c1    = (const float*)d_in[36];
  const float* w_c2    = (const float*)d_in[37];
  const float* b_c2    = (const float*)d_in[38];
  const float* w_c3    = (const float*)d_in[39];
  const float* b_c3    = (const float*)d_in[40];

  const int N = in_sizes[0] / 128;   // 50000
  const int NI = in_sizes[1] / 128;  // 20000
  const int E_RES = in_sizes[5];
  const int E_MAT = in_sizes[7];
  const int E_PREC = in_sizes[9];

  // ---- ws layout ----
  size_t off = 0;
  auto take = [&](size_t bytes) {
    size_t o = off;
    off += (bytes + 63) & ~(size_t)63;
    return o;
  };
  size_t xbuf_off  = take((size_t)N * 608 * 2);
  size_t aggp_off  = take((size_t)N * 128 * 2);
  size_t aggsu_off = take((size_t)N * 128 * 2);
  size_t aggr_off  = take((size_t)N * 64 * 2);
  size_t aggm_off  = take((size_t)N * 32 * 2);
  size_t wf_off    = take((size_t)499712 * 2);
  size_t opsb_off  = take((size_t)N * 128 * 2);
  size_t itemb_off = take((size_t)NI * 128 * 2);
  size_t offs_off  = take((size_t)4 * (N + 1) * 4);
  size_t tmp_off   = take((size_t)4 * N * 4);
  size_t cols_off  = take(((size_t)2 * E_PREC + E_RES + E_MAT) * 4);
  size_t bsum_off  = take((size_t)4 * 64 * 4);

  char* ws = (char*)d_ws;
  bf16* xbuf = (bf16*)(ws + xbuf_off);
  bf16* agg_pred = (bf16*)(ws + aggp_off);
  bf16* agg_succ = (bf16*)(ws + aggsu_off);
  bf16* agg_res  = (bf16*)(ws + aggr_off);
  bf16* agg_mat  = (bf16*)(ws + aggm_off);
  short* wf = (short*)(ws + wf_off);
  bf16* ops_bf   = (bf16*)(ws + opsb_off);
  bf16* items_bf = (bf16*)(ws + itemb_off);
  int* offs = (int*)(ws + offs_off);
  int* tmp  = (int*)(ws + tmp_off);
  int* cols = (int*)(ws + cols_off);
  int* bsum = (int*)(ws + bsum_off);

  int* offs_pred = offs;
  int* offs_succ = offs + (N + 1);
  int* offs_res  = offs + 2 * (N + 1);
  int* offs_mat  = offs + 3 * (N + 1);
  int* cur_pred = tmp;
  int* cur_succ = tmp + N;
  int* cur_res  = tmp + 2 * N;
  int* cur_mat  = tmp + 3 * N;
  int* col_pred = cols;
  int* col_succ = col_pred + E_PREC;
  int* col_res  = col_succ + E_PREC;
  int* col_mat  = col_res + E_RES;

  dim3 blk(256);

  // ---- bf16 tables ----
  cvt_bf16_kernel<<<(N * 128 / 4 + 255) / 256, blk, 0, stream>>>(operations, ops_bf, N * 128 / 4);
  cvt_bf16_kernel<<<(NI * 128 / 4 + 255) / 256, blk, 0, stream>>>(items, items_bf, NI * 128 / 4);

  // ---- weight fragments ----
  WDescs14 wd;
  wd.w[0]  = {w_self1, 128, 256, 0};
  wd.w[1]  = {w_item1, 128, 256, 32768};
  wd.w[2]  = {w_pred1, 128, 256, 65536};
  wd.w[3]  = {w_succ1, 128, 256, 98304};
  wd.w[4]  = {w_res1,   64, 256, 131072};
  wd.w[5]  = {w_mat1,   32, 256, 147456};
  wd.w[6]  = {w_self2, 256, 128, 155648};
  wd.w[7]  = {w_item2, 256, 128, 188416};
  wd.w[8]  = {w_pred2, 256, 128, 221184};
  wd.w[9]  = {w_succ2, 256, 128, 253952};
  wd.w[10] = {w_res2,  256,  64, 286720};
  wd.w[11] = {w_mat2,  256,  32, 303104};
  wd.w[12] = {w_c1,    608, 256, 311296};
  wd.w[13] = {w_c2,    256, 128, 466944};
  wconv_kernel<<<dim3(76, 14), blk, 0, stream>>>(wd, wf);

  // ---- CSR build ----
  (void)hipMemsetAsync(tmp, 0, 4 * (size_t)N * sizeof(int), stream);
  EdgeLists4 els;
  els.l[0] = {prec_src, prec_dst, cur_pred, col_pred, E_PREC};
  els.l[1] = {prec_dst, prec_src, cur_succ, col_succ, E_PREC};
  els.l[2] = {res_op, res_res, cur_res, col_res, E_RES};
  els.l[3] = {mat_op, mat_mat, cur_mat, col_mat, E_MAT};
  int cgx = (E_PREC + 255) / 256;
  count4_kernel<<<dim3(cgx, 4), blk, 0, stream>>>(els);
  int nchunk = (N + 1023) / 1024;  // 49
  chunksum_kernel<<<dim3(nchunk, 4), blk, 0, stream>>>(tmp, bsum, N, nchunk);
  scanchunks_kernel<<<1, blk, 0, stream>>>(bsum, offs, N, nchunk);
  scanfinal_kernel<<<dim3(nchunk, 4), dim3(1024), 0, stream>>>(tmp, bsum, offs, tmp, N, nchunk);
  fill4_kernel<<<dim3(cgx, 4), blk, 0, stream>>>(els);

  // ---- aggregates ----
  csr_agg128_kernel<<<dim3((N + 3) / 4, 2), blk, 0, stream>>>(
      ops_bf, col_pred, col_succ, offs_pred, offs_succ, agg_pred, agg_succ, N);
  csr_agg_kernel<64, 32><<<(N + 7) / 8, blk, 0, stream>>>(resources, col_res, offs_res, agg_res, N);
  csr_agg_kernel<32, 16><<<(N + 15) / 16, blk, 0, stream>>>(materials, col_mat, offs_mat, agg_mat, N);

  // ---- 6 MLPs in one launch ----
  int ntiles = N / 16;           // 3125
  int mgrid = (ntiles + 3) / 4;  // 782
  Mlp6Args ma;
  ma.agg_pred = agg_pred; ma.agg_succ = agg_succ; ma.agg_res = agg_res; ma.agg_mat = agg_mat;
  ma.items_bf = items_bf; ma.ops_bf = ops_bf; ma.related = related; ma.wf = wf;
  ma.b_pred1 = b_pred1; ma.b_pred2 = b_pred2; ma.b_succ1 = b_succ1; ma.b_succ2 = b_succ2;
  ma.b_res1 = b_res1; ma.b_res2 = b_res2; ma.b_mat1 = b_mat1; ma.b_mat2 = b_mat2;
  ma.b_item1 = b_item1; ma.b_item2 = b_item2; ma.b_self1 = b_self1; ma.b_self2 = b_self2;
  ma.xbuf = xbuf; ma.ntiles = ntiles;
  mlp6_kernel<<<dim3(mgrid, 6), blk, 0, stream>>>(ma);

  // ---- final combiner ----
  final_kernel<<<mgrid, blk, 0, stream>>>(
      xbuf, wf + 311296, b_c1, wf + 466944, b_c2, w_c3, b_c3, (float*)d_out, ntiles);
}

// Round 13
// 592.633 us; speedup vs baseline: 7.3816x; 1.0058x over previous
//
#include <hip/hip_runtime.h>
#include <hip/hip_bf16.h>

typedef __attribute__((ext_vector_type(8))) short short8;
typedef __attribute__((ext_vector_type(4))) float f32x4;
using bf16 = __hip_bfloat16;

// N=50000, OP=128, H=256, H2=128, OUT=128
// xbuf concat: [pred 0 | succ 128 | res 256 | mat 320 | item 352 | self 480], 608

__device__ __forceinline__ short f2bf(float f) {
  union { float f; unsigned u; } v; v.f = f;
  unsigned r = (v.u + 0x7fffu + ((v.u >> 16) & 1u)) >> 16;  // RNE
  return (short)r;
}
__device__ __forceinline__ float bf2f(short s) {
  union { unsigned u; float f; } x;
  x.u = ((unsigned)(unsigned short)s) << 16;
  return x.f;
}

// ---------------------------------------------------------------------------
// f32 -> bf16 table conversion (merged: y=0 ops, y=1 items)
// ---------------------------------------------------------------------------
__global__ __launch_bounds__(256) void cvt_bf16_kernel(
    const float* __restrict__ src, bf16* __restrict__ dst, int n4) {
  int i = blockIdx.x * 256 + threadIdx.x;
  if (i >= n4) return;
  f32x4 v = *reinterpret_cast<const f32x4*>(src + (size_t)i * 4);
  uint2 u;
  u.x = (unsigned)(unsigned short)f2bf(v.x) | ((unsigned)(unsigned short)f2bf(v.y) << 16);
  u.y = (unsigned)(unsigned short)f2bf(v.z) | ((unsigned)(unsigned short)f2bf(v.w) << 16);
  *reinterpret_cast<uint2*>(dst + (size_t)i * 4) = u;
}

__global__ __launch_bounds__(256) void cvt2_kernel(
    const float* __restrict__ s0, bf16* __restrict__ d0, int n40,
    const float* __restrict__ s1, bf16* __restrict__ d1, int n41) {
  const float* src = blockIdx.y ? s1 : s0;
  bf16* dst = blockIdx.y ? d1 : d0;
  int n4 = blockIdx.y ? n41 : n40;
  int i = blockIdx.x * 256 + threadIdx.x;
  if (i >= n4) return;
  f32x4 v = *reinterpret_cast<const f32x4*>(src + (size_t)i * 4);
  uint2 u;
  u.x = (unsigned)(unsigned short)f2bf(v.x) | ((unsigned)(unsigned short)f2bf(v.y) << 16);
  u.y = (unsigned)(unsigned short)f2bf(v.z) | ((unsigned)(unsigned short)f2bf(v.w) << 16);
  *reinterpret_cast<uint2*>(dst + (size_t)i * 4) = u;
}

// ---------------------------------------------------------------------------
// CSR build: merged count / parallel scan / merged fill
// ---------------------------------------------------------------------------
struct EdgeList { const int* dst; const int* src; int* counts; int* col; int E; };
struct EdgeLists4 { EdgeList l[4]; };

__global__ __launch_bounds__(256) void count4_kernel(EdgeLists4 ls) {
  EdgeList l = ls.l[blockIdx.y];
  int e = blockIdx.x * 256 + threadIdx.x;
  if (e < l.E) atomicAdd(&l.counts[l.dst[e]], 1);
}

// vectorized: 4 edges/thread
__global__ __launch_bounds__(256) void count4v_kernel(EdgeLists4 ls) {
  EdgeList l = ls.l[blockIdx.y];
  int e0 = (blockIdx.x * 256 + threadIdx.x) * 4;
  if (e0 + 4 <= l.E) {
    int4 d = *reinterpret_cast<const int4*>(l.dst + e0);
    atomicAdd(&l.counts[d.x], 1);
    atomicAdd(&l.counts[d.y], 1);
    atomicAdd(&l.counts[d.z], 1);
    atomicAdd(&l.counts[d.w], 1);
  } else {
    for (int e = e0; e < l.E; ++e) atomicAdd(&l.counts[l.dst[e]], 1);
  }
}

// (legacy serial scan kept unlaunched to minimize codegen-context diff)
__global__ __launch_bounds__(1024) void scan4_kernel(
    const int* __restrict__ counts, int* __restrict__ offsets, int n) {
  const int* cnt = counts + (size_t)blockIdx.x * n;
  int* offs = offsets + (size_t)blockIdx.x * (n + 1);
  __shared__ int wsum[16];
  __shared__ int carry_s;
  const int lane = threadIdx.x & 63;
  const int wid = threadIdx.x >> 6;
  if (threadIdx.x == 0) carry_s = 0;
  __syncthreads();
  for (int base = 0; base < n; base += 1024) {
    int i = base + threadIdx.x;
    int v = (i < n) ? cnt[i] : 0;
    int x = v;
#pragma unroll
    for (int off = 1; off < 64; off <<= 1) {
      int t = __shfl_up(x, off, 64);
      if (lane >= off) x += t;
    }
    if (lane == 63) wsum[wid] = x;
    __syncthreads();
    if (wid == 0 && lane < 16) {
      int w = wsum[lane];
#pragma unroll
      for (int off = 1; off < 16; off <<= 1) {
        int t = __shfl_up(w, off, 16);
        if (lane >= off) w += t;
      }
      wsum[lane] = w;
    }
    __syncthreads();
    int carry = carry_s;
    int wpre = (wid == 0) ? 0 : wsum[wid - 1];
    if (i < n) offs[i] = carry + wpre + x - v;
    __syncthreads();
    if (threadIdx.x == 1023) carry_s = carry + wsum[15];
    __syncthreads();
  }
  if (threadIdx.x == 0) offs[n] = carry_s;
}

__global__ __launch_bounds__(256) void cursor_copy_kernel(
    const int* __restrict__ offsets, int* __restrict__ cursor, int n) {
  int i = blockIdx.x * 256 + threadIdx.x;
  if (i < 4 * n) {
    int t = i / n, j = i - t * n;
    cursor[(size_t)t * n + j] = offsets[(size_t)t * (n + 1) + j];
  }
}

// ---- parallel scan, phase B: per-1024-chunk sums for the 4 count arrays ----
__global__ __launch_bounds__(256) void chunksum_kernel(
    const int* __restrict__ counts, int* __restrict__ bsum, int n, int nchunk) {
  const int t = blockIdx.y;
  const int* cnt = counts + (size_t)t * n;
  int base = blockIdx.x * 1024;
  int s = 0;
  for (int j = threadIdx.x; j < 1024; j += 256) {
    int i = base + j;
    if (i < n) s += cnt[i];
  }
#pragma unroll
  for (int off = 32; off > 0; off >>= 1) s += __shfl_down(s, off, 64);
  __shared__ int ws[4];
  const int lane = threadIdx.x & 63, wid = threadIdx.x >> 6;
  if (lane == 0) ws[wid] = s;
  __syncthreads();
  if (threadIdx.x == 0)
    bsum[(size_t)t * nchunk + blockIdx.x] = ws[0] + ws[1] + ws[2] + ws[3];
}

// ---- phase C: exclusive-scan the chunk sums (nchunk <= 64), 1 wave/list ----
__global__ __launch_bounds__(256) void scanchunks_kernel(
    int* __restrict__ bsum, int* __restrict__ offsets, int n, int nchunk) {
  const int t = threadIdx.x >> 6, lane = threadIdx.x & 63;
  int v = (lane < nchunk) ? bsum[(size_t)t * nchunk + lane] : 0;
  int x = v;
#pragma unroll
  for (int off = 1; off < 64; off <<= 1) {
    int u = __shfl_up(x, off, 64);
    if (lane >= off) x += u;
  }
  if (lane < nchunk) bsum[(size_t)t * nchunk + lane] = x - v;  // exclusive
  if (lane == nchunk - 1) offsets[(size_t)t * (n + 1) + n] = x;  // total
}

// ---- phase D: intra-chunk scan + chunk base; writes offs AND cursor ----
__global__ __launch_bounds__(1024) void scanfinal_kernel(
    const int* __restrict__ counts, const int* __restrict__ bsum,
    int* __restrict__ offsets, int* __restrict__ cursor, int n, int nchunk) {
  const int t = blockIdx.y;
  const int* cnt = counts + (size_t)t * n;
  __shared__ int wsum[16];
  const int lane = threadIdx.x & 63, wid = threadIdx.x >> 6;
  int i = blockIdx.x * 1024 + threadIdx.x;
  int v = (i < n) ? cnt[i] : 0;
  int x = v;
#pragma unroll
  for (int off = 1; off < 64; off <<= 1) {
    int u = __shfl_up(x, off, 64);
    if (lane >= off) x += u;
  }
  if (lane == 63) wsum[wid] = x;
  __syncthreads();
  if (wid == 0 && lane < 16) {
    int w = wsum[lane];
#pragma unroll
    for (int off = 1; off < 16; off <<= 1) {
      int u = __shfl_up(w, off, 16);
      if (lane >= off) w += u;
    }
    wsum[lane] = w;
  }
  __syncthreads();
  int wpre = (wid == 0) ? 0 : wsum[wid - 1];
  int val = bsum[(size_t)t * nchunk + blockIdx.x] + wpre + x - v;
  if (i < n) {
    offsets[(size_t)t * (n + 1) + i] = val;
    cursor[(size_t)t * n + i] = val;   // same storage as counts; 1 owner/addr
  }
}

__global__ __launch_bounds__(256) void fill4_kernel(EdgeLists4 ls) {
  EdgeList l = ls.l[blockIdx.y];
  int e = blockIdx.x * 256 + threadIdx.x;
  if (e < l.E) {
    int p = atomicAdd(&l.counts[l.dst[e]], 1);  // counts == cursor at this stage
    l.col[p] = l.src[e];
  }
}

// vectorized: 4 edges/thread
__global__ __launch_bounds__(256) void fill4v_kernel(EdgeLists4 ls) {
  EdgeList l = ls.l[blockIdx.y];
  int e0 = (blockIdx.x * 256 + threadIdx.x) * 4;
  if (e0 + 4 <= l.E) {
    int4 d = *reinterpret_cast<const int4*>(l.dst + e0);
    int4 s = *reinterpret_cast<const int4*>(l.src + e0);
    int p0 = atomicAdd(&l.counts[d.x], 1);
    int p1 = atomicAdd(&l.counts[d.y], 1);
    int p2 = atomicAdd(&l.counts[d.z], 1);
    int p3 = atomicAdd(&l.counts[d.w], 1);
    l.col[p0] = s.x;
    l.col[p1] = s.y;
    l.col[p2] = s.z;
    l.col[p3] = s.w;
  } else {
    for (int e = e0; e < l.E; ++e) {
      int p = atomicAdd(&l.counts[l.dst[e]], 1);
      l.col[p] = l.src[e];
    }
  }
}

// ---------------------------------------------------------------------------
// Aggregate device bodies (proven R12 logic, verbatim)
// ---------------------------------------------------------------------------
__device__ __forceinline__ void agg128_dev(
    const bf16* __restrict__ tab, const int* __restrict__ col,
    const int* __restrict__ offs, bf16* __restrict__ out, int n) {
  const int lane = threadIdx.x & 63;
  const int wid = threadIdx.x >> 6;
  const int r = blockIdx.x * 4 + wid;
  if (r >= n) return;
  const int slot = lane >> 4, lp = lane & 15;
  const int beg = offs[r], end = offs[r + 1];
  float acc[8] = {0.f, 0.f, 0.f, 0.f, 0.f, 0.f, 0.f, 0.f};
  float acc2[8] = {0.f, 0.f, 0.f, 0.f, 0.f, 0.f, 0.f, 0.f};
  float acc3[8] = {0.f, 0.f, 0.f, 0.f, 0.f, 0.f, 0.f, 0.f};
  float acc4[8] = {0.f, 0.f, 0.f, 0.f, 0.f, 0.f, 0.f, 0.f};
  int e = beg;
  for (; e + 16 <= end; e += 16) {
    int c0 = col[e + slot];
    int c1 = col[e + 4 + slot];
    int c2 = col[e + 8 + slot];
    int c3 = col[e + 12 + slot];
    short8 v0 = *reinterpret_cast<const short8*>(tab + (size_t)c0 * 128 + lp * 8);
    short8 v1 = *reinterpret_cast<const short8*>(tab + (size_t)c1 * 128 + lp * 8);
    short8 v2 = *reinterpret_cast<const short8*>(tab + (size_t)c2 * 128 + lp * 8);
    short8 v3 = *reinterpret_cast<const short8*>(tab + (size_t)c3 * 128 + lp * 8);
#pragma unroll
    for (int j = 0; j < 8; ++j) {
      acc[j] += bf2f(v0[j]);
      acc2[j] += bf2f(v1[j]);
      acc3[j] += bf2f(v2[j]);
      acc4[j] += bf2f(v3[j]);
    }
  }
  for (; e + 8 <= end; e += 8) {
    int c0 = col[e + slot];
    int c1 = col[e + 4 + slot];
    short8 v0 = *reinterpret_cast<const short8*>(tab + (size_t)c0 * 128 + lp * 8);
    short8 v1 = *reinterpret_cast<const short8*>(tab + (size_t)c1 * 128 + lp * 8);
#pragma unroll
    for (int j = 0; j < 8; ++j) {
      acc[j] += bf2f(v0[j]);
      acc2[j] += bf2f(v1[j]);
    }
  }
  for (; e < end; e += 4) {
    int idx = e + slot;
    if (idx < end) {
      int cc = col[idx];
      short8 v = *reinterpret_cast<const short8*>(tab + (size_t)cc * 128 + lp * 8);
#pragma unroll
      for (int j = 0; j < 8; ++j) acc[j] += bf2f(v[j]);
    }
  }
#pragma unroll
  for (int j = 0; j < 8; ++j) acc[j] = (acc[j] + acc2[j]) + (acc3[j] + acc4[j]);
#pragma unroll
  for (int j = 0; j < 8; ++j) {
    acc[j] += __shfl_xor(acc[j], 16, 64);
    acc[j] += __shfl_xor(acc[j], 32, 64);
  }
  if (slot == 0) {
    short8 sv;
#pragma unroll
    for (int j = 0; j < 8; ++j) sv[j] = f2bf(acc[j]);
    *reinterpret_cast<short8*>(out + (size_t)r * 128 + lp * 8) = sv;
  }
}

template <int D, int LPR>
__device__ __forceinline__ void agg_small_dev(
    const float* __restrict__ tab, const int* __restrict__ col,
    const int* __restrict__ offsets, bf16* __restrict__ out, int n) {
  constexpr int RPB = 256 / LPR;
  const int lane = threadIdx.x % LPR;
  const int r = blockIdx.x * RPB + threadIdx.x / LPR;
  if (r >= n) return;
  const int beg = offsets[r], end = offsets[r + 1];
  float2 acc = make_float2(0.f, 0.f);
  for (int e = beg; e < end; ++e) {
    int s = col[e];
    float2 v = *reinterpret_cast<const float2*>(tab + (size_t)s * D + lane * 2);
    acc.x += v.x;
    acc.y += v.y;
  }
  unsigned u = (unsigned)(unsigned short)f2bf(acc.x) |
               ((unsigned)(unsigned short)f2bf(acc.y) << 16);
  *reinterpret_cast<unsigned*>(out + (size_t)r * D + lane * 2) = u;
}

// legacy wrappers (unlaunched)
__global__ __launch_bounds__(256) void csr_agg128_kernel(
    const bf16* __restrict__ tab,
    const int* __restrict__ col0, const int* __restrict__ col1,
    const int* __restrict__ offs0, const int* __restrict__ offs1,
    bf16* __restrict__ out0, bf16* __restrict__ out1, int n) {
  const int* col = blockIdx.y ? col1 : col0;
  const int* offs = blockIdx.y ? offs1 : offs0;
  bf16* out = blockIdx.y ? out1 : out0;
  agg128_dev(tab, col, offs, out, n);
}

template <int D, int LPR>
__global__ __launch_bounds__(256) void csr_agg_kernel(
    const float* __restrict__ tab, const int* __restrict__ col,
    const int* __restrict__ offsets, bf16* __restrict__ out, int n) {
  agg_small_dev<D, LPR>(tab, col, offsets, out, n);
}

// merged aggregate: y=0 pred, y=1 succ, y=2 res, y=3 mat
struct AggArgs {
  const bf16* ops_tab;
  const float* res_tab;
  const float* mat_tab;
  const int *col_pred, *col_succ, *col_res, *col_mat;
  const int *offs_pred, *offs_succ, *offs_res, *offs_mat;
  bf16 *agg_pred, *agg_succ, *agg_res, *agg_mat;
  int n;
};

__global__ __launch_bounds__(256) void agg_all_kernel(AggArgs A) {
  switch (blockIdx.y) {
    case 0: agg128_dev(A.ops_tab, A.col_pred, A.offs_pred, A.agg_pred, A.n); break;
    case 1: agg128_dev(A.ops_tab, A.col_succ, A.offs_succ, A.agg_succ, A.n); break;
    case 2: agg_small_dev<64, 32>(A.res_tab, A.col_res, A.offs_res, A.agg_res, A.n); break;
    default: agg_small_dev<32, 16>(A.mat_tab, A.col_mat, A.offs_mat, A.agg_mat, A.n); break;
  }
}

// ---------------------------------------------------------------------------
// Weight -> MFMA B-fragment conversion
// frag[tile=kc*CT+ct][lane][j] = W[kc*32+(lane>>4)*8+j][ct*16+(lane&15)]
// ---------------------------------------------------------------------------
struct WDesc { const float* src; int K; int C; int dstoff; };
struct WDescs14 { WDesc w[14]; };

__global__ __launch_bounds__(256) void wconv_kernel(WDescs14 ds, short* __restrict__ dstbase) {
  WDesc d = ds.w[blockIdx.y];
  int KC = d.K >> 5, CT = d.C >> 4;
  int t = blockIdx.x * 256 + threadIdx.x;
  if (t >= KC * CT * 64) return;
  int lane = t & 63, tile = t >> 6;
  int kc = tile / CT, ct = tile - kc * CT;
  int g = lane >> 4, lp = lane & 15;
  short8 v;
#pragma unroll
  for (int j = 0; j < 8; ++j)
    v[j] = f2bf(d.src[(size_t)(kc * 32 + g * 8 + j) * d.C + ct * 16 + lp]);
  *reinterpret_cast<short8*>(dstbase + d.dstoff + (size_t)t * 8) = v;
}

// ---------------------------------------------------------------------------
// MFMA fused 2-layer MLP device body (bf16 in, bf16 out, wave-private LDS)
// FROZEN AT R8 — byte-for-byte. Do NOT restructure (R5/R6/R9/R10 all failed).
// ---------------------------------------------------------------------------
template <int K, int O, bool GATHER>
__device__ __forceinline__ void mlp2_dev(
    const bf16* __restrict__ X, const int* __restrict__ gidx,
    const short* __restrict__ W1f, const float* __restrict__ B1,
    const short* __restrict__ W2f, const float* __restrict__ B2,
    bf16* __restrict__ xbuf, int ooff, int tile, int lane, char* hw) {
  constexpr int KC = K / 32;
  constexpr int KC2 = 8;
  constexpr int OT = O / 16;
  const int g = lane >> 4, lp = lane & 15;
  const int row0 = tile * 16;

  short8 a[KC];
  {
    int srow = GATHER ? gidx[row0 + lp] : (row0 + lp);
    const bf16* xp = X + (size_t)srow * K + g * 8;
#pragma unroll
    for (int kc = 0; kc < KC; ++kc)
      a[kc] = *reinterpret_cast<const short8*>(xp + kc * 32);
  }

#pragma unroll
  for (int ct = 0; ct < 16; ++ct) {
    float bv = B1[ct * 16 + lp];
    f32x4 acc = {bv, bv, bv, bv};
#pragma unroll
    for (int kc = 0; kc < KC; ++kc) {
      short8 b = *reinterpret_cast<const short8*>(
          W1f + ((size_t)(kc * 16 + ct) * 64 + lane) * 8);
      acc = __builtin_amdgcn_mfma_f32_16x16x32_bf16(a[kc], b, acc, 0, 0, 0);
    }
#pragma unroll
    for (int r = 0; r < 4; ++r) {
      int rr = g * 4 + r;
      int byte = rr * 512 + (ct * 16 + lp) * 2;
      byte ^= (rr & 7) << 4;
      *reinterpret_cast<short*>(hw + byte) = f2bf(fmaxf(acc[r], 0.f));
    }
  }
  asm volatile("s_waitcnt lgkmcnt(0)" ::: "memory");
  __builtin_amdgcn_sched_barrier(0);

  short8 a2[KC2];
#pragma unroll
  for (int kc = 0; kc < KC2; ++kc) {
    int byte = lp * 512 + (kc * 32 + g * 8) * 2;
    byte ^= (lp & 7) << 4;
    a2[kc] = *reinterpret_cast<const short8*>(hw + byte);
  }
#pragma unroll
  for (int ot = 0; ot < OT; ++ot) {
    float bv = B2[ot * 16 + lp];
    f32x4 acc = {bv, bv, bv, bv};
#pragma unroll
    for (int kc = 0; kc < KC2; ++kc) {
      short8 b = *reinterpret_cast<const short8*>(
          W2f + ((size_t)(kc * OT + ot) * 64 + lane) * 8);
      acc = __builtin_amdgcn_mfma_f32_16x16x32_bf16(a2[kc], b, acc, 0, 0, 0);
    }
#pragma unroll
    for (int r = 0; r < 4; ++r) {
      int rr = g * 4 + r;
      *reinterpret_cast<short*>(xbuf + (size_t)(row0 + rr) * 608 + ooff + ot * 16 + lp) =
          f2bf(acc[r]);
    }
  }
}

struct Mlp6Args {
  const bf16 *agg_pred, *agg_succ, *agg_res, *agg_mat, *items_bf, *ops_bf;
  const int* related;
  const short* wf;
  const float *b_pred1, *b_pred2, *b_succ1, *b_succ2, *b_res1, *b_res2;
  const float *b_mat1, *b_mat2, *b_item1, *b_item2, *b_self1, *b_self2;
  bf16* xbuf;
  int ntiles;
};

__global__ __launch_bounds__(256) void mlp6_kernel(Mlp6Args A) {
  __shared__ short hbuf[4 * 16 * 256];  // 32 KB, 8 KB/wave
  const int lane = threadIdx.x & 63, wid = threadIdx.x >> 6;
  int tile = blockIdx.x * 4 + wid;
  if (tile >= A.ntiles) tile = A.ntiles - 1;  // dup benign
  char* hw = (char*)(hbuf + wid * (16 * 256));
  const short* wf = A.wf;
  switch (blockIdx.y) {
    case 0: mlp2_dev<128, 128, false>(A.agg_pred, nullptr, wf + 65536, A.b_pred1,
                                      wf + 221184, A.b_pred2, A.xbuf, 0, tile, lane, hw); break;
    case 1: mlp2_dev<128, 128, false>(A.agg_succ, nullptr, wf + 98304, A.b_succ1,
                                      wf + 253952, A.b_succ2, A.xbuf, 128, tile, lane, hw); break;
    case 2: mlp2_dev<64, 64, false>(A.agg_res, nullptr, wf + 131072, A.b_res1,
                                    wf + 286720, A.b_res2, A.xbuf, 256, tile, lane, hw); break;
    case 3: mlp2_dev<32, 32, false>(A.agg_mat, nullptr, wf + 147456, A.b_mat1,
                                    wf + 303104, A.b_mat2, A.xbuf, 320, tile, lane, hw); break;
    case 4: mlp2_dev<128, 128, true>(A.items_bf, A.related, wf + 32768, A.b_item1,
                                     wf + 188416, A.b_item2, A.xbuf, 352, tile, lane, hw); break;
    default: mlp2_dev<128, 128, false>(A.ops_bf, nullptr, wf + 0, A.b_self1,
                                       wf + 155648, A.b_self2, A.xbuf, 480, tile, lane, hw); break;
  }
}

// ---------------------------------------------------------------------------
// Final combiner: FROZEN AT R8 — byte-for-byte.
// ---------------------------------------------------------------------------
__global__ __launch_bounds__(256, 4) void final_kernel(
    const bf16* __restrict__ xbuf,
    const short* __restrict__ Wc1f, const float* __restrict__ B1,
    const short* __restrict__ Wc2f, const float* __restrict__ B2,
    const float* __restrict__ W3, const float* __restrict__ B3,
    float* __restrict__ out, int ntiles) {
  __shared__ short hbuf[4 * 16 * 256];  // 32 KB: per-wave h1 bf16, then h2 f32 aliased
  const int lane = threadIdx.x & 63, wid = threadIdx.x >> 6;
  int tile = blockIdx.x * 4 + wid;
  if (tile >= ntiles) tile = ntiles - 1;
  const int g = lane >> 4, lp = lane & 15;
  const int row0 = tile * 16;
  char* hw = (char*)(hbuf + wid * (16 * 256));

  // ---- L1: h1 = relu(x @ Wc1 + b1), 608->256, MFMA ----
  {
    const bf16* xp = xbuf + (size_t)(row0 + lp) * 608 + g * 8;
    short8 a[19];
#pragma unroll
    for (int kc = 0; kc < 19; ++kc)
      a[kc] = *reinterpret_cast<const short8*>(xp + kc * 32);
#pragma unroll
    for (int ct = 0; ct < 16; ++ct) {
      float bv = B1[ct * 16 + lp];
      f32x4 acc = {bv, bv, bv, bv};
#pragma unroll
      for (int kc = 0; kc < 19; ++kc) {
        short8 b = *reinterpret_cast<const short8*>(
            Wc1f + ((size_t)(kc * 16 + ct) * 64 + lane) * 8);
        acc = __builtin_amdgcn_mfma_f32_16x16x32_bf16(a[kc], b, acc, 0, 0, 0);
      }
#pragma unroll
      for (int r = 0; r < 4; ++r) {
        int rr = g * 4 + r;
        int byte = rr * 512 + (ct * 16 + lp) * 2;
        byte ^= (rr & 7) << 4;
        *reinterpret_cast<short*>(hw + byte) = f2bf(fmaxf(acc[r], 0.f));
      }
    }
  }
  asm volatile("s_waitcnt lgkmcnt(0)" ::: "memory");
  __builtin_amdgcn_sched_barrier(0);

  // ---- L2: h2 = relu(h1 @ Wc2 + b2), 256->128, MFMA ----
  {
    short8 a2[8];
#pragma unroll
    for (int kc = 0; kc < 8; ++kc) {
      int byte = lp * 512 + (kc * 32 + g * 8) * 2;
      byte ^= (lp & 7) << 4;
      a2[kc] = *reinterpret_cast<const short8*>(hw + byte);
    }
    asm volatile("s_waitcnt lgkmcnt(0)" ::: "memory");
    __builtin_amdgcn_sched_barrier(0);
    float* h2 = (float*)hw;  // alias over h1 (a2 fully in regs)
#pragma unroll
    for (int ot = 0; ot < 8; ++ot) {
      float bv = B2[ot * 16 + lp];
      f32x4 acc = {bv, bv, bv, bv};
#pragma unroll
      for (int kc = 0; kc < 8; ++kc) {
        short8 b = *reinterpret_cast<const short8*>(
            Wc2f + ((size_t)(kc * 8 + ot) * 64 + lane) * 8);
        acc = __builtin_amdgcn_mfma_f32_16x16x32_bf16(a2[kc], b, acc, 0, 0, 0);
      }
#pragma unroll
      for (int r = 0; r < 4; ++r)
        h2[(g * 4 + r) * 128 + ot * 16 + lp] = fmaxf(acc[r], 0.f);
    }
  }
  asm volatile("s_waitcnt lgkmcnt(0)" ::: "memory");
  __builtin_amdgcn_sched_barrier(0);

  // ---- L3: out = h2 @ W3 + b3, f32 VALU (precision-critical) ----
  {
    const float* h2 = (const float*)hw;
    const int half = lane >> 5;
    const int c = (lane & 31) * 4;
    const int rbase = half * 8;
    f32x4 acc3[8];
    f32x4 bv = *reinterpret_cast<const f32x4*>(B3 + c);
#pragma unroll
    for (int rr = 0; rr < 8; ++rr) acc3[rr] = bv;
    for (int k0 = 0; k0 < 128; k0 += 4) {
      f32x4 w0 = *reinterpret_cast<const f32x4*>(W3 + (size_t)(k0 + 0) * 128 + c);
      f32x4 w1 = *reinterpret_cast<const f32x4*>(W3 + (size_t)(k0 + 1) * 128 + c);
      f32x4 w2v = *reinterpret_cast<const f32x4*>(W3 + (size_t)(k0 + 2) * 128 + c);
      f32x4 w3v = *reinterpret_cast<const f32x4*>(W3 + (size_t)(k0 + 3) * 128 + c);
#pragma unroll
      for (int rr = 0; rr < 8; ++rr) {
        f32x4 h = *reinterpret_cast<const f32x4*>(&h2[(rbase + rr) * 128 + k0]);
        acc3[rr] += h.x * w0 + h.y * w1 + h.z * w2v + h.w * w3v;
      }
    }
#pragma unroll
    for (int rr = 0; rr < 8; ++rr)
      *reinterpret_cast<f32x4*>(out + (size_t)(row0 + rbase + rr) * 128 + c) = acc3[rr];
  }
}

// ---------------------------------------------------------------------------
// kernel_launch
// ---------------------------------------------------------------------------
extern "C" void kernel_launch(void* const* d_in, const int* in_sizes, int n_in,
                              void* d_out, int out_size, void* d_ws,
                              size_t ws_size, hipStream_t stream) {
  const float* operations = (const float*)d_in[0];
  const float* items      = (const float*)d_in[1];
  const float* materials  = (const float*)d_in[2];
  const float* resources  = (const float*)d_in[3];
  const int* related      = (const int*)d_in[4];
  const int* res_op       = (const int*)d_in[5];
  const int* res_res      = (const int*)d_in[6];
  const int* mat_op       = (const int*)d_in[7];
  const int* mat_mat      = (const int*)d_in[8];
  const int* prec_src     = (const int*)d_in[9];
  const int* prec_dst     = (const int*)d_in[10];
  const float* w_self1 = (const float*)d_in[11];
  const float* b_self1 = (const float*)d_in[12];
  const float* w_self2 = (const float*)d_in[13];
  const float* b_self2 = (const float*)d_in[14];
  const float* w_item1 = (const float*)d_in[15];
  const float* b_item1 = (const float*)d_in[16];
  const float* w_item2 = (const float*)d_in[17];
  const float* b_item2 = (const float*)d_in[18];
  const float* w_pred1 = (const float*)d_in[19];
  const float* b_pred1 = (const float*)d_in[20];
  const float* w_pred2 = (const float*)d_in[21];
  const float* b_pred2 = (const float*)d_in[22];
  const float* w_succ1 = (const float*)d_in[23];
  const float* b_succ1 = (const float*)d_in[24];
  const float* w_succ2 = (const float*)d_in[25];
  const float* b_succ2 = (const float*)d_in[26];
  const float* w_res1  = (const float*)d_in[27];
  const float* b_res1  = (const float*)d_in[28];
  const float* w_res2  = (const float*)d_in[29];
  const float* b_res2  = (const float*)d_in[30];
  const float* w_mat1  = (const float*)d_in[31];
  const float* b_mat1  = (const float*)d_in[32];
  const float* w_mat2  = (const float*)d_in[33];
  const float* b_mat2  = (const float*)d_in[34];
  const float* w_c1    = (const float*)d_in[35];
  const float* b_c1    = (const float*)d_in[36];
  const float* w_c2    = (const float*)d_in[37];
  const float* b_c2    = (const float*)d_in[38];
  const float* w_c3    = (const float*)d_in[39];
  const float* b_c3    = (const float*)d_in[40];

  const int N = in_sizes[0] / 128;   // 50000
  const int NI = in_sizes[1] / 128;  // 20000
  const int E_RES = in_sizes[5];
  const int E_MAT = in_sizes[7];
  const int E_PREC = in_sizes[9];

  // ---- ws layout ----
  size_t off = 0;
  auto take = [&](size_t bytes) {
    size_t o = off;
    off += (bytes + 63) & ~(size_t)63;
    return o;
  };
  size_t xbuf_off  = take((size_t)N * 608 * 2);
  size_t aggp_off  = take((size_t)N * 128 * 2);
  size_t aggsu_off = take((size_t)N * 128 * 2);
  size_t aggr_off  = take((size_t)N * 64 * 2);
  size_t aggm_off  = take((size_t)N * 32 * 2);
  size_t wf_off    = take((size_t)499712 * 2);
  size_t opsb_off  = take((size_t)N * 128 * 2);
  size_t itemb_off = take((size_t)NI * 128 * 2);
  size_t offs_off  = take((size_t)4 * (N + 1) * 4);
  size_t tmp_off   = take((size_t)4 * N * 4);
  size_t cols_off  = take(((size_t)2 * E_PREC + E_RES + E_MAT) * 4);
  size_t bsum_off  = take((size_t)4 * 64 * 4);

  char* ws = (char*)d_ws;
  bf16* xbuf = (bf16*)(ws + xbuf_off);
  bf16* agg_pred = (bf16*)(ws + aggp_off);
  bf16* agg_succ = (bf16*)(ws + aggsu_off);
  bf16* agg_res  = (bf16*)(ws + aggr_off);
  bf16* agg_mat  = (bf16*)(ws + aggm_off);
  short* wf = (short*)(ws + wf_off);
  bf16* ops_bf   = (bf16*)(ws + opsb_off);
  bf16* items_bf = (bf16*)(ws + itemb_off);
  int* offs = (int*)(ws + offs_off);
  int* tmp  = (int*)(ws + tmp_off);
  int* cols = (int*)(ws + cols_off);
  int* bsum = (int*)(ws + bsum_off);

  int* offs_pred = offs;
  int* offs_succ = offs + (N + 1);
  int* offs_res  = offs + 2 * (N + 1);
  int* offs_mat  = offs + 3 * (N + 1);
  int* cur_pred = tmp;
  int* cur_succ = tmp + N;
  int* cur_res  = tmp + 2 * N;
  int* cur_mat  = tmp + 3 * N;
  int* col_pred = cols;
  int* col_succ = col_pred + E_PREC;
  int* col_res  = col_succ + E_PREC;
  int* col_mat  = col_res + E_RES;

  dim3 blk(256);

  // ---- bf16 tables (merged launch) ----
  int nops4 = N * 128 / 4, nitems4 = NI * 128 / 4;
  cvt2_kernel<<<dim3((nops4 + 255) / 256, 2), blk, 0, stream>>>(
      operations, ops_bf, nops4, items, items_bf, nitems4);

  // ---- weight fragments ----
  WDescs14 wd;
  wd.w[0]  = {w_self1, 128, 256, 0};
  wd.w[1]  = {w_item1, 128, 256, 32768};
  wd.w[2]  = {w_pred1, 128, 256, 65536};
  wd.w[3]  = {w_succ1, 128, 256, 98304};
  wd.w[4]  = {w_res1,   64, 256, 131072};
  wd.w[5]  = {w_mat1,   32, 256, 147456};
  wd.w[6]  = {w_self2, 256, 128, 155648};
  wd.w[7]  = {w_item2, 256, 128, 188416};
  wd.w[8]  = {w_pred2, 256, 128, 221184};
  wd.w[9]  = {w_succ2, 256, 128, 253952};
  wd.w[10] = {w_res2,  256,  64, 286720};
  wd.w[11] = {w_mat2,  256,  32, 303104};
  wd.w[12] = {w_c1,    608, 256, 311296};
  wd.w[13] = {w_c2,    256, 128, 466944};
  wconv_kernel<<<dim3(76, 14), blk, 0, stream>>>(wd, wf);

  // ---- CSR build ----
  (void)hipMemsetAsync(tmp, 0, 4 * (size_t)N * sizeof(int), stream);
  EdgeLists4 els;
  els.l[0] = {prec_src, prec_dst, cur_pred, col_pred, E_PREC};
  els.l[1] = {prec_dst, prec_src, cur_succ, col_succ, E_PREC};
  els.l[2] = {res_op, res_res, cur_res, col_res, E_RES};
  els.l[3] = {mat_op, mat_mat, cur_mat, col_mat, E_MAT};
  int cgx = (E_PREC / 4 + 255) / 256;  // 4 edges/thread
  count4v_kernel<<<dim3(cgx, 4), blk, 0, stream>>>(els);
  int nchunk = (N + 1023) / 1024;  // 49
  chunksum_kernel<<<dim3(nchunk, 4), blk, 0, stream>>>(tmp, bsum, N, nchunk);
  scanchunks_kernel<<<1, blk, 0, stream>>>(bsum, offs, N, nchunk);
  scanfinal_kernel<<<dim3(nchunk, 4), dim3(1024), 0, stream>>>(tmp, bsum, offs, tmp, N, nchunk);
  fill4v_kernel<<<dim3(cgx, 4), blk, 0, stream>>>(els);

  // ---- aggregates (merged launch; short res/mat overlap pred/succ tail) ----
  AggArgs aa;
  aa.ops_tab = ops_bf; aa.res_tab = resources; aa.mat_tab = materials;
  aa.col_pred = col_pred; aa.col_succ = col_succ; aa.col_res = col_res; aa.col_mat = col_mat;
  aa.offs_pred = offs_pred; aa.offs_succ = offs_succ; aa.offs_res = offs_res; aa.offs_mat = offs_mat;
  aa.agg_pred = agg_pred; aa.agg_succ = agg_succ; aa.agg_res = agg_res; aa.agg_mat = agg_mat;
  aa.n = N;
  agg_all_kernel<<<dim3((N + 3) / 4, 4), blk, 0, stream>>>(aa);

  // ---- 6 MLPs in one launch ----
  int ntiles = N / 16;           // 3125
  int mgrid = (ntiles + 3) / 4;  // 782
  Mlp6Args ma;
  ma.agg_pred = agg_pred; ma.agg_succ = agg_succ; ma.agg_res = agg_res; ma.agg_mat = agg_mat;
  ma.items_bf = items_bf; ma.ops_bf = ops_bf; ma.related = related; ma.wf = wf;
  ma.b_pred1 = b_pred1; ma.b_pred2 = b_pred2; ma.b_succ1 = b_succ1; ma.b_succ2 = b_succ2;
  ma.b_res1 = b_res1; ma.b_res2 = b_res2; ma.b_mat1 = b_mat1; ma.b_mat2 = b_mat2;
  ma.b_item1 = b_item1; ma.b_item2 = b_item2; ma.b_self1 = b_self1; ma.b_self2 = b_self2;
  ma.xbuf = xbuf; ma.ntiles = ntiles;
  mlp6_kernel<<<dim3(mgrid, 6), blk, 0, stream>>>(ma);

  // ---- final combiner ----
  final_kernel<<<mgrid, blk, 0, stream>>>(
      xbuf, wf + 311296, b_c1, wf + 466944, b_c2, w_c3, b_c3, (float*)d_out, ntiles);
}

// Round 14
// 580.658 us; speedup vs baseline: 7.5338x; 1.0206x over previous
//
#include <hip/hip_runtime.h>
#include <hip/hip_bf16.h>

typedef __attribute__((ext_vector_type(8))) short short8;
typedef __attribute__((ext_vector_type(4))) float f32x4;
using bf16 = __hip_bfloat16;

// N=50000, OP=128, H=256, H2=128, OUT=128
// xbuf concat: [pred 0 | succ 128 | res 256 | mat 320 | item 352 | self 480], 608

__device__ __forceinline__ short f2bf(float f) {
  union { float f; unsigned u; } v; v.f = f;
  unsigned r = (v.u + 0x7fffu + ((v.u >> 16) & 1u)) >> 16;  // RNE
  return (short)r;
}
__device__ __forceinline__ float bf2f(short s) {
  union { unsigned u; float f; } x;
  x.u = ((unsigned)(unsigned short)s) << 16;
  return x.f;
}

// ---------------------------------------------------------------------------
// Weight descriptor (needed by prep)
// ---------------------------------------------------------------------------
struct WDesc { const float* src; int K; int C; int dstoff; };
struct WDescs14 { WDesc w[14]; };

// ---------------------------------------------------------------------------
// Fused preprocessing: y=0 cvt ops, y=1 cvt items, y=2 wconv (14 mats in x),
// y=3 zero tmp. Replaces cvt2 + wconv + hipMemsetAsync.
// ---------------------------------------------------------------------------
struct PrepArgs {
  const float* ops_src; bf16* ops_dst; int nops4;
  const float* items_src; bf16* items_dst; int nitems4;
  WDescs14 wd; short* wf;
  int* tmp; int ntmp;
};

__global__ __launch_bounds__(256) void prep_kernel(PrepArgs P) {
  const int bx = blockIdx.x;
  switch (blockIdx.y) {
    case 0: {
      int i = bx * 256 + threadIdx.x;
      if (i >= P.nops4) return;
      f32x4 v = *reinterpret_cast<const f32x4*>(P.ops_src + (size_t)i * 4);
      uint2 u;
      u.x = (unsigned)(unsigned short)f2bf(v.x) | ((unsigned)(unsigned short)f2bf(v.y) << 16);
      u.y = (unsigned)(unsigned short)f2bf(v.z) | ((unsigned)(unsigned short)f2bf(v.w) << 16);
      *reinterpret_cast<uint2*>(P.ops_dst + (size_t)i * 4) = u;
    } break;
    case 1: {
      int i = bx * 256 + threadIdx.x;
      if (i >= P.nitems4) return;
      f32x4 v = *reinterpret_cast<const f32x4*>(P.items_src + (size_t)i * 4);
      uint2 u;
      u.x = (unsigned)(unsigned short)f2bf(v.x) | ((unsigned)(unsigned short)f2bf(v.y) << 16);
      u.y = (unsigned)(unsigned short)f2bf(v.z) | ((unsigned)(unsigned short)f2bf(v.w) << 16);
      *reinterpret_cast<uint2*>(P.items_dst + (size_t)i * 4) = u;
    } break;
    case 2: {
      if (bx >= 76 * 14) return;
      WDesc d = P.wd.w[bx / 76];
      int KC = d.K >> 5, CT = d.C >> 4;
      int t = (bx % 76) * 256 + threadIdx.x;
      if (t >= KC * CT * 64) return;
      int lane = t & 63, tile = t >> 6;
      int kc = tile / CT, ct = tile - kc * CT;
      int g = lane >> 4, lp = lane & 15;
      short8 v;
#pragma unroll
      for (int j = 0; j < 8; ++j)
        v[j] = f2bf(d.src[(size_t)(kc * 32 + g * 8 + j) * d.C + ct * 16 + lp]);
      *reinterpret_cast<short8*>(P.wf + d.dstoff + (size_t)t * 8) = v;
    } break;
    default: {
      int i = bx * 256 + threadIdx.x;
      if (i < P.ntmp) P.tmp[i] = 0;
    } break;
  }
}

// ---------------------------------------------------------------------------
// CSR build structures
// ---------------------------------------------------------------------------
struct EdgeList { const int* dst; const int* src; int* counts; int* col; int E; };
struct EdgeLists4 { EdgeList l[4]; };

// vectorized: 4 edges/thread
__global__ __launch_bounds__(256) void count4v_kernel(EdgeLists4 ls) {
  EdgeList l = ls.l[blockIdx.y];
  int e0 = (blockIdx.x * 256 + threadIdx.x) * 4;
  if (e0 + 4 <= l.E) {
    int4 d = *reinterpret_cast<const int4*>(l.dst + e0);
    atomicAdd(&l.counts[d.x], 1);
    atomicAdd(&l.counts[d.y], 1);
    atomicAdd(&l.counts[d.z], 1);
    atomicAdd(&l.counts[d.w], 1);
  } else {
    for (int e = e0; e < l.E; ++e) atomicAdd(&l.counts[l.dst[e]], 1);
  }
}

// ---- per-1024-chunk RAW sums for the 4 count arrays ----
__global__ __launch_bounds__(256) void chunksum_kernel(
    const int* __restrict__ counts, int* __restrict__ bsum, int n, int nchunk) {
  const int t = blockIdx.y;
  const int* cnt = counts + (size_t)t * n;
  int base = blockIdx.x * 1024;
  int s = 0;
  for (int j = threadIdx.x; j < 1024; j += 256) {
    int i = base + j;
    if (i < n) s += cnt[i];
  }
#pragma unroll
  for (int off = 32; off > 0; off >>= 1) s += __shfl_down(s, off, 64);
  __shared__ int ws[4];
  const int lane = threadIdx.x & 63, wid = threadIdx.x >> 6;
  if (lane == 0) ws[wid] = s;
  __syncthreads();
  if (threadIdx.x == 0)
    bsum[(size_t)t * nchunk + blockIdx.x] = ws[0] + ws[1] + ws[2] + ws[3];
}

// ---- fused: per-block base from raw chunk sums + intra-chunk scan;
//      writes offs AND cursor; last element writes total ----
__global__ __launch_bounds__(1024) void scanfinal2_kernel(
    const int* __restrict__ counts, const int* __restrict__ bsum,
    int* __restrict__ offsets, int* __restrict__ cursor, int n, int nchunk) {
  const int t = blockIdx.y;
  const int* cnt = counts + (size_t)t * n;
  __shared__ int wsum[16];
  __shared__ int base_s;
  const int lane = threadIdx.x & 63, wid = threadIdx.x >> 6;
  if (wid == 0) {
    int b = (lane < blockIdx.x) ? bsum[(size_t)t * nchunk + lane] : 0;  // nchunk<=64
#pragma unroll
    for (int off = 32; off > 0; off >>= 1) b += __shfl_down(b, off, 64);
    if (lane == 0) base_s = b;
  }
  int i = blockIdx.x * 1024 + threadIdx.x;
  int v = (i < n) ? cnt[i] : 0;
  int x = v;
#pragma unroll
  for (int off = 1; off < 64; off <<= 1) {
    int u = __shfl_up(x, off, 64);
    if (lane >= off) x += u;
  }
  if (lane == 63) wsum[wid] = x;
  __syncthreads();
  if (wid == 0 && lane < 16) {
    int w = wsum[lane];
#pragma unroll
    for (int off = 1; off < 16; off <<= 1) {
      int u = __shfl_up(w, off, 16);
      if (lane >= off) w += u;
    }
    wsum[lane] = w;
  }
  __syncthreads();
  int wpre = (wid == 0) ? 0 : wsum[wid - 1];
  int val = base_s + wpre + x - v;
  if (i < n) {
    offsets[(size_t)t * (n + 1) + i] = val;
    cursor[(size_t)t * n + i] = val;
    if (i == n - 1) offsets[(size_t)t * (n + 1) + n] = val + v;
  }
}

// vectorized: 4 edges/thread
__global__ __launch_bounds__(256) void fill4v_kernel(EdgeLists4 ls) {
  EdgeList l = ls.l[blockIdx.y];
  int e0 = (blockIdx.x * 256 + threadIdx.x) * 4;
  if (e0 + 4 <= l.E) {
    int4 d = *reinterpret_cast<const int4*>(l.dst + e0);
    int4 s = *reinterpret_cast<const int4*>(l.src + e0);
    int p0 = atomicAdd(&l.counts[d.x], 1);
    int p1 = atomicAdd(&l.counts[d.y], 1);
    int p2 = atomicAdd(&l.counts[d.z], 1);
    int p3 = atomicAdd(&l.counts[d.w], 1);
    l.col[p0] = s.x;
    l.col[p1] = s.y;
    l.col[p2] = s.z;
    l.col[p3] = s.w;
  } else {
    for (int e = e0; e < l.E; ++e) {
      int p = atomicAdd(&l.counts[l.dst[e]], 1);
      l.col[p] = l.src[e];
    }
  }
}

// ---------------------------------------------------------------------------
// Aggregate device bodies (proven R12 logic, verbatim)
// ---------------------------------------------------------------------------
__device__ __forceinline__ void agg128_dev(
    const bf16* __restrict__ tab, const int* __restrict__ col,
    const int* __restrict__ offs, bf16* __restrict__ out, int n) {
  const int lane = threadIdx.x & 63;
  const int wid = threadIdx.x >> 6;
  const int r = blockIdx.x * 4 + wid;
  if (r >= n) return;
  const int slot = lane >> 4, lp = lane & 15;
  const int beg = offs[r], end = offs[r + 1];
  float acc[8] = {0.f, 0.f, 0.f, 0.f, 0.f, 0.f, 0.f, 0.f};
  float acc2[8] = {0.f, 0.f, 0.f, 0.f, 0.f, 0.f, 0.f, 0.f};
  float acc3[8] = {0.f, 0.f, 0.f, 0.f, 0.f, 0.f, 0.f, 0.f};
  float acc4[8] = {0.f, 0.f, 0.f, 0.f, 0.f, 0.f, 0.f, 0.f};
  int e = beg;
  for (; e + 16 <= end; e += 16) {
    int c0 = col[e + slot];
    int c1 = col[e + 4 + slot];
    int c2 = col[e + 8 + slot];
    int c3 = col[e + 12 + slot];
    short8 v0 = *reinterpret_cast<const short8*>(tab + (size_t)c0 * 128 + lp * 8);
    short8 v1 = *reinterpret_cast<const short8*>(tab + (size_t)c1 * 128 + lp * 8);
    short8 v2 = *reinterpret_cast<const short8*>(tab + (size_t)c2 * 128 + lp * 8);
    short8 v3 = *reinterpret_cast<const short8*>(tab + (size_t)c3 * 128 + lp * 8);
#pragma unroll
    for (int j = 0; j < 8; ++j) {
      acc[j] += bf2f(v0[j]);
      acc2[j] += bf2f(v1[j]);
      acc3[j] += bf2f(v2[j]);
      acc4[j] += bf2f(v3[j]);
    }
  }
  for (; e + 8 <= end; e += 8) {
    int c0 = col[e + slot];
    int c1 = col[e + 4 + slot];
    short8 v0 = *reinterpret_cast<const short8*>(tab + (size_t)c0 * 128 + lp * 8);
    short8 v1 = *reinterpret_cast<const short8*>(tab + (size_t)c1 * 128 + lp * 8);
#pragma unroll
    for (int j = 0; j < 8; ++j) {
      acc[j] += bf2f(v0[j]);
      acc2[j] += bf2f(v1[j]);
    }
  }
  for (; e < end; e += 4) {
    int idx = e + slot;
    if (idx < end) {
      int cc = col[idx];
      short8 v = *reinterpret_cast<const short8*>(tab + (size_t)cc * 128 + lp * 8);
#pragma unroll
      for (int j = 0; j < 8; ++j) acc[j] += bf2f(v[j]);
    }
  }
#pragma unroll
  for (int j = 0; j < 8; ++j) acc[j] = (acc[j] + acc2[j]) + (acc3[j] + acc4[j]);
#pragma unroll
  for (int j = 0; j < 8; ++j) {
    acc[j] += __shfl_xor(acc[j], 16, 64);
    acc[j] += __shfl_xor(acc[j], 32, 64);
  }
  if (slot == 0) {
    short8 sv;
#pragma unroll
    for (int j = 0; j < 8; ++j) sv[j] = f2bf(acc[j]);
    *reinterpret_cast<short8*>(out + (size_t)r * 128 + lp * 8) = sv;
  }
}

template <int D, int LPR>
__device__ __forceinline__ void agg_small_dev(
    const float* __restrict__ tab, const int* __restrict__ col,
    const int* __restrict__ offsets, bf16* __restrict__ out, int n) {
  constexpr int RPB = 256 / LPR;
  const int lane = threadIdx.x % LPR;
  const int r = blockIdx.x * RPB + threadIdx.x / LPR;
  if (r >= n) return;
  const int beg = offsets[r], end = offsets[r + 1];
  float2 acc = make_float2(0.f, 0.f);
  for (int e = beg; e < end; ++e) {
    int s = col[e];
    float2 v = *reinterpret_cast<const float2*>(tab + (size_t)s * D + lane * 2);
    acc.x += v.x;
    acc.y += v.y;
  }
  unsigned u = (unsigned)(unsigned short)f2bf(acc.x) |
               ((unsigned)(unsigned short)f2bf(acc.y) << 16);
  *reinterpret_cast<unsigned*>(out + (size_t)r * D + lane * 2) = u;
}

// merged aggregate: y=0 pred, y=1 succ, y=2 res, y=3 mat
struct AggArgs {
  const bf16* ops_tab;
  const float* res_tab;
  const float* mat_tab;
  const int *col_pred, *col_succ, *col_res, *col_mat;
  const int *offs_pred, *offs_succ, *offs_res, *offs_mat;
  bf16 *agg_pred, *agg_succ, *agg_res, *agg_mat;
  int n;
};

__global__ __launch_bounds__(256) void agg_all_kernel(AggArgs A) {
  switch (blockIdx.y) {
    case 0: agg128_dev(A.ops_tab, A.col_pred, A.offs_pred, A.agg_pred, A.n); break;
    case 1: agg128_dev(A.ops_tab, A.col_succ, A.offs_succ, A.agg_succ, A.n); break;
    case 2: agg_small_dev<64, 32>(A.res_tab, A.col_res, A.offs_res, A.agg_res, A.n); break;
    default: agg_small_dev<32, 16>(A.mat_tab, A.col_mat, A.offs_mat, A.agg_mat, A.n); break;
  }
}

// ---------------------------------------------------------------------------
// MFMA fused 2-layer MLP device body (bf16 in, bf16 out, wave-private LDS)
// FROZEN AT R8 — byte-for-byte. Do NOT restructure (R5/R6/R9/R10 all failed).
// ---------------------------------------------------------------------------
template <int K, int O, bool GATHER>
__device__ __forceinline__ void mlp2_dev(
    const bf16* __restrict__ X, const int* __restrict__ gidx,
    const short* __restrict__ W1f, const float* __restrict__ B1,
    const short* __restrict__ W2f, const float* __restrict__ B2,
    bf16* __restrict__ xbuf, int ooff, int tile, int lane, char* hw) {
  constexpr int KC = K / 32;
  constexpr int KC2 = 8;
  constexpr int OT = O / 16;
  const int g = lane >> 4, lp = lane & 15;
  const int row0 = tile * 16;

  short8 a[KC];
  {
    int srow = GATHER ? gidx[row0 + lp] : (row0 + lp);
    const bf16* xp = X + (size_t)srow * K + g * 8;
#pragma unroll
    for (int kc = 0; kc < KC; ++kc)
      a[kc] = *reinterpret_cast<const short8*>(xp + kc * 32);
  }

#pragma unroll
  for (int ct = 0; ct < 16; ++ct) {
    float bv = B1[ct * 16 + lp];
    f32x4 acc = {bv, bv, bv, bv};
#pragma unroll
    for (int kc = 0; kc < KC; ++kc) {
      short8 b = *reinterpret_cast<const short8*>(
          W1f + ((size_t)(kc * 16 + ct) * 64 + lane) * 8);
      acc = __builtin_amdgcn_mfma_f32_16x16x32_bf16(a[kc], b, acc, 0, 0, 0);
    }
#pragma unroll
    for (int r = 0; r < 4; ++r) {
      int rr = g * 4 + r;
      int byte = rr * 512 + (ct * 16 + lp) * 2;
      byte ^= (rr & 7) << 4;
      *reinterpret_cast<short*>(hw + byte) = f2bf(fmaxf(acc[r], 0.f));
    }
  }
  asm volatile("s_waitcnt lgkmcnt(0)" ::: "memory");
  __builtin_amdgcn_sched_barrier(0);

  short8 a2[KC2];
#pragma unroll
  for (int kc = 0; kc < KC2; ++kc) {
    int byte = lp * 512 + (kc * 32 + g * 8) * 2;
    byte ^= (lp & 7) << 4;
    a2[kc] = *reinterpret_cast<const short8*>(hw + byte);
  }
#pragma unroll
  for (int ot = 0; ot < OT; ++ot) {
    float bv = B2[ot * 16 + lp];
    f32x4 acc = {bv, bv, bv, bv};
#pragma unroll
    for (int kc = 0; kc < KC2; ++kc) {
      short8 b = *reinterpret_cast<const short8*>(
          W2f + ((size_t)(kc * OT + ot) * 64 + lane) * 8);
      acc = __builtin_amdgcn_mfma_f32_16x16x32_bf16(a2[kc], b, acc, 0, 0, 0);
    }
#pragma unroll
    for (int r = 0; r < 4; ++r) {
      int rr = g * 4 + r;
      *reinterpret_cast<short*>(xbuf + (size_t)(row0 + rr) * 608 + ooff + ot * 16 + lp) =
          f2bf(acc[r]);
    }
  }
}

struct Mlp6Args {
  const bf16 *agg_pred, *agg_succ, *agg_res, *agg_mat, *items_bf, *ops_bf;
  const int* related;
  const short* wf;
  const float *b_pred1, *b_pred2, *b_succ1, *b_succ2, *b_res1, *b_res2;
  const float *b_mat1, *b_mat2, *b_item1, *b_item2, *b_self1, *b_self2;
  bf16* xbuf;
  int ntiles;
};

__global__ __launch_bounds__(256) void mlp6_kernel(Mlp6Args A) {
  __shared__ short hbuf[4 * 16 * 256];  // 32 KB, 8 KB/wave
  const int lane = threadIdx.x & 63, wid = threadIdx.x >> 6;
  int tile = blockIdx.x * 4 + wid;
  if (tile >= A.ntiles) tile = A.ntiles - 1;  // dup benign
  char* hw = (char*)(hbuf + wid * (16 * 256));
  const short* wf = A.wf;
  switch (blockIdx.y) {
    case 0: mlp2_dev<128, 128, false>(A.agg_pred, nullptr, wf + 65536, A.b_pred1,
                                      wf + 221184, A.b_pred2, A.xbuf, 0, tile, lane, hw); break;
    case 1: mlp2_dev<128, 128, false>(A.agg_succ, nullptr, wf + 98304, A.b_succ1,
                                      wf + 253952, A.b_succ2, A.xbuf, 128, tile, lane, hw); break;
    case 2: mlp2_dev<64, 64, false>(A.agg_res, nullptr, wf + 131072, A.b_res1,
                                    wf + 286720, A.b_res2, A.xbuf, 256, tile, lane, hw); break;
    case 3: mlp2_dev<32, 32, false>(A.agg_mat, nullptr, wf + 147456, A.b_mat1,
                                    wf + 303104, A.b_mat2, A.xbuf, 320, tile, lane, hw); break;
    case 4: mlp2_dev<128, 128, true>(A.items_bf, A.related, wf + 32768, A.b_item1,
                                     wf + 188416, A.b_item2, A.xbuf, 352, tile, lane, hw); break;
    default: mlp2_dev<128, 128, false>(A.ops_bf, nullptr, wf + 0, A.b_self1,
                                       wf + 155648, A.b_self2, A.xbuf, 480, tile, lane, hw); break;
  }
}

// ---------------------------------------------------------------------------
// Final combiner: FROZEN AT R8 — byte-for-byte.
// ---------------------------------------------------------------------------
__global__ __launch_bounds__(256, 4) void final_kernel(
    const bf16* __restrict__ xbuf,
    const short* __restrict__ Wc1f, const float* __restrict__ B1,
    const short* __restrict__ Wc2f, const float* __restrict__ B2,
    const float* __restrict__ W3, const float* __restrict__ B3,
    float* __restrict__ out, int ntiles) {
  __shared__ short hbuf[4 * 16 * 256];  // 32 KB: per-wave h1 bf16, then h2 f32 aliased
  const int lane = threadIdx.x & 63, wid = threadIdx.x >> 6;
  int tile = blockIdx.x * 4 + wid;
  if (tile >= ntiles) tile = ntiles - 1;
  const int g = lane >> 4, lp = lane & 15;
  const int row0 = tile * 16;
  char* hw = (char*)(hbuf + wid * (16 * 256));

  // ---- L1: h1 = relu(x @ Wc1 + b1), 608->256, MFMA ----
  {
    const bf16* xp = xbuf + (size_t)(row0 + lp) * 608 + g * 8;
    short8 a[19];
#pragma unroll
    for (int kc = 0; kc < 19; ++kc)
      a[kc] = *reinterpret_cast<const short8*>(xp + kc * 32);
#pragma unroll
    for (int ct = 0; ct < 16; ++ct) {
      float bv = B1[ct * 16 + lp];
      f32x4 acc = {bv, bv, bv, bv};
#pragma unroll
      for (int kc = 0; kc < 19; ++kc) {
        short8 b = *reinterpret_cast<const short8*>(
            Wc1f + ((size_t)(kc * 16 + ct) * 64 + lane) * 8);
        acc = __builtin_amdgcn_mfma_f32_16x16x32_bf16(a[kc], b, acc, 0, 0, 0);
      }
#pragma unroll
      for (int r = 0; r < 4; ++r) {
        int rr = g * 4 + r;
        int byte = rr * 512 + (ct * 16 + lp) * 2;
        byte ^= (rr & 7) << 4;
        *reinterpret_cast<short*>(hw + byte) = f2bf(fmaxf(acc[r], 0.f));
      }
    }
  }
  asm volatile("s_waitcnt lgkmcnt(0)" ::: "memory");
  __builtin_amdgcn_sched_barrier(0);

  // ---- L2: h2 = relu(h1 @ Wc2 + b2), 256->128, MFMA ----
  {
    short8 a2[8];
#pragma unroll
    for (int kc = 0; kc < 8; ++kc) {
      int byte = lp * 512 + (kc * 32 + g * 8) * 2;
      byte ^= (lp & 7) << 4;
      a2[kc] = *reinterpret_cast<const short8*>(hw + byte);
    }
    asm volatile("s_waitcnt lgkmcnt(0)" ::: "memory");
    __builtin_amdgcn_sched_barrier(0);
    float* h2 = (float*)hw;  // alias over h1 (a2 fully in regs)
#pragma unroll
    for (int ot = 0; ot < 8; ++ot) {
      float bv = B2[ot * 16 + lp];
      f32x4 acc = {bv, bv, bv, bv};
#pragma unroll
      for (int kc = 0; kc < 8; ++kc) {
        short8 b = *reinterpret_cast<const short8*>(
            Wc2f + ((size_t)(kc * 8 + ot) * 64 + lane) * 8);
        acc = __builtin_amdgcn_mfma_f32_16x16x32_bf16(a2[kc], b, acc, 0, 0, 0);
      }
#pragma unroll
      for (int r = 0; r < 4; ++r)
        h2[(g * 4 + r) * 128 + ot * 16 + lp] = fmaxf(acc[r], 0.f);
    }
  }
  asm volatile("s_waitcnt lgkmcnt(0)" ::: "memory");
  __builtin_amdgcn_sched_barrier(0);

  // ---- L3: out = h2 @ W3 + b3, f32 VALU (precision-critical) ----
  {
    const float* h2 = (const float*)hw;
    const int half = lane >> 5;
    const int c = (lane & 31) * 4;
    const int rbase = half * 8;
    f32x4 acc3[8];
    f32x4 bv = *reinterpret_cast<const f32x4*>(B3 + c);
#pragma unroll
    for (int rr = 0; rr < 8; ++rr) acc3[rr] = bv;
    for (int k0 = 0; k0 < 128; k0 += 4) {
      f32x4 w0 = *reinterpret_cast<const f32x4*>(W3 + (size_t)(k0 + 0) * 128 + c);
      f32x4 w1 = *reinterpret_cast<const f32x4*>(W3 + (size_t)(k0 + 1) * 128 + c);
      f32x4 w2v = *reinterpret_cast<const f32x4*>(W3 + (size_t)(k0 + 2) * 128 + c);
      f32x4 w3v = *reinterpret_cast<const f32x4*>(W3 + (size_t)(k0 + 3) * 128 + c);
#pragma unroll
      for (int rr = 0; rr < 8; ++rr) {
        f32x4 h = *reinterpret_cast<const f32x4*>(&h2[(rbase + rr) * 128 + k0]);
        acc3[rr] += h.x * w0 + h.y * w1 + h.z * w2v + h.w * w3v;
      }
    }
#pragma unroll
    for (int rr = 0; rr < 8; ++rr)
      *reinterpret_cast<f32x4*>(out + (size_t)(row0 + rbase + rr) * 128 + c) = acc3[rr];
  }
}

// ---------------------------------------------------------------------------
// kernel_launch
// ---------------------------------------------------------------------------
extern "C" void kernel_launch(void* const* d_in, const int* in_sizes, int n_in,
                              void* d_out, int out_size, void* d_ws,
                              size_t ws_size, hipStream_t stream) {
  const float* operations = (const float*)d_in[0];
  const float* items      = (const float*)d_in[1];
  const float* materials  = (const float*)d_in[2];
  const float* resources  = (const float*)d_in[3];
  const int* related      = (const int*)d_in[4];
  const int* res_op       = (const int*)d_in[5];
  const int* res_res      = (const int*)d_in[6];
  const int* mat_op       = (const int*)d_in[7];
  const int* mat_mat      = (const int*)d_in[8];
  const int* prec_src     = (const int*)d_in[9];
  const int* prec_dst     = (const int*)d_in[10];
  const float* w_self1 = (const float*)d_in[11];
  const float* b_self1 = (const float*)d_in[12];
  const float* w_self2 = (const float*)d_in[13];
  const float* b_self2 = (const float*)d_in[14];
  const float* w_item1 = (const float*)d_in[15];
  const float* b_item1 = (const float*)d_in[16];
  const float* w_item2 = (const float*)d_in[17];
  const float* b_item2 = (const float*)d_in[18];
  const float* w_pred1 = (const float*)d_in[19];
  const float* b_pred1 = (const float*)d_in[20];
  const float* w_pred2 = (const float*)d_in[21];
  const float* b_pred2 = (const float*)d_in[22];
  const float* w_succ1 = (const float*)d_in[23];
  const float* b_succ1 = (const float*)d_in[24];
  const float* w_succ2 = (const float*)d_in[25];
  const float* b_succ2 = (const float*)d_in[26];
  const float* w_res1  = (const float*)d_in[27];
  const float* b_res1  = (const float*)d_in[28];
  const float* w_res2  = (const float*)d_in[29];
  const float* b_res2  = (const float*)d_in[30];
  const float* w_mat1  = (const float*)d_in[31];
  const float* b_mat1  = (const float*)d_in[32];
  const float* w_mat2  = (const float*)d_in[33];
  const float* b_mat2  = (const float*)d_in[34];
  const float* w_c1    = (const float*)d_in[35];
  const float* b_c1    = (const float*)d_in[36];
  const float* w_c2    = (const float*)d_in[37];
  const float* b_c2    = (const float*)d_in[38];
  const float* w_c3    = (const float*)d_in[39];
  const float* b_c3    = (const float*)d_in[40];

  const int N = in_sizes[0] / 128;   // 50000
  const int NI = in_sizes[1] / 128;  // 20000
  const int E_RES = in_sizes[5];
  const int E_MAT = in_sizes[7];
  const int E_PREC = in_sizes[9];

  // ---- ws layout ----
  size_t off = 0;
  auto take = [&](size_t bytes) {
    size_t o = off;
    off += (bytes + 63) & ~(size_t)63;
    return o;
  };
  size_t xbuf_off  = take((size_t)N * 608 * 2);
  size_t aggp_off  = take((size_t)N * 128 * 2);
  size_t aggsu_off = take((size_t)N * 128 * 2);
  size_t aggr_off  = take((size_t)N * 64 * 2);
  size_t aggm_off  = take((size_t)N * 32 * 2);
  size_t wf_off    = take((size_t)499712 * 2);
  size_t opsb_off  = take((size_t)N * 128 * 2);
  size_t itemb_off = take((size_t)NI * 128 * 2);
  size_t offs_off  = take((size_t)4 * (N + 1) * 4);
  size_t tmp_off   = take((size_t)4 * N * 4);
  size_t cols_off  = take(((size_t)2 * E_PREC + E_RES + E_MAT) * 4);
  size_t bsum_off  = take((size_t)4 * 64 * 4);

  char* ws = (char*)d_ws;
  bf16* xbuf = (bf16*)(ws + xbuf_off);
  bf16* agg_pred = (bf16*)(ws + aggp_off);
  bf16* agg_succ = (bf16*)(ws + aggsu_off);
  bf16* agg_res  = (bf16*)(ws + aggr_off);
  bf16* agg_mat  = (bf16*)(ws + aggm_off);
  short* wf = (short*)(ws + wf_off);
  bf16* ops_bf   = (bf16*)(ws + opsb_off);
  bf16* items_bf = (bf16*)(ws + itemb_off);
  int* offs = (int*)(ws + offs_off);
  int* tmp  = (int*)(ws + tmp_off);
  int* cols = (int*)(ws + cols_off);
  int* bsum = (int*)(ws + bsum_off);

  int* offs_pred = offs;
  int* offs_succ = offs + (N + 1);
  int* offs_res  = offs + 2 * (N + 1);
  int* offs_mat  = offs + 3 * (N + 1);
  int* cur_pred = tmp;
  int* cur_succ = tmp + N;
  int* cur_res  = tmp + 2 * N;
  int* cur_mat  = tmp + 3 * N;
  int* col_pred = cols;
  int* col_succ = col_pred + E_PREC;
  int* col_res  = col_succ + E_PREC;
  int* col_mat  = col_res + E_RES;

  dim3 blk(256);

  // ---- fused preprocessing: cvt ops/items + wconv + zero tmp ----
  PrepArgs pp;
  pp.ops_src = operations; pp.ops_dst = ops_bf; pp.nops4 = N * 128 / 4;
  pp.items_src = items; pp.items_dst = items_bf; pp.nitems4 = NI * 128 / 4;
  pp.wd.w[0]  = {w_self1, 128, 256, 0};
  pp.wd.w[1]  = {w_item1, 128, 256, 32768};
  pp.wd.w[2]  = {w_pred1, 128, 256, 65536};
  pp.wd.w[3]  = {w_succ1, 128, 256, 98304};
  pp.wd.w[4]  = {w_res1,   64, 256, 131072};
  pp.wd.w[5]  = {w_mat1,   32, 256, 147456};
  pp.wd.w[6]  = {w_self2, 256, 128, 155648};
  pp.wd.w[7]  = {w_item2, 256, 128, 188416};
  pp.wd.w[8]  = {w_pred2, 256, 128, 221184};
  pp.wd.w[9]  = {w_succ2, 256, 128, 253952};
  pp.wd.w[10] = {w_res2,  256,  64, 286720};
  pp.wd.w[11] = {w_mat2,  256,  32, 303104};
  pp.wd.w[12] = {w_c1,    608, 256, 311296};
  pp.wd.w[13] = {w_c2,    256, 128, 466944};
  pp.wf = wf;
  pp.tmp = tmp; pp.ntmp = 4 * N;
  int prepx = (pp.nops4 + 255) / 256;  // 6250, covers all slices
  prep_kernel<<<dim3(prepx, 4), blk, 0, stream>>>(pp);

  // ---- CSR build ----
  EdgeLists4 els;
  els.l[0] = {prec_src, prec_dst, cur_pred, col_pred, E_PREC};
  els.l[1] = {prec_dst, prec_src, cur_succ, col_succ, E_PREC};
  els.l[2] = {res_op, res_res, cur_res, col_res, E_RES};
  els.l[3] = {mat_op, mat_mat, cur_mat, col_mat, E_MAT};
  int cgx = (E_PREC / 4 + 255) / 256;  // 4 edges/thread
  count4v_kernel<<<dim3(cgx, 4), blk, 0, stream>>>(els);
  int nchunk = (N + 1023) / 1024;  // 49
  chunksum_kernel<<<dim3(nchunk, 4), blk, 0, stream>>>(tmp, bsum, N, nchunk);
  scanfinal2_kernel<<<dim3(nchunk, 4), dim3(1024), 0, stream>>>(tmp, bsum, offs, tmp, N, nchunk);
  fill4v_kernel<<<dim3(cgx, 4), blk, 0, stream>>>(els);

  // ---- aggregates ----
  AggArgs aa;
  aa.ops_tab = ops_bf; aa.res_tab = resources; aa.mat_tab = materials;
  aa.col_pred = col_pred; aa.col_succ = col_succ; aa.col_res = col_res; aa.col_mat = col_mat;
  aa.offs_pred = offs_pred; aa.offs_succ = offs_succ; aa.offs_res = offs_res; aa.offs_mat = offs_mat;
  aa.agg_pred = agg_pred; aa.agg_succ = agg_succ; aa.agg_res = agg_res; aa.agg_mat = agg_mat;
  aa.n = N;
  agg_all_kernel<<<dim3((N + 3) / 4, 4), blk, 0, stream>>>(aa);

  // ---- 6 MLPs in one launch ----
  int ntiles = N / 16;           // 3125
  int mgrid = (ntiles + 3) / 4;  // 782
  Mlp6Args ma;
  ma.agg_pred = agg_pred; ma.agg_succ = agg_succ; ma.agg_res = agg_res; ma.agg_mat = agg_mat;
  ma.items_bf = items_bf; ma.ops_bf = ops_bf; ma.related = related; ma.wf = wf;
  ma.b_pred1 = b_pred1; ma.b_pred2 = b_pred2; ma.b_succ1 = b_succ1; ma.b_succ2 = b_succ2;
  ma.b_res1 = b_res1; ma.b_res2 = b_res2; ma.b_mat1 = b_mat1; ma.b_mat2 = b_mat2;
  ma.b_item1 = b_item1; ma.b_item2 = b_item2; ma.b_self1 = b_self1; ma.b_self2 = b_self2;
  ma.xbuf = xbuf; ma.ntiles = ntiles;
  mlp6_kernel<<<dim3(mgrid, 6), blk, 0, stream>>>(ma);

  // ---- final combiner ----
  final_kernel<<<mgrid, blk, 0, stream>>>(
      xbuf, wf + 311296, b_c1, wf + 466944, b_c2, w_c3, b_c3, (float*)d_out, ntiles);
}